// Round 1
// baseline (858.993 us; speedup 1.0000x reference)
//
#include <hip/hip_runtime.h>
#include <math.h>

#define EPS 1e-6f
#define LN_EPS 1e-5f

static constexpr int Bn = 2, Tn = 2048, Dn = 512, Hn = 8, KT = 2, DH = 64, NC = Tn / 64;

__device__ __forceinline__ float wred_sum(float v) {
#pragma unroll
  for (int o = 32; o > 0; o >>= 1) v += __shfl_xor(v, o, 64);
  return v;
}
__device__ __forceinline__ float wred_max(float v) {
#pragma unroll
  for (int o = 32; o > 0; o >>= 1) v = fmaxf(v, __shfl_xor(v, o, 64));
  return v;
}
__device__ __forceinline__ float sigmoidf_(float v) { return 1.0f / (1.0f + expf(-v)); }

// ---------------------------------------------------------------------------
// C[M,N] = A[M,Kd] @ W[N,Kd]^T (+bias). fp32, 64x64 tile, BK=16, 4x4 microtile.
// ---------------------------------------------------------------------------
__global__ __launch_bounds__(256) void gemm_bt(const float* __restrict__ A,
                                               const float* __restrict__ W,
                                               const float* __restrict__ bias,
                                               float* __restrict__ C,
                                               int M, int N, int Kd) {
  constexpr int LSTR = 68;  // pad 64->68: breaks stride-64 bank aliasing, keeps 16B align
  __shared__ float As[16][LSTR];
  __shared__ float Bs[16][LSTR];
  const int tid = threadIdx.x;
  const int tx = tid & 15, ty = tid >> 4;
  const int n0 = blockIdx.x * 64, m0 = blockIdx.y * 64;
  const int r = tid >> 2, g = tid & 3;
  float acc[4][4] = {};
  for (int k0 = 0; k0 < Kd; k0 += 16) {
    float4 av = *(const float4*)&A[(size_t)(m0 + r) * Kd + k0 + g * 4];
    float4 bv = *(const float4*)&W[(size_t)(n0 + r) * Kd + k0 + g * 4];
    __syncthreads();
    As[g * 4 + 0][r] = av.x; As[g * 4 + 1][r] = av.y;
    As[g * 4 + 2][r] = av.z; As[g * 4 + 3][r] = av.w;
    Bs[g * 4 + 0][r] = bv.x; Bs[g * 4 + 1][r] = bv.y;
    Bs[g * 4 + 2][r] = bv.z; Bs[g * 4 + 3][r] = bv.w;
    __syncthreads();
#pragma unroll
    for (int kk = 0; kk < 16; ++kk) {
      float4 a = *(const float4*)&As[kk][ty * 4];
      float4 b = *(const float4*)&Bs[kk][tx * 4];
      float aa[4] = {a.x, a.y, a.z, a.w};
      float bb[4] = {b.x, b.y, b.z, b.w};
#pragma unroll
      for (int ii = 0; ii < 4; ++ii)
#pragma unroll
        for (int jj = 0; jj < 4; ++jj) acc[ii][jj] += aa[ii] * bb[jj];
    }
  }
#pragma unroll
  for (int ii = 0; ii < 4; ++ii) {
    int row = m0 + ty * 4 + ii, col = n0 + tx * 4;
    float4 o;
    o.x = acc[ii][0]; o.y = acc[ii][1]; o.z = acc[ii][2]; o.w = acc[ii][3];
    if (bias) { o.x += bias[col]; o.y += bias[col + 1]; o.z += bias[col + 2]; o.w += bias[col + 3]; }
    *(float4*)&C[(size_t)row * N + col] = o;
  }
}

// ---------------------------------------------------------------------------
// gate = sigmoid(x@Wg^T + bg)  [B,T,H,K];  alpha = sigmoid(x@Wa^T + ba) [B,T,H]
// one block per token row; wave w computes outputs o = 6w..6w+5 (24 total)
// ---------------------------------------------------------------------------
__global__ __launch_bounds__(256) void gate_alpha(const float* __restrict__ x,
                                                  const float* __restrict__ Wg,
                                                  const float* __restrict__ bg,
                                                  const float* __restrict__ Wa,
                                                  const float* __restrict__ ba,
                                                  float* __restrict__ gate,
                                                  float* __restrict__ alpha) {
  const int row = blockIdx.x;  // b*T + t
  const int wave = threadIdx.x >> 6, lane = threadIdx.x & 63;
  const float* xr = x + (size_t)row * Dn;
  for (int o = wave * 6; o < wave * 6 + 6; ++o) {
    const float* wrow;
    float bv;
    if (o < Hn * KT) { wrow = Wg + (size_t)o * Dn; bv = bg[o]; }
    else             { wrow = Wa + (size_t)(o - Hn * KT) * Dn; bv = ba[o - Hn * KT]; }
    float p = 0.f;
#pragma unroll
    for (int rr = 0; rr < 8; ++rr) p += xr[lane + 64 * rr] * wrow[lane + 64 * rr];
    p = wred_sum(p);
    if (lane == 0) {
      float s = sigmoidf_(p + bv);
      if (o < Hn * KT) gate[(size_t)row * (Hn * KT) + o] = s;
      else             alpha[(size_t)row * Hn + (o - Hn * KT)] = s;
    }
  }
}

// ---------------------------------------------------------------------------
// Per (b,h,k,chunk) wave: S = sum_t lam^{63-t} g_t k_t v_t^T  [64x64], z scalar
// lane = column j; acc[i] = S[i][lane]
// ---------------------------------------------------------------------------
__global__ __launch_bounds__(256) void chunk_sums(const float* __restrict__ K_,
                                                  const float* __restrict__ V_,
                                                  const float* __restrict__ gate,
                                                  const float* __restrict__ decay,
                                                  float* __restrict__ S,
                                                  float* __restrict__ Zc) {
  const int gw = (blockIdx.x * blockDim.x + threadIdx.x) >> 6;
  const int lane = threadIdx.x & 63;
  int c = gw % NC, tmp = gw / NC;
  int k = tmp % KT; tmp /= KT;
  int h = tmp % Hn, b = tmp / Hn;
  const float lam = sigmoidf_(decay[h * KT + k]);
  float acc[64];
#pragma unroll
  for (int i = 0; i < 64; ++i) acc[i] = 0.f;
  float z = 0.f, lampow = 1.f;
  for (int t = 63; t >= 0; --t) {
    int tg = c * 64 + t;
    size_t base = ((size_t)(b * Tn + tg) * Hn + h) * DH;
    float kv = K_[base + lane];
    float vv = V_[base + lane];
    float gv = gate[((size_t)(b * Tn + tg) * Hn + h) * KT + k];
    float coef = gv * lampow;
    float asum = wred_sum(fabsf(kv));
    z += coef * (asum * (1.f / 64.f) + EPS);
    float ck = coef * kv;
#pragma unroll
    for (int i = 0; i < 64; ++i) acc[i] += __shfl(ck, i, 64) * vv;
    lampow *= lam;
  }
  size_t sb = (size_t)gw * 4096;
#pragma unroll
  for (int i = 0; i < 64; ++i) S[sb + i * 64 + lane] = acc[i];
  if (lane == 0) Zc[gw] = z;
}

// ---------------------------------------------------------------------------
// Serial scan over chunks: Hinit[c] = state before chunk c. 32 blocks (b,h,k).
// ---------------------------------------------------------------------------
__global__ __launch_bounds__(256) void scan_chunks(const float* __restrict__ S,
                                                   const float* __restrict__ Zc,
                                                   const float* __restrict__ decay,
                                                   float* __restrict__ Hinit,
                                                   float* __restrict__ Zinit) {
  const int bhk = blockIdx.x;
  const int k = bhk % KT, h = (bhk / KT) % Hn;
  const float lam = sigmoidf_(decay[h * KT + k]);
  const float lam64 = powf(lam, 64.f);
  const int tid = threadIdx.x;
  const size_t base = (size_t)bhk * NC * 4096;
  float st[16];
#pragma unroll
  for (int rr = 0; rr < 16; ++rr) st[rr] = 0.f;
  float zst = 0.f;
  for (int c = 0; c < NC; ++c) {
    size_t off = base + (size_t)c * 4096 + (size_t)tid * 16;
    float4* hp = (float4*)(Hinit + off);
    const float4* sp = (const float4*)(S + off);
#pragma unroll
    for (int rr = 0; rr < 4; ++rr) {
      float4 o; o.x = st[4*rr]; o.y = st[4*rr+1]; o.z = st[4*rr+2]; o.w = st[4*rr+3];
      hp[rr] = o;
      float4 sv = sp[rr];
      st[4*rr]   = lam64 * st[4*rr]   + sv.x;
      st[4*rr+1] = lam64 * st[4*rr+1] + sv.y;
      st[4*rr+2] = lam64 * st[4*rr+2] + sv.z;
      st[4*rr+3] = lam64 * st[4*rr+3] + sv.w;
    }
    if (tid == 0) {
      Zinit[bhk * NC + c] = zst;
      zst = lam64 * zst + Zc[bhk * NC + c];
    }
  }
}

// ---------------------------------------------------------------------------
// One wave per (b,t,h): sliding-window ALiBi softmax + chunked linear readout,
// alpha-combined -> ypre[B,T,D]
// ---------------------------------------------------------------------------
__global__ __launch_bounds__(256) void attn_fused(const float* __restrict__ Q_,
                                                  const float* __restrict__ K_,
                                                  const float* __restrict__ V_,
                                                  const float* __restrict__ gate,
                                                  const float* __restrict__ alpha,
                                                  const float* __restrict__ decay,
                                                  const float* __restrict__ Hinit,
                                                  const float* __restrict__ Zinit,
                                                  float* __restrict__ ypre) {
  const int gw = (blockIdx.x * blockDim.x + threadIdx.x) >> 6;  // (b*T+t)*H + h
  const int lane = threadIdx.x & 63;
  const int h = gw % Hn;
  const int bt = gw / Hn;
  const int t = bt % Tn, b = bt / Tn;
  const int c = t >> 6, i = t & 63;

  const size_t qoff = (size_t)gw * DH;
  const float qv = Q_[qoff + lane];

  // ---- local sliding-window attention (64 keys incl self), lane = key ----
  const int kg = t - 63 + lane;
  const int kgc = kg < 0 ? 0 : kg;
  const float4* krow = (const float4*)(K_ + ((size_t)(b * Tn + kgc) * Hn + h) * DH);
  float score = 0.f;
#pragma unroll
  for (int dq = 0; dq < 16; ++dq) {
    float4 kk = krow[dq];
    score += __shfl(qv, 4 * dq + 0, 64) * kk.x + __shfl(qv, 4 * dq + 1, 64) * kk.y +
             __shfl(qv, 4 * dq + 2, 64) * kk.z + __shfl(qv, 4 * dq + 3, 64) * kk.w;
  }
  const float slope = exp2f(-(float)(h + 1) * 8.0f / (float)Hn);
  score -= slope * (float)(63 - lane);
  if (kg < 0) score = -1e30f;
  float mx = wred_max(score);
  float p = __expf(score - mx);
  float psum = wred_sum(p);
  p /= psum;
  float yloc = 0.f;
#pragma unroll
  for (int j = 0; j < 64; ++j) {
    int kj = t - 63 + j;           // wave-uniform
    if (kj >= 0) {
      float pj = __shfl(p, j, 64);
      yloc += pj * V_[((size_t)(b * Tn + kj) * Hn + h) * DH + lane];
    }
  }

  // ---- linear attention readout, lane = intra-chunk key s (and out-dim) ----
  const int sg0 = c * 64;
  const float4* lkrow = (const float4*)(K_ + ((size_t)(b * Tn + sg0 + lane) * Hn + h) * DH);
  float Pdot = 0.f, asum = 0.f;
#pragma unroll
  for (int dq = 0; dq < 16; ++dq) {
    float4 kk = lkrow[dq];
    Pdot += __shfl(qv, 4 * dq + 0, 64) * kk.x + __shfl(qv, 4 * dq + 1, 64) * kk.y +
            __shfl(qv, 4 * dq + 2, 64) * kk.z + __shfl(qv, 4 * dq + 3, 64) * kk.w;
    asum += fabsf(kk.x) + fabsf(kk.y) + fabsf(kk.z) + fabsf(kk.w);
  }
  const float sval = asum * (1.f / 64.f) + EPS;
  float ylin = 0.f;
  for (int k = 0; k < KT; ++k) {
    const float lam = sigmoidf_(decay[h * KT + k]);
    const float gv = gate[((size_t)(b * Tn + sg0 + lane) * Hn + h) * KT + k];
    const float wgt = (lane <= i) ? gv * __powf(lam, (float)(i - lane)) : 0.f;
    float z = wred_sum(wgt * sval);
    const float lamip1 = __powf(lam, (float)(i + 1));
    const int bhk = (b * Hn + h) * KT + k;
    const size_t hb = ((size_t)bhk * NC + c) * 4096;
    float m = 0.f;
#pragma unroll
    for (int rr = 0; rr < 64; ++rr) m += __shfl(qv, rr, 64) * Hinit[hb + (size_t)rr * 64 + lane];
    z = lamip1 * Zinit[bhk * NC + c] + z;
    float yk = lamip1 * m;
    const float coef = wgt * Pdot;
    for (int s = 0; s <= i; ++s) {  // wave-uniform bound
      float cs = __shfl(coef, s, 64);
      yk += cs * V_[((size_t)(b * Tn + sg0 + s) * Hn + h) * DH + lane];
    }
    ylin += yk / (z + EPS);
  }
  const float av = alpha[(size_t)bt * Hn + h];
  ypre[qoff + lane] = av * yloc + (1.f - av) * ylin;
}

// ---------------------------------------------------------------------------
// out = LayerNorm(x + proj) * gamma + beta ; one block per row of 512
// ---------------------------------------------------------------------------
__global__ __launch_bounds__(256) void ln_kernel(const float* __restrict__ x,
                                                 const float* __restrict__ proj,
                                                 const float* __restrict__ gamma,
                                                 const float* __restrict__ beta,
                                                 float* __restrict__ out) {
  const int row = blockIdx.x;
  const int tid = threadIdx.x;
  const int wave = tid >> 6, lane = tid & 63;
  const size_t base = (size_t)row * Dn;
  __shared__ float red[8];
  float r0 = x[base + tid] + proj[base + tid];
  float r1 = x[base + tid + 256] + proj[base + tid + 256];
  float s = wred_sum(r0 + r1);
  if (lane == 0) red[wave] = s;
  __syncthreads();
  float mu = (red[0] + red[1] + red[2] + red[3]) * (1.f / (float)Dn);
  float d0 = r0 - mu, d1 = r1 - mu;
  float q = wred_sum(d0 * d0 + d1 * d1);
  if (lane == 0) red[4 + wave] = q;
  __syncthreads();
  float var = (red[4] + red[5] + red[6] + red[7]) * (1.f / (float)Dn);
  float inv = rsqrtf(var + LN_EPS);
  out[base + tid]       = d0 * inv * gamma[tid]       + beta[tid];
  out[base + tid + 256] = d1 * inv * gamma[tid + 256] + beta[tid + 256];
}

// ---------------------------------------------------------------------------
extern "C" void kernel_launch(void* const* d_in, const int* in_sizes, int n_in,
                              void* d_out, int out_size, void* d_ws, size_t ws_size,
                              hipStream_t stream) {
  const float* x     = (const float*)d_in[0];
  const float* Wq    = (const float*)d_in[1];
  const float* Wk    = (const float*)d_in[2];
  const float* Wv    = (const float*)d_in[3];
  const float* Wg    = (const float*)d_in[4];
  const float* bg    = (const float*)d_in[5];
  const float* Wa    = (const float*)d_in[6];
  const float* ba    = (const float*)d_in[7];
  const float* Wo    = (const float*)d_in[8];
  const float* bo    = (const float*)d_in[9];
  const float* decay = (const float*)d_in[10];
  const float* gamma = (const float*)d_in[11];
  const float* beta  = (const float*)d_in[12];
  float* out = (float*)d_out;

  const size_t NTOK = (size_t)Bn * Tn;        // 4096
  const size_t NEL  = NTOK * Dn;              // 2097152
  float* ws = (float*)d_ws;
  float* qb    = ws;              ws += NEL;
  float* kb    = ws;              ws += NEL;
  float* vb    = ws;              ws += NEL;
  float* gateb = ws;              ws += NTOK * Hn * KT;
  float* alphb = ws;              ws += NTOK * Hn;
  float* Sb    = ws;              ws += (size_t)Bn * Hn * KT * NC * 4096;
  float* Zcb   = ws;              ws += (size_t)Bn * Hn * KT * NC;
  float* Hib   = ws;              ws += (size_t)Bn * Hn * KT * NC * 4096;
  float* Zib   = ws;              ws += (size_t)Bn * Hn * KT * NC;
  float* ypre  = ws;              ws += NEL;
  float* proj  = ws;              ws += NEL;

  const int M = (int)NTOK, N = Dn, Kd = Dn;
  dim3 ggrid(N / 64, M / 64);

  gemm_bt<<<ggrid, 256, 0, stream>>>(x, Wq, nullptr, qb, M, N, Kd);
  gemm_bt<<<ggrid, 256, 0, stream>>>(x, Wk, nullptr, kb, M, N, Kd);
  gemm_bt<<<ggrid, 256, 0, stream>>>(x, Wv, nullptr, vb, M, N, Kd);
  gate_alpha<<<(int)NTOK, 256, 0, stream>>>(x, Wg, bg, Wa, ba, gateb, alphb);

  chunk_sums<<<(Bn * Hn * KT * NC * 64) / 256, 256, 0, stream>>>(kb, vb, gateb, decay, Sb, Zcb);
  scan_chunks<<<Bn * Hn * KT, 256, 0, stream>>>(Sb, Zcb, decay, Hib, Zib);

  attn_fused<<<(int)(NTOK * Hn * 64) / 256, 256, 0, stream>>>(qb, kb, vb, gateb, alphb,
                                                              decay, Hib, Zib, ypre);

  gemm_bt<<<ggrid, 256, 0, stream>>>(ypre, Wo, bo, proj, M, N, Kd);
  ln_kernel<<<(int)NTOK, 256, 0, stream>>>(x, proj, gamma, beta, out);
}

// Round 2
// 429.539 us; speedup vs baseline: 1.9998x; 1.9998x over previous
//
#include <hip/hip_runtime.h>
#include <math.h>

#define EPS 1e-6f
#define LN_EPS 1e-5f

static constexpr int Bn = 2, Tn = 2048, Dn = 512, Hn = 8, KT = 2, DH = 64, NC = Tn / 64;

__device__ __forceinline__ float wred_sum(float v) {
#pragma unroll
  for (int o = 32; o > 0; o >>= 1) v += __shfl_xor(v, o, 64);
  return v;
}
__device__ __forceinline__ float wred_max(float v) {
#pragma unroll
  for (int o = 32; o > 0; o >>= 1) v = fmaxf(v, __shfl_xor(v, o, 64));
  return v;
}
__device__ __forceinline__ float sigmoidf_(float v) { return 1.0f / (1.0f + expf(-v)); }

// ---------------------------------------------------------------------------
// C[M,N] = A[M,Kd] @ W[N,Kd]^T (+bias). fp32, 64x64 tile, BK=16, 4x4 microtile.
// ---------------------------------------------------------------------------
__global__ __launch_bounds__(256) void gemm_bt(const float* __restrict__ A,
                                               const float* __restrict__ W,
                                               const float* __restrict__ bias,
                                               float* __restrict__ C,
                                               int M, int N, int Kd) {
  constexpr int LSTR = 68;
  __shared__ float As[16][LSTR];
  __shared__ float Bs[16][LSTR];
  const int tid = threadIdx.x;
  const int tx = tid & 15, ty = tid >> 4;
  const int n0 = blockIdx.x * 64, m0 = blockIdx.y * 64;
  const int r = tid >> 2, g = tid & 3;
  float acc[4][4] = {};
  for (int k0 = 0; k0 < Kd; k0 += 16) {
    float4 av = *(const float4*)&A[(size_t)(m0 + r) * Kd + k0 + g * 4];
    float4 bv = *(const float4*)&W[(size_t)(n0 + r) * Kd + k0 + g * 4];
    __syncthreads();
    As[g * 4 + 0][r] = av.x; As[g * 4 + 1][r] = av.y;
    As[g * 4 + 2][r] = av.z; As[g * 4 + 3][r] = av.w;
    Bs[g * 4 + 0][r] = bv.x; Bs[g * 4 + 1][r] = bv.y;
    Bs[g * 4 + 2][r] = bv.z; Bs[g * 4 + 3][r] = bv.w;
    __syncthreads();
#pragma unroll
    for (int kk = 0; kk < 16; ++kk) {
      float4 a = *(const float4*)&As[kk][ty * 4];
      float4 b = *(const float4*)&Bs[kk][tx * 4];
      float aa[4] = {a.x, a.y, a.z, a.w};
      float bb[4] = {b.x, b.y, b.z, b.w};
#pragma unroll
      for (int ii = 0; ii < 4; ++ii)
#pragma unroll
        for (int jj = 0; jj < 4; ++jj) acc[ii][jj] += aa[ii] * bb[jj];
    }
  }
#pragma unroll
  for (int ii = 0; ii < 4; ++ii) {
    int row = m0 + ty * 4 + ii, col = n0 + tx * 4;
    float4 o;
    o.x = acc[ii][0]; o.y = acc[ii][1]; o.z = acc[ii][2]; o.w = acc[ii][3];
    if (bias) { o.x += bias[col]; o.y += bias[col + 1]; o.z += bias[col + 2]; o.w += bias[col + 3]; }
    *(float4*)&C[(size_t)row * N + col] = o;
  }
}

// ---------------------------------------------------------------------------
// gate/alpha projections + sigmoid
// ---------------------------------------------------------------------------
__global__ __launch_bounds__(256) void gate_alpha(const float* __restrict__ x,
                                                  const float* __restrict__ Wg,
                                                  const float* __restrict__ bg,
                                                  const float* __restrict__ Wa,
                                                  const float* __restrict__ ba,
                                                  float* __restrict__ gate,
                                                  float* __restrict__ alpha) {
  const int row = blockIdx.x;
  const int wave = threadIdx.x >> 6, lane = threadIdx.x & 63;
  const float* xr = x + (size_t)row * Dn;
  for (int o = wave * 6; o < wave * 6 + 6; ++o) {
    const float* wrow;
    float bv;
    if (o < Hn * KT) { wrow = Wg + (size_t)o * Dn; bv = bg[o]; }
    else             { wrow = Wa + (size_t)(o - Hn * KT) * Dn; bv = ba[o - Hn * KT]; }
    float p = 0.f;
#pragma unroll
    for (int rr = 0; rr < 8; ++rr) p += xr[lane + 64 * rr] * wrow[lane + 64 * rr];
    p = wred_sum(p);
    if (lane == 0) {
      float s = sigmoidf_(p + bv);
      if (o < Hn * KT) gate[(size_t)row * (Hn * KT) + o] = s;
      else             alpha[(size_t)row * Hn + (o - Hn * KT)] = s;
    }
  }
}

// ---------------------------------------------------------------------------
// Per (b,h,k,chunk) wave: S = sum_t lam^{63-t} g_t k_t v_t^T  [64x64], z scalar
// ---------------------------------------------------------------------------
__global__ __launch_bounds__(256) void chunk_sums(const float* __restrict__ K_,
                                                  const float* __restrict__ V_,
                                                  const float* __restrict__ gate,
                                                  const float* __restrict__ decay,
                                                  float* __restrict__ S,
                                                  float* __restrict__ Zc) {
  const int gw = (blockIdx.x * blockDim.x + threadIdx.x) >> 6;
  const int lane = threadIdx.x & 63;
  int c = gw % NC, tmp = gw / NC;
  int k = tmp % KT; tmp /= KT;
  int h = tmp % Hn, b = tmp / Hn;
  const float lam = sigmoidf_(decay[h * KT + k]);
  float acc[64];
#pragma unroll
  for (int i = 0; i < 64; ++i) acc[i] = 0.f;
  float z = 0.f, lampow = 1.f;
  for (int t = 63; t >= 0; --t) {
    int tg = c * 64 + t;
    size_t base = ((size_t)(b * Tn + tg) * Hn + h) * DH;
    float kv = K_[base + lane];
    float vv = V_[base + lane];
    float gv = gate[((size_t)(b * Tn + tg) * Hn + h) * KT + k];
    float coef = gv * lampow;
    float asum = wred_sum(fabsf(kv));
    z += coef * (asum * (1.f / 64.f) + EPS);
    float ck = coef * kv;
#pragma unroll
    for (int i = 0; i < 64; ++i) acc[i] += __shfl(ck, i, 64) * vv;
    lampow *= lam;
  }
  size_t sb = (size_t)gw * 4096;
#pragma unroll
  for (int i = 0; i < 64; ++i) S[sb + i * 64 + lane] = acc[i];
  if (lane == 0) Zc[gw] = z;
}

// ---------------------------------------------------------------------------
// Serial scan over chunks: Hinit[c] = state before chunk c.
// ---------------------------------------------------------------------------
__global__ __launch_bounds__(256) void scan_chunks(const float* __restrict__ S,
                                                   const float* __restrict__ Zc,
                                                   const float* __restrict__ decay,
                                                   float* __restrict__ Hinit,
                                                   float* __restrict__ Zinit) {
  const int bhk = blockIdx.x;
  const int k = bhk % KT, h = (bhk / KT) % Hn;
  const float lam = sigmoidf_(decay[h * KT + k]);
  const float lam64 = powf(lam, 64.f);
  const int tid = threadIdx.x;
  const size_t base = (size_t)bhk * NC * 4096;
  float st[16];
#pragma unroll
  for (int rr = 0; rr < 16; ++rr) st[rr] = 0.f;
  float zst = 0.f;
  for (int c = 0; c < NC; ++c) {
    size_t off = base + (size_t)c * 4096 + (size_t)tid * 16;
    float4* hp = (float4*)(Hinit + off);
    const float4* sp = (const float4*)(S + off);
#pragma unroll
    for (int rr = 0; rr < 4; ++rr) {
      float4 o; o.x = st[4*rr]; o.y = st[4*rr+1]; o.z = st[4*rr+2]; o.w = st[4*rr+3];
      hp[rr] = o;
      float4 sv = sp[rr];
      st[4*rr]   = lam64 * st[4*rr]   + sv.x;
      st[4*rr+1] = lam64 * st[4*rr+1] + sv.y;
      st[4*rr+2] = lam64 * st[4*rr+2] + sv.z;
      st[4*rr+3] = lam64 * st[4*rr+3] + sv.w;
    }
    if (tid == 0) {
      Zinit[bhk * NC + c] = zst;
      zst = lam64 * zst + Zc[bhk * NC + c];
    }
  }
}

// ---------------------------------------------------------------------------
// Block per (b,h,c): chunked attention. 256 threads, micro-tiled block GEMMs.
//   sS = Qc @ Kwin^T  (64x128 raw scores; cur half doubles as P for linear)
//   ylin_k = [lam^(i+1)*(Q@Hinit_k) + (W_k o P)@Vc] / z_k ; z via decay-scan
//   softmax(sS) in place; yloc = A @ Vwin; out = alpha*yloc+(1-alpha)*ylin
// ---------------------------------------------------------------------------
__global__ __launch_bounds__(256) void attn_chunk(const float* __restrict__ Q_,
                                                  const float* __restrict__ K_,
                                                  const float* __restrict__ V_,
                                                  const float* __restrict__ gate,
                                                  const float* __restrict__ alpha,
                                                  const float* __restrict__ decay,
                                                  const float* __restrict__ Hinit,
                                                  const float* __restrict__ Zinit,
                                                  float* __restrict__ ypre) {
  __shared__ float sS[64][129];   // stride 129 (odd): column reads spread banks
  __shared__ float sQ[64][68];
  __shared__ float sB[16][132];   // staging tile (also scratch in prologue)
  __shared__ float sval_s[64];
  __shared__ float gk[KT][64];
  __shared__ float sz[KT][64];
  __shared__ float pw[KT][65];
  __shared__ float zin[KT];

  const int c = blockIdx.x, h = blockIdx.y, b = blockIdx.z;
  const int c0 = c * 64;
  const int tid = threadIdx.x;
  const int tx = tid & 15, ty = tid >> 4;
  const int i0 = ty * 4;
  const int wave = tid >> 6, lane = tid & 63;

  // ---------------- prologue: sQ, sval partials, gates, pow tables ---------
#pragma unroll
  for (int u = 0; u < 4; ++u) {
    int idx = tid + 256 * u;
    int fi = idx >> 4, fc = idx & 15;
    float4 v = *(const float4*)&Q_[((size_t)(b * Tn + c0 + fi) * Hn + h) * DH + fc * 4];
    *(float4*)&sQ[fi][fc * 4] = v;
  }
  {
    int s = tid >> 2, qq = tid & 3;
    const float* kr = K_ + ((size_t)(b * Tn + c0 + s) * Hn + h) * DH + qq * 16;
    float acc = 0.f;
#pragma unroll
    for (int u = 0; u < 4; ++u) {
      float4 v = *(const float4*)(kr + u * 4);
      acc += fabsf(v.x) + fabsf(v.y) + fabsf(v.z) + fabsf(v.w);
    }
    ((float*)sB)[tid] = acc;
  }
  if (tid < 128) {
    int s = tid >> 1, k2 = tid & 1;
    gk[k2][s] = gate[((size_t)(b * Tn + c0 + s) * Hn + h) * KT + k2];
  }
  if (tid < 128) {
    int k2 = tid >> 6, d = tid & 63;
    float lamv = sigmoidf_(decay[h * KT + k2]);
    pw[k2][d] = powf(lamv, (float)d);
  }
  if (tid < 2) {
    float lamv = sigmoidf_(decay[h * KT + tid]);
    pw[tid][64] = powf(lamv, 64.f);
    zin[tid] = Zinit[((size_t)((b * Hn + h) * KT + tid)) * NC + c];
  }
  __syncthreads();
  if (tid < 64) {
    const float* f = (const float*)sB;
    sval_s[tid] = (f[tid * 4] + f[tid * 4 + 1] + f[tid * 4 + 2] + f[tid * 4 + 3]) * (1.f / 64.f) + EPS;
  }
  __syncthreads();
  // decay-weighted inclusive scan for z (waves 0,1)
  if (wave < 2) {
    const int kx = wave;
    float v = gk[kx][lane] * sval_s[lane];
#pragma unroll
    for (int o = 1; o < 64; o <<= 1) {
      float t2 = __shfl_up(v, o, 64);
      if (lane >= o) v += pw[kx][o] * t2;
    }
    sz[kx][lane] = v + pw[kx][lane + 1] * zin[kx];
  }

  // ---------------- phase A: sS = Qc @ Kwin^T (raw scores) -----------------
  float accA[4][8];
#pragma unroll
  for (int ii = 0; ii < 4; ++ii)
#pragma unroll
    for (int jj = 0; jj < 8; ++jj) accA[ii][jj] = 0.f;
  const int j0 = tx * 8;
  for (int k0 = 0; k0 < 64; k0 += 16) {
    __syncthreads();
    {
      int j = tid & 127, half = tid >> 7;
      int tg = c0 - 64 + j;
      float4 v0 = {0, 0, 0, 0}, v1 = {0, 0, 0, 0};
      if (tg >= 0) {
        const float* kr = K_ + ((size_t)(b * Tn + tg) * Hn + h) * DH + k0 + half * 8;
        v0 = *(const float4*)kr;
        v1 = *(const float4*)(kr + 4);
      }
      int kk0 = half * 8;
      sB[kk0 + 0][j] = v0.x; sB[kk0 + 1][j] = v0.y; sB[kk0 + 2][j] = v0.z; sB[kk0 + 3][j] = v0.w;
      sB[kk0 + 4][j] = v1.x; sB[kk0 + 5][j] = v1.y; sB[kk0 + 6][j] = v1.z; sB[kk0 + 7][j] = v1.w;
    }
    __syncthreads();
#pragma unroll
    for (int ks = 0; ks < 16; ks += 4) {
      float4 aq[4];
#pragma unroll
      for (int ii = 0; ii < 4; ++ii) aq[ii] = *(const float4*)&sQ[i0 + ii][k0 + ks];
#pragma unroll
      for (int kk = 0; kk < 4; ++kk) {
        float4 b0 = *(const float4*)&sB[ks + kk][j0];
        float4 b1 = *(const float4*)&sB[ks + kk][j0 + 4];
        float bb[8] = {b0.x, b0.y, b0.z, b0.w, b1.x, b1.y, b1.z, b1.w};
#pragma unroll
        for (int ii = 0; ii < 4; ++ii) {
          const float* ap = (const float*)&aq[ii];
          float av = ap[kk];
#pragma unroll
          for (int jj = 0; jj < 8; ++jj) accA[ii][jj] += av * bb[jj];
        }
      }
    }
  }
  __syncthreads();
#pragma unroll
  for (int ii = 0; ii < 4; ++ii)
#pragma unroll
    for (int jj = 0; jj < 8; ++jj) sS[i0 + ii][j0 + jj] = accA[ii][jj];
  __syncthreads();

  // ---------------- phase C: linear readout ---------------------------------
  const int d0 = tx * 4;
  float accY[4][4];
#pragma unroll
  for (int ii = 0; ii < 4; ++ii)
#pragma unroll
    for (int jj = 0; jj < 4; ++jj) accY[ii][jj] = 0.f;

  for (int k = 0; k < KT; ++k) {
    float accD[4][4];
#pragma unroll
    for (int ii = 0; ii < 4; ++ii)
#pragma unroll
      for (int jj = 0; jj < 4; ++jj) accD[ii][jj] = 0.f;
    float lamip1[4], lami[4];
#pragma unroll
    for (int ii = 0; ii < 4; ++ii) {
      lamip1[ii] = pw[k][i0 + ii + 1];
      lami[ii]   = pw[k][i0 + ii];
      (void)lami[ii];
    }
    const size_t hb = ((size_t)((b * Hn + h) * KT + k) * NC + c) * 4096;
    // part 1: lam^(i+1) * (Q @ Hinit_k)
    for (int st = 0; st < 4; ++st) {
      const int r0 = st * 16;
      __syncthreads();
      {
        int kk = tid >> 4, dq = tid & 15;
        float4 v = *(const float4*)&Hinit[hb + (size_t)(r0 + kk) * 64 + dq * 4];
        *(float4*)&sB[kk][dq * 4] = v;
      }
      __syncthreads();
#pragma unroll
      for (int ks = 0; ks < 16; ks += 4) {
        float4 aq[4];
#pragma unroll
        for (int ii = 0; ii < 4; ++ii) {
          aq[ii] = *(const float4*)&sQ[i0 + ii][r0 + ks];
          aq[ii].x *= lamip1[ii]; aq[ii].y *= lamip1[ii];
          aq[ii].z *= lamip1[ii]; aq[ii].w *= lamip1[ii];
        }
#pragma unroll
        for (int kk = 0; kk < 4; ++kk) {
          float4 bv = *(const float4*)&sB[ks + kk][d0];
          float bb[4] = {bv.x, bv.y, bv.z, bv.w};
#pragma unroll
          for (int ii = 0; ii < 4; ++ii) {
            const float* ap = (const float*)&aq[ii];
            float av = ap[kk];
#pragma unroll
            for (int jj = 0; jj < 4; ++jj) accD[ii][jj] += av * bb[jj];
          }
        }
      }
    }
    // part 2: (W_k o P) @ Vc
    for (int st = 0; st < 4; ++st) {
      const int s0 = st * 16;
      __syncthreads();
      {
        int kk = tid >> 4, dq = tid & 15;
        float4 v = *(const float4*)&V_[((size_t)(b * Tn + c0 + s0 + kk) * Hn + h) * DH + dq * 4];
        *(float4*)&sB[kk][dq * 4] = v;
      }
      __syncthreads();
#pragma unroll
      for (int kk = 0; kk < 16; ++kk) {
        const int s = s0 + kk;
        const float c1 = gk[k][s];
        float4 bv = *(const float4*)&sB[kk][d0];
        float bb[4] = {bv.x, bv.y, bv.z, bv.w};
#pragma unroll
        for (int ii = 0; ii < 4; ++ii) {
          const int i = i0 + ii;
          float av = (s <= i) ? sS[i][64 + s] * c1 * pw[k][i - s] : 0.f;
#pragma unroll
          for (int jj = 0; jj < 4; ++jj) accD[ii][jj] += av * bb[jj];
        }
      }
    }
#pragma unroll
    for (int ii = 0; ii < 4; ++ii) {
      float inv = 1.f / (sz[k][i0 + ii] + EPS);
#pragma unroll
      for (int jj = 0; jj < 4; ++jj) accY[ii][jj] += accD[ii][jj] * inv;
    }
  }

  // ---------------- phase D: in-place masked ALiBi softmax on sS -----------
  __syncthreads();
  {
    const float slope = exp2f(-8.f * (float)(h + 1) / (float)Hn);
    for (int rr = 0; rr < 16; ++rr) {
      const int i = wave * 16 + rr;
      float s0v = sS[i][lane], s1v = sS[i][lane + 64];
      const int ja = lane, jb = lane + 64;
      bool va = (ja >= i + 1) && (c0 - 64 + ja >= 0);          // ja <= i+64 always (ja<64)
      bool vb2 = (jb >= i + 1) && (jb <= i + 64);
      s0v = va  ? s0v - slope * (float)(i + 64 - ja) : -1e30f;
      s1v = vb2 ? s1v - slope * (float)(i + 64 - jb) : -1e30f;
      float m = wred_max(fmaxf(s0v, s1v));
      float p0 = __expf(s0v - m), p1 = __expf(s1v - m);
      float inv = 1.f / wred_sum(p0 + p1);
      sS[i][lane] = p0 * inv;
      sS[i][lane + 64] = p1 * inv;
    }
  }

  // ---------------- phase E: yloc = A @ Vwin --------------------------------
  float accL[4][4];
#pragma unroll
  for (int ii = 0; ii < 4; ++ii)
#pragma unroll
    for (int jj = 0; jj < 4; ++jj) accL[ii][jj] = 0.f;
  for (int st = 0; st < 8; ++st) {
    __syncthreads();
    {
      int kk = tid >> 4, dq = tid & 15;
      int j = st * 16 + kk;
      int tg = c0 - 64 + j;
      float4 v = {0, 0, 0, 0};
      if (tg >= 0) v = *(const float4*)&V_[((size_t)(b * Tn + tg) * Hn + h) * DH + dq * 4];
      *(float4*)&sB[kk][dq * 4] = v;
    }
    __syncthreads();
#pragma unroll
    for (int kk = 0; kk < 16; ++kk) {
      const int j = st * 16 + kk;
      float4 bv = *(const float4*)&sB[kk][d0];
      float bb[4] = {bv.x, bv.y, bv.z, bv.w};
#pragma unroll
      for (int ii = 0; ii < 4; ++ii) {
        float av = sS[i0 + ii][j];
#pragma unroll
        for (int jj = 0; jj < 4; ++jj) accL[ii][jj] += av * bb[jj];
      }
    }
  }

  // ---------------- phase F: combine + write --------------------------------
#pragma unroll
  for (int ii = 0; ii < 4; ++ii) {
    const int tt = c0 + i0 + ii;
    float av = alpha[((size_t)(b * Tn + tt)) * Hn + h];
    float4 o;
    o.x = av * accL[ii][0] + (1.f - av) * accY[ii][0];
    o.y = av * accL[ii][1] + (1.f - av) * accY[ii][1];
    o.z = av * accL[ii][2] + (1.f - av) * accY[ii][2];
    o.w = av * accL[ii][3] + (1.f - av) * accY[ii][3];
    *(float4*)&ypre[((size_t)(b * Tn + tt) * Hn + h) * DH + d0] = o;
  }
}

// ---------------------------------------------------------------------------
// out = LayerNorm(x + proj) * gamma + beta
// ---------------------------------------------------------------------------
__global__ __launch_bounds__(256) void ln_kernel(const float* __restrict__ x,
                                                 const float* __restrict__ proj,
                                                 const float* __restrict__ gamma,
                                                 const float* __restrict__ beta,
                                                 float* __restrict__ out) {
  const int row = blockIdx.x;
  const int tid = threadIdx.x;
  const int wave = tid >> 6, lane = tid & 63;
  const size_t base = (size_t)row * Dn;
  __shared__ float red[8];
  float r0 = x[base + tid] + proj[base + tid];
  float r1 = x[base + tid + 256] + proj[base + tid + 256];
  float s = wred_sum(r0 + r1);
  if (lane == 0) red[wave] = s;
  __syncthreads();
  float mu = (red[0] + red[1] + red[2] + red[3]) * (1.f / (float)Dn);
  float d0 = r0 - mu, d1 = r1 - mu;
  float q = wred_sum(d0 * d0 + d1 * d1);
  if (lane == 0) red[4 + wave] = q;
  __syncthreads();
  float var = (red[4] + red[5] + red[6] + red[7]) * (1.f / (float)Dn);
  float inv = rsqrtf(var + LN_EPS);
  out[base + tid]       = d0 * inv * gamma[tid]       + beta[tid];
  out[base + tid + 256] = d1 * inv * gamma[tid + 256] + beta[tid + 256];
}

// ---------------------------------------------------------------------------
extern "C" void kernel_launch(void* const* d_in, const int* in_sizes, int n_in,
                              void* d_out, int out_size, void* d_ws, size_t ws_size,
                              hipStream_t stream) {
  const float* x     = (const float*)d_in[0];
  const float* Wq    = (const float*)d_in[1];
  const float* Wk    = (const float*)d_in[2];
  const float* Wv    = (const float*)d_in[3];
  const float* Wg    = (const float*)d_in[4];
  const float* bg    = (const float*)d_in[5];
  const float* Wa    = (const float*)d_in[6];
  const float* ba    = (const float*)d_in[7];
  const float* Wo    = (const float*)d_in[8];
  const float* bo    = (const float*)d_in[9];
  const float* decay = (const float*)d_in[10];
  const float* gamma = (const float*)d_in[11];
  const float* beta  = (const float*)d_in[12];
  float* out = (float*)d_out;

  const size_t NTOK = (size_t)Bn * Tn;
  const size_t NEL  = NTOK * Dn;
  float* ws = (float*)d_ws;
  float* qb    = ws;              ws += NEL;
  float* kb    = ws;              ws += NEL;
  float* vb    = ws;              ws += NEL;
  float* gateb = ws;              ws += NTOK * Hn * KT;
  float* alphb = ws;              ws += NTOK * Hn;
  float* Sb    = ws;              ws += (size_t)Bn * Hn * KT * NC * 4096;
  float* Zcb   = ws;              ws += (size_t)Bn * Hn * KT * NC;
  float* Hib   = ws;              ws += (size_t)Bn * Hn * KT * NC * 4096;
  float* Zib   = ws;              ws += (size_t)Bn * Hn * KT * NC;
  float* ypre  = ws;              ws += NEL;
  float* proj  = ws;              ws += NEL;

  const int M = (int)NTOK, N = Dn, Kd = Dn;
  dim3 ggrid(N / 64, M / 64);

  gemm_bt<<<ggrid, 256, 0, stream>>>(x, Wq, nullptr, qb, M, N, Kd);
  gemm_bt<<<ggrid, 256, 0, stream>>>(x, Wk, nullptr, kb, M, N, Kd);
  gemm_bt<<<ggrid, 256, 0, stream>>>(x, Wv, nullptr, vb, M, N, Kd);
  gate_alpha<<<(int)NTOK, 256, 0, stream>>>(x, Wg, bg, Wa, ba, gateb, alphb);

  chunk_sums<<<(Bn * Hn * KT * NC * 64) / 256, 256, 0, stream>>>(kb, vb, gateb, decay, Sb, Zcb);
  scan_chunks<<<Bn * Hn * KT, 256, 0, stream>>>(Sb, Zcb, decay, Hib, Zib);

  attn_chunk<<<dim3(NC, Hn, Bn), 256, 0, stream>>>(qb, kb, vb, gateb, alphb,
                                                   decay, Hib, Zib, ypre);

  gemm_bt<<<ggrid, 256, 0, stream>>>(ypre, Wo, bo, proj, M, N, Kd);
  ln_kernel<<<(int)NTOK, 256, 0, stream>>>(x, proj, gamma, beta, out);
}

// Round 3
// 312.802 us; speedup vs baseline: 2.7461x; 1.3732x over previous
//
#include <hip/hip_runtime.h>
#include <math.h>

#define EPS 1e-6f
#define LN_EPS 1e-5f

static constexpr int Bn = 2, Tn = 2048, Dn = 512, Hn = 8, KT = 2, DH = 64, NC = Tn / 64;
static constexpr int QS = 1536;  // fused qkv row stride (fp32 cols: q|k|v)

typedef __bf16 bfrag8 __attribute__((ext_vector_type(8)));
typedef float ffrag4 __attribute__((ext_vector_type(4)));

__device__ __forceinline__ float wred_sum(float v) {
#pragma unroll
  for (int o = 32; o > 0; o >>= 1) v += __shfl_xor(v, o, 64);
  return v;
}
__device__ __forceinline__ float wred_max(float v) {
#pragma unroll
  for (int o = 32; o > 0; o >>= 1) v = fmaxf(v, __shfl_xor(v, o, 64));
  return v;
}
__device__ __forceinline__ float sigmoidf_(float v) { return 1.0f / (1.0f + expf(-v)); }
__device__ __forceinline__ unsigned short f2bf(float f) {
  unsigned u = __builtin_bit_cast(unsigned, f);
  return (unsigned short)((u + 0x7FFFu + ((u >> 16) & 1u)) >> 16);
}

// ---------------------------------------------------------------------------
// fp32 -> bf16 conversion: x (2M), Wq/Wk/Wv -> Wc (contig [1536][512]), Wo->Wob
// float4-granular; grid covers 786432 float4s exactly.
// ---------------------------------------------------------------------------
__global__ __launch_bounds__(256) void conv_bf16(const float* __restrict__ x,
                                                 const float* __restrict__ Wq,
                                                 const float* __restrict__ Wk,
                                                 const float* __restrict__ Wv,
                                                 const float* __restrict__ Wo,
                                                 unsigned short* __restrict__ xb,
                                                 unsigned short* __restrict__ Wc,
                                                 unsigned short* __restrict__ Wob) {
  int idx = blockIdx.x * 256 + threadIdx.x;  // float4 index
  const float* src;
  unsigned short* dst;
  int off;
  if (idx < 524288)      { src = x;  dst = xb;           off = idx; }
  else if (idx < 589824) { src = Wq; dst = Wc;           off = idx - 524288; }
  else if (idx < 655360) { src = Wk; dst = Wc + 262144;  off = idx - 589824; }
  else if (idx < 720896) { src = Wv; dst = Wc + 524288;  off = idx - 655360; }
  else                   { src = Wo; dst = Wob;          off = idx - 720896; }
  float4 v = *(const float4*)&src[(size_t)off * 4];
  ushort4 o;
  o.x = f2bf(v.x); o.y = f2bf(v.y); o.z = f2bf(v.z); o.w = f2bf(v.w);
  *(ushort4*)&dst[(size_t)off * 4] = o;
}

// ---------------------------------------------------------------------------
// bf16 MFMA GEMM: C[M,N](fp32) = A[M,Kd](bf16) @ W[N,Kd](bf16)^T (+bias)
// 128x128 tile, BK=32, 4 waves x (4x4) 16x16x32 MFMA tiles.
// LDS in fragment order: frag(mtile,lane) at [(mtile*64+lane)*8] -> every
// ds_read_b128 is lane-sequential (conflict-free).
// ---------------------------------------------------------------------------
__global__ __launch_bounds__(256) void gemm_mfma(const unsigned short* __restrict__ A,
                                                 const unsigned short* __restrict__ W,
                                                 const float* __restrict__ bias,
                                                 float* __restrict__ C,
                                                 int N, int Kd) {
  __shared__ unsigned short As[4096];  // 8 mtiles * 64 lanes * 8 bf16
  __shared__ unsigned short Bs[4096];
  const int tid = threadIdx.x;
  const int lane = tid & 63, wave = tid >> 6;
  const int m0 = blockIdx.y * 128, n0 = blockIdx.x * 128;
  const int mo16 = (wave >> 1) * 4;  // 16-row tile index base (0 or 4)
  const int no16 = (wave & 1) * 4;

  ffrag4 acc[4][4];
#pragma unroll
  for (int i = 0; i < 4; ++i)
#pragma unroll
    for (int j = 0; j < 4; ++j) acc[i][j] = (ffrag4){0.f, 0.f, 0.f, 0.f};

  // precompute staging indices
  for (int k0 = 0; k0 < Kd; k0 += 32) {
    __syncthreads();
#pragma unroll
    for (int u = 0; u < 2; ++u) {
      int f = tid + u * 256;
      int mtile = f >> 6, li = f & 63;
      int row = mtile * 16 + (li & 15), colq = (li >> 4) * 8;
      uint4 va = *(const uint4*)&A[(size_t)(m0 + row) * Kd + k0 + colq];
      uint4 vb = *(const uint4*)&W[(size_t)(n0 + row) * Kd + k0 + colq];
      *(uint4*)&As[f * 8] = va;
      *(uint4*)&Bs[f * 8] = vb;
    }
    __syncthreads();
    bfrag8 af[4], bf_[4];
#pragma unroll
    for (int mt = 0; mt < 4; ++mt)
      af[mt] = __builtin_bit_cast(bfrag8, *(const uint4*)&As[((mo16 + mt) * 64 + lane) * 8]);
#pragma unroll
    for (int nt = 0; nt < 4; ++nt)
      bf_[nt] = __builtin_bit_cast(bfrag8, *(const uint4*)&Bs[((no16 + nt) * 64 + lane) * 8]);
#pragma unroll
    for (int mt = 0; mt < 4; ++mt)
#pragma unroll
      for (int nt = 0; nt < 4; ++nt)
        acc[mt][nt] = __builtin_amdgcn_mfma_f32_16x16x32_bf16(af[mt], bf_[nt], acc[mt][nt], 0, 0, 0);
  }

  const int quad = lane >> 4, l15 = lane & 15;
#pragma unroll
  for (int nt = 0; nt < 4; ++nt) {
    int col = n0 + (no16 + nt) * 16 + l15;
    float bb = bias ? bias[col] : 0.f;
#pragma unroll
    for (int mt = 0; mt < 4; ++mt) {
#pragma unroll
      for (int r = 0; r < 4; ++r) {
        int row = m0 + (mo16 + mt) * 16 + quad * 4 + r;
        C[(size_t)row * N + col] = acc[mt][nt][r] + bb;
      }
    }
  }
}

// ---------------------------------------------------------------------------
// gate/alpha projections + sigmoid
// ---------------------------------------------------------------------------
__global__ __launch_bounds__(256) void gate_alpha(const float* __restrict__ x,
                                                  const float* __restrict__ Wg,
                                                  const float* __restrict__ bg,
                                                  const float* __restrict__ Wa,
                                                  const float* __restrict__ ba,
                                                  float* __restrict__ gate,
                                                  float* __restrict__ alpha) {
  const int row = blockIdx.x;
  const int wave = threadIdx.x >> 6, lane = threadIdx.x & 63;
  const float* xr = x + (size_t)row * Dn;
  for (int o = wave * 6; o < wave * 6 + 6; ++o) {
    const float* wrow;
    float bv;
    if (o < Hn * KT) { wrow = Wg + (size_t)o * Dn; bv = bg[o]; }
    else             { wrow = Wa + (size_t)(o - Hn * KT) * Dn; bv = ba[o - Hn * KT]; }
    float p = 0.f;
#pragma unroll
    for (int rr = 0; rr < 8; ++rr) p += xr[lane + 64 * rr] * wrow[lane + 64 * rr];
    p = wred_sum(p);
    if (lane == 0) {
      float s = sigmoidf_(p + bv);
      if (o < Hn * KT) gate[(size_t)row * (Hn * KT) + o] = s;
      else             alpha[(size_t)row * Hn + (o - Hn * KT)] = s;
    }
  }
}

// ---------------------------------------------------------------------------
// Per (b,h,k,chunk) wave: S = sum_t lam^{63-t} g_t k_t v_t^T  [64x64], z scalar
// K_/V_ point into fused qkv buffer (row stride QS)
// ---------------------------------------------------------------------------
__global__ __launch_bounds__(256) void chunk_sums(const float* __restrict__ K_,
                                                  const float* __restrict__ V_,
                                                  const float* __restrict__ gate,
                                                  const float* __restrict__ decay,
                                                  float* __restrict__ S,
                                                  float* __restrict__ Zc) {
  const int gw = (blockIdx.x * blockDim.x + threadIdx.x) >> 6;
  const int lane = threadIdx.x & 63;
  int c = gw % NC, tmp = gw / NC;
  int k = tmp % KT; tmp /= KT;
  int h = tmp % Hn, b = tmp / Hn;
  const float lam = sigmoidf_(decay[h * KT + k]);
  float acc[64];
#pragma unroll
  for (int i = 0; i < 64; ++i) acc[i] = 0.f;
  float z = 0.f, lampow = 1.f;
  for (int t = 63; t >= 0; --t) {
    int tg = c * 64 + t;
    size_t base = (size_t)(b * Tn + tg) * QS + h * DH;
    float kv = K_[base + lane];
    float vv = V_[base + lane];
    float gv = gate[((size_t)(b * Tn + tg) * Hn + h) * KT + k];
    float coef = gv * lampow;
    float asum = wred_sum(fabsf(kv));
    z += coef * (asum * (1.f / 64.f) + EPS);
    float ck = coef * kv;
#pragma unroll
    for (int i = 0; i < 64; ++i) acc[i] += __shfl(ck, i, 64) * vv;
    lampow *= lam;
  }
  size_t sb = (size_t)gw * 4096;
#pragma unroll
  for (int i = 0; i < 64; ++i) S[sb + i * 64 + lane] = acc[i];
  if (lane == 0) Zc[gw] = z;
}

// ---------------------------------------------------------------------------
// Serial scan over chunks, widened: grid (32 bhk, 8 slices of 512 floats).
// z-scan: 32-lane Kogge-Stone decay scan in slice 0.
// ---------------------------------------------------------------------------
__global__ __launch_bounds__(256) void scan_chunks(const float* __restrict__ S,
                                                   const float* __restrict__ Zc,
                                                   const float* __restrict__ decay,
                                                   float* __restrict__ Hinit,
                                                   float* __restrict__ Zinit) {
  const int bhk = blockIdx.x, slice = blockIdx.y;
  const int k = bhk % KT, h = (bhk / KT) % Hn;
  const float lam = sigmoidf_(decay[h * KT + k]);
  const float lam64 = powf(lam, 64.f);
  const int tid = threadIdx.x;
  const size_t base = (size_t)bhk * NC * 4096 + (size_t)slice * 512 + (size_t)tid * 2;
  float2 st = {0.f, 0.f};
#pragma unroll 2
  for (int c = 0; c < NC; ++c) {
    size_t off = base + (size_t)c * 4096;
    *(float2*)&Hinit[off] = st;
    float2 sv = *(const float2*)&S[off];
    st.x = lam64 * st.x + sv.x;
    st.y = lam64 * st.y + sv.y;
  }
  if (slice == 0 && tid < 64) {
    float v = (tid < NC) ? Zc[bhk * NC + tid] : 0.f;
    float lp = lam64;
#pragma unroll
    for (int o = 1; o < 32; o <<= 1) {
      float t2 = __shfl_up(v, o, 64);
      if (tid >= o) v += lp * t2;
      lp *= lp;
    }
    float prev = __shfl_up(v, 1, 64);
    if (tid < NC) Zinit[bhk * NC + tid] = (tid == 0) ? 0.f : prev;
  }
}

// ---------------------------------------------------------------------------
// Block per (b,h,c): chunked attention (unchanged math; qkv stride QS, bf16 out)
// ---------------------------------------------------------------------------
__global__ __launch_bounds__(256) void attn_chunk(const float* __restrict__ Q_,
                                                  const float* __restrict__ K_,
                                                  const float* __restrict__ V_,
                                                  const float* __restrict__ gate,
                                                  const float* __restrict__ alpha,
                                                  const float* __restrict__ decay,
                                                  const float* __restrict__ Hinit,
                                                  const float* __restrict__ Zinit,
                                                  unsigned short* __restrict__ ypre) {
  __shared__ float sS[64][129];
  __shared__ float sQ[64][68];
  __shared__ float sB[16][132];
  __shared__ float sval_s[64];
  __shared__ float gk[KT][64];
  __shared__ float sz[KT][64];
  __shared__ float pw[KT][65];
  __shared__ float zin[KT];

  const int c = blockIdx.x, h = blockIdx.y, b = blockIdx.z;
  const int c0 = c * 64;
  const int tid = threadIdx.x;
  const int tx = tid & 15, ty = tid >> 4;
  const int i0 = ty * 4;
  const int wave = tid >> 6, lane = tid & 63;

#pragma unroll
  for (int u = 0; u < 4; ++u) {
    int idx = tid + 256 * u;
    int fi = idx >> 4, fc = idx & 15;
    float4 v = *(const float4*)&Q_[(size_t)(b * Tn + c0 + fi) * QS + h * DH + fc * 4];
    *(float4*)&sQ[fi][fc * 4] = v;
  }
  {
    int s = tid >> 2, qq = tid & 3;
    const float* kr = K_ + (size_t)(b * Tn + c0 + s) * QS + h * DH + qq * 16;
    float acc = 0.f;
#pragma unroll
    for (int u = 0; u < 4; ++u) {
      float4 v = *(const float4*)(kr + u * 4);
      acc += fabsf(v.x) + fabsf(v.y) + fabsf(v.z) + fabsf(v.w);
    }
    ((float*)sB)[tid] = acc;
  }
  if (tid < 128) {
    int s = tid >> 1, k2 = tid & 1;
    gk[k2][s] = gate[((size_t)(b * Tn + c0 + s) * Hn + h) * KT + k2];
  }
  if (tid < 128) {
    int k2 = tid >> 6, d = tid & 63;
    float lamv = sigmoidf_(decay[h * KT + k2]);
    pw[k2][d] = powf(lamv, (float)d);
  }
  if (tid < 2) {
    float lamv = sigmoidf_(decay[h * KT + tid]);
    pw[tid][64] = powf(lamv, 64.f);
    zin[tid] = Zinit[((size_t)((b * Hn + h) * KT + tid)) * NC + c];
  }
  __syncthreads();
  if (tid < 64) {
    const float* f = (const float*)sB;
    sval_s[tid] = (f[tid * 4] + f[tid * 4 + 1] + f[tid * 4 + 2] + f[tid * 4 + 3]) * (1.f / 64.f) + EPS;
  }
  __syncthreads();
  if (wave < 2) {
    const int kx = wave;
    float v = gk[kx][lane] * sval_s[lane];
#pragma unroll
    for (int o = 1; o < 64; o <<= 1) {
      float t2 = __shfl_up(v, o, 64);
      if (lane >= o) v += pw[kx][o] * t2;
    }
    sz[kx][lane] = v + pw[kx][lane + 1] * zin[kx];
  }

  // phase A: sS = Qc @ Kwin^T
  float accA[4][8];
#pragma unroll
  for (int ii = 0; ii < 4; ++ii)
#pragma unroll
    for (int jj = 0; jj < 8; ++jj) accA[ii][jj] = 0.f;
  const int j0 = tx * 8;
  for (int k0 = 0; k0 < 64; k0 += 16) {
    __syncthreads();
    {
      int j = tid & 127, half = tid >> 7;
      int tg = c0 - 64 + j;
      float4 v0 = {0, 0, 0, 0}, v1 = {0, 0, 0, 0};
      if (tg >= 0) {
        const float* kr = K_ + (size_t)(b * Tn + tg) * QS + h * DH + k0 + half * 8;
        v0 = *(const float4*)kr;
        v1 = *(const float4*)(kr + 4);
      }
      int kk0 = half * 8;
      sB[kk0 + 0][j] = v0.x; sB[kk0 + 1][j] = v0.y; sB[kk0 + 2][j] = v0.z; sB[kk0 + 3][j] = v0.w;
      sB[kk0 + 4][j] = v1.x; sB[kk0 + 5][j] = v1.y; sB[kk0 + 6][j] = v1.z; sB[kk0 + 7][j] = v1.w;
    }
    __syncthreads();
#pragma unroll
    for (int ks = 0; ks < 16; ks += 4) {
      float4 aq[4];
#pragma unroll
      for (int ii = 0; ii < 4; ++ii) aq[ii] = *(const float4*)&sQ[i0 + ii][k0 + ks];
#pragma unroll
      for (int kk = 0; kk < 4; ++kk) {
        float4 b0 = *(const float4*)&sB[ks + kk][j0];
        float4 b1 = *(const float4*)&sB[ks + kk][j0 + 4];
        float bb[8] = {b0.x, b0.y, b0.z, b0.w, b1.x, b1.y, b1.z, b1.w};
#pragma unroll
        for (int ii = 0; ii < 4; ++ii) {
          const float* ap = (const float*)&aq[ii];
          float av = ap[kk];
#pragma unroll
          for (int jj = 0; jj < 8; ++jj) accA[ii][jj] += av * bb[jj];
        }
      }
    }
  }
  __syncthreads();
#pragma unroll
  for (int ii = 0; ii < 4; ++ii)
#pragma unroll
    for (int jj = 0; jj < 8; ++jj) sS[i0 + ii][j0 + jj] = accA[ii][jj];
  __syncthreads();

  // phase C: linear readout
  const int d0 = tx * 4;
  float accY[4][4];
#pragma unroll
  for (int ii = 0; ii < 4; ++ii)
#pragma unroll
    for (int jj = 0; jj < 4; ++jj) accY[ii][jj] = 0.f;

  for (int k = 0; k < KT; ++k) {
    float accD[4][4];
#pragma unroll
    for (int ii = 0; ii < 4; ++ii)
#pragma unroll
      for (int jj = 0; jj < 4; ++jj) accD[ii][jj] = 0.f;
    float lamip1[4];
#pragma unroll
    for (int ii = 0; ii < 4; ++ii) lamip1[ii] = pw[k][i0 + ii + 1];
    const size_t hb = ((size_t)((b * Hn + h) * KT + k) * NC + c) * 4096;
    for (int st = 0; st < 4; ++st) {
      const int r0 = st * 16;
      __syncthreads();
      {
        int kk = tid >> 4, dq = tid & 15;
        float4 v = *(const float4*)&Hinit[hb + (size_t)(r0 + kk) * 64 + dq * 4];
        *(float4*)&sB[kk][dq * 4] = v;
      }
      __syncthreads();
#pragma unroll
      for (int ks = 0; ks < 16; ks += 4) {
        float4 aq[4];
#pragma unroll
        for (int ii = 0; ii < 4; ++ii) {
          aq[ii] = *(const float4*)&sQ[i0 + ii][r0 + ks];
          aq[ii].x *= lamip1[ii]; aq[ii].y *= lamip1[ii];
          aq[ii].z *= lamip1[ii]; aq[ii].w *= lamip1[ii];
        }
#pragma unroll
        for (int kk = 0; kk < 4; ++kk) {
          float4 bv = *(const float4*)&sB[ks + kk][d0];
          float bb[4] = {bv.x, bv.y, bv.z, bv.w};
#pragma unroll
          for (int ii = 0; ii < 4; ++ii) {
            const float* ap = (const float*)&aq[ii];
            float av = ap[kk];
#pragma unroll
            for (int jj = 0; jj < 4; ++jj) accD[ii][jj] += av * bb[jj];
          }
        }
      }
    }
    for (int st = 0; st < 4; ++st) {
      const int s0 = st * 16;
      __syncthreads();
      {
        int kk = tid >> 4, dq = tid & 15;
        float4 v = *(const float4*)&V_[(size_t)(b * Tn + c0 + s0 + kk) * QS + h * DH + dq * 4];
        *(float4*)&sB[kk][dq * 4] = v;
      }
      __syncthreads();
#pragma unroll
      for (int kk = 0; kk < 16; ++kk) {
        const int s = s0 + kk;
        const float c1 = gk[k][s];
        float4 bv = *(const float4*)&sB[kk][d0];
        float bb[4] = {bv.x, bv.y, bv.z, bv.w};
#pragma unroll
        for (int ii = 0; ii < 4; ++ii) {
          const int i = i0 + ii;
          float av = (s <= i) ? sS[i][64 + s] * c1 * pw[k][i - s] : 0.f;
#pragma unroll
          for (int jj = 0; jj < 4; ++jj) accD[ii][jj] += av * bb[jj];
        }
      }
    }
#pragma unroll
    for (int ii = 0; ii < 4; ++ii) {
      float inv = 1.f / (sz[k][i0 + ii] + EPS);
#pragma unroll
      for (int jj = 0; jj < 4; ++jj) accY[ii][jj] += accD[ii][jj] * inv;
    }
  }

  // phase D: softmax
  __syncthreads();
  {
    const float slope = exp2f(-8.f * (float)(h + 1) / (float)Hn);
    for (int rr = 0; rr < 16; ++rr) {
      const int i = wave * 16 + rr;
      float s0v = sS[i][lane], s1v = sS[i][lane + 64];
      const int ja = lane, jb = lane + 64;
      bool va = (ja >= i + 1) && (c0 - 64 + ja >= 0);
      bool vb2 = (jb >= i + 1) && (jb <= i + 64);
      s0v = va  ? s0v - slope * (float)(i + 64 - ja) : -1e30f;
      s1v = vb2 ? s1v - slope * (float)(i + 64 - jb) : -1e30f;
      float m = wred_max(fmaxf(s0v, s1v));
      float p0 = __expf(s0v - m), p1 = __expf(s1v - m);
      float inv = 1.f / wred_sum(p0 + p1);
      sS[i][lane] = p0 * inv;
      sS[i][lane + 64] = p1 * inv;
    }
  }

  // phase E: yloc = A @ Vwin
  float accL[4][4];
#pragma unroll
  for (int ii = 0; ii < 4; ++ii)
#pragma unroll
    for (int jj = 0; jj < 4; ++jj) accL[ii][jj] = 0.f;
  for (int st = 0; st < 8; ++st) {
    __syncthreads();
    {
      int kk = tid >> 4, dq = tid & 15;
      int j = st * 16 + kk;
      int tg = c0 - 64 + j;
      float4 v = {0, 0, 0, 0};
      if (tg >= 0) v = *(const float4*)&V_[(size_t)(b * Tn + tg) * QS + h * DH + dq * 4];
      *(float4*)&sB[kk][dq * 4] = v;
    }
    __syncthreads();
#pragma unroll
    for (int kk = 0; kk < 16; ++kk) {
      const int j = st * 16 + kk;
      float4 bv = *(const float4*)&sB[kk][d0];
      float bb[4] = {bv.x, bv.y, bv.z, bv.w};
#pragma unroll
      for (int ii = 0; ii < 4; ++ii) {
        float av = sS[i0 + ii][j];
#pragma unroll
        for (int jj = 0; jj < 4; ++jj) accL[ii][jj] += av * bb[jj];
      }
    }
  }

  // phase F: combine + bf16 write
#pragma unroll
  for (int ii = 0; ii < 4; ++ii) {
    const int tt = c0 + i0 + ii;
    float av = alpha[((size_t)(b * Tn + tt)) * Hn + h];
    ushort4 o;
    o.x = f2bf(av * accL[ii][0] + (1.f - av) * accY[ii][0]);
    o.y = f2bf(av * accL[ii][1] + (1.f - av) * accY[ii][1]);
    o.z = f2bf(av * accL[ii][2] + (1.f - av) * accY[ii][2]);
    o.w = f2bf(av * accL[ii][3] + (1.f - av) * accY[ii][3]);
    *(ushort4*)&ypre[(size_t)(b * Tn + tt) * Dn + h * DH + d0] = o;
  }
}

// ---------------------------------------------------------------------------
// out = LayerNorm(x + proj) * gamma + beta
// ---------------------------------------------------------------------------
__global__ __launch_bounds__(256) void ln_kernel(const float* __restrict__ x,
                                                 const float* __restrict__ proj,
                                                 const float* __restrict__ gamma,
                                                 const float* __restrict__ beta,
                                                 float* __restrict__ out) {
  const int row = blockIdx.x;
  const int tid = threadIdx.x;
  const int wave = tid >> 6, lane = tid & 63;
  const size_t base = (size_t)row * Dn;
  __shared__ float red[8];
  float r0 = x[base + tid] + proj[base + tid];
  float r1 = x[base + tid + 256] + proj[base + tid + 256];
  float s = wred_sum(r0 + r1);
  if (lane == 0) red[wave] = s;
  __syncthreads();
  float mu = (red[0] + red[1] + red[2] + red[3]) * (1.f / (float)Dn);
  float d0 = r0 - mu, d1 = r1 - mu;
  float q = wred_sum(d0 * d0 + d1 * d1);
  if (lane == 0) red[4 + wave] = q;
  __syncthreads();
  float var = (red[4] + red[5] + red[6] + red[7]) * (1.f / (float)Dn);
  float inv = rsqrtf(var + LN_EPS);
  out[base + tid]       = d0 * inv * gamma[tid]       + beta[tid];
  out[base + tid + 256] = d1 * inv * gamma[tid + 256] + beta[tid + 256];
}

// ---------------------------------------------------------------------------
extern "C" void kernel_launch(void* const* d_in, const int* in_sizes, int n_in,
                              void* d_out, int out_size, void* d_ws, size_t ws_size,
                              hipStream_t stream) {
  const float* x     = (const float*)d_in[0];
  const float* Wq    = (const float*)d_in[1];
  const float* Wk    = (const float*)d_in[2];
  const float* Wv    = (const float*)d_in[3];
  const float* Wg    = (const float*)d_in[4];
  const float* bg    = (const float*)d_in[5];
  const float* Wa    = (const float*)d_in[6];
  const float* ba    = (const float*)d_in[7];
  const float* Wo    = (const float*)d_in[8];
  const float* bo    = (const float*)d_in[9];
  const float* decay = (const float*)d_in[10];
  const float* gamma = (const float*)d_in[11];
  const float* beta  = (const float*)d_in[12];
  float* out = (float*)d_out;

  const size_t NTOK = (size_t)Bn * Tn;  // 4096
  float* ws = (float*)d_ws;
  float* qkv  = ws; ws += NTOK * QS;                          // 6291456 f
  float* Sb   = ws; ws += (size_t)Bn * Hn * KT * NC * 4096;   // 4194304 f
  float* Hib  = ws; ws += (size_t)Bn * Hn * KT * NC * 4096;   // 4194304 f
  float* gateb = ws; ws += NTOK * Hn * KT;
  float* alphb = ws; ws += NTOK * Hn;
  float* Zcb  = ws; ws += (size_t)Bn * Hn * KT * NC;
  float* Zib  = ws; ws += (size_t)Bn * Hn * KT * NC;
  unsigned short* us = (unsigned short*)ws;
  unsigned short* xb  = us; us += NTOK * Dn;        // bf16 x
  unsigned short* Wc  = us; us += (size_t)3 * Dn * Dn;  // bf16 [Wq;Wk;Wv]
  unsigned short* Wob = us; us += (size_t)Dn * Dn;
  unsigned short* ypre = us; us += NTOK * Dn;
  float* proj = Sb;  // alias: Sb dead after scan_chunks, proj written later

  const float* qb = qkv;
  const float* kb = qkv + 512;
  const float* vb = qkv + 1024;

  conv_bf16<<<3072, 256, 0, stream>>>(x, Wq, Wk, Wv, Wo, xb, Wc, Wob);

  gemm_mfma<<<dim3(QS / 128, (int)NTOK / 128), 256, 0, stream>>>(xb, Wc, nullptr, qkv, QS, Dn);

  gate_alpha<<<(int)NTOK, 256, 0, stream>>>(x, Wg, bg, Wa, ba, gateb, alphb);

  chunk_sums<<<(Bn * Hn * KT * NC * 64) / 256, 256, 0, stream>>>(kb, vb, gateb, decay, Sb, Zcb);
  scan_chunks<<<dim3(Bn * Hn * KT, 8), 256, 0, stream>>>(Sb, Zcb, decay, Hib, Zib);

  attn_chunk<<<dim3(NC, Hn, Bn), 256, 0, stream>>>(qb, kb, vb, gateb, alphb,
                                                   decay, Hib, Zib, ypre);

  gemm_mfma<<<dim3(Dn / 128, (int)NTOK / 128), 256, 0, stream>>>(ypre, Wob, bo, proj, Dn, Dn);
  ln_kernel<<<(int)NTOK, 256, 0, stream>>>(x, proj, gamma, beta, out);
}

// Round 4
// 262.277 us; speedup vs baseline: 3.2751x; 1.1926x over previous
//
#include <hip/hip_runtime.h>
#include <math.h>

#define EPS 1e-6f
#define LN_EPS 1e-5f

static constexpr int Bn = 2, Tn = 2048, Dn = 512, Hn = 8, KT = 2, DH = 64, NC = Tn / 64;
static constexpr int QS = 1536;  // fused qkv row stride (cols: q|k|v)

typedef __bf16 bfrag8 __attribute__((ext_vector_type(8)));
typedef float ffrag4 __attribute__((ext_vector_type(4)));
typedef unsigned short us8v __attribute__((ext_vector_type(8)));

__device__ __forceinline__ float wred_sum(float v) {
#pragma unroll
  for (int o = 32; o > 0; o >>= 1) v += __shfl_xor(v, o, 64);
  return v;
}
__device__ __forceinline__ float wred_max(float v) {
#pragma unroll
  for (int o = 32; o > 0; o >>= 1) v = fmaxf(v, __shfl_xor(v, o, 64));
  return v;
}
__device__ __forceinline__ float sigmoidf_(float v) { return 1.0f / (1.0f + expf(-v)); }
__device__ __forceinline__ unsigned short f2bf(float f) {
  unsigned u = __builtin_bit_cast(unsigned, f);
  return (unsigned short)((u + 0x7FFFu + ((u >> 16) & 1u)) >> 16);
}

// ---------------------------------------------------------------------------
// fp32 -> bf16 conversion: x, Wq/Wk/Wv -> Wc (contig [1536][512]), Wo->Wob
// ---------------------------------------------------------------------------
__global__ __launch_bounds__(256) void conv_bf16(const float* __restrict__ x,
                                                 const float* __restrict__ Wq,
                                                 const float* __restrict__ Wk,
                                                 const float* __restrict__ Wv,
                                                 const float* __restrict__ Wo,
                                                 unsigned short* __restrict__ xb,
                                                 unsigned short* __restrict__ Wc,
                                                 unsigned short* __restrict__ Wob) {
  int idx = blockIdx.x * 256 + threadIdx.x;  // float4 index
  const float* src;
  unsigned short* dst;
  int off;
  if (idx < 524288)      { src = x;  dst = xb;           off = idx; }
  else if (idx < 589824) { src = Wq; dst = Wc;           off = idx - 524288; }
  else if (idx < 655360) { src = Wk; dst = Wc + 262144;  off = idx - 589824; }
  else if (idx < 720896) { src = Wv; dst = Wc + 524288;  off = idx - 655360; }
  else                   { src = Wo; dst = Wob;          off = idx - 720896; }
  float4 v = *(const float4*)&src[(size_t)off * 4];
  ushort4 o;
  o.x = f2bf(v.x); o.y = f2bf(v.y); o.z = f2bf(v.z); o.w = f2bf(v.w);
  *(ushort4*)&dst[(size_t)off * 4] = o;
}

// ---------------------------------------------------------------------------
// bf16 MFMA GEMM: C[M,N](fp32) = A[M,Kd](bf16) @ W[N,Kd](bf16)^T (+bias)
// optional bf16 copy of C into Cb.
// ---------------------------------------------------------------------------
__global__ __launch_bounds__(256) void gemm_mfma(const unsigned short* __restrict__ A,
                                                 const unsigned short* __restrict__ W,
                                                 const float* __restrict__ bias,
                                                 float* __restrict__ C,
                                                 unsigned short* __restrict__ Cb,
                                                 int N, int Kd) {
  __shared__ unsigned short As[4096];
  __shared__ unsigned short Bs[4096];
  const int tid = threadIdx.x;
  const int lane = tid & 63, wave = tid >> 6;
  const int m0 = blockIdx.y * 128, n0 = blockIdx.x * 128;
  const int mo16 = (wave >> 1) * 4;
  const int no16 = (wave & 1) * 4;

  ffrag4 acc[4][4];
#pragma unroll
  for (int i = 0; i < 4; ++i)
#pragma unroll
    for (int j = 0; j < 4; ++j) acc[i][j] = (ffrag4){0.f, 0.f, 0.f, 0.f};

  for (int k0 = 0; k0 < Kd; k0 += 32) {
    __syncthreads();
#pragma unroll
    for (int u = 0; u < 2; ++u) {
      int f = tid + u * 256;
      int mtile = f >> 6, li = f & 63;
      int row = mtile * 16 + (li & 15), colq = (li >> 4) * 8;
      uint4 va = *(const uint4*)&A[(size_t)(m0 + row) * Kd + k0 + colq];
      uint4 vb = *(const uint4*)&W[(size_t)(n0 + row) * Kd + k0 + colq];
      *(uint4*)&As[f * 8] = va;
      *(uint4*)&Bs[f * 8] = vb;
    }
    __syncthreads();
    bfrag8 af[4], bf_[4];
#pragma unroll
    for (int mt = 0; mt < 4; ++mt)
      af[mt] = __builtin_bit_cast(bfrag8, *(const uint4*)&As[((mo16 + mt) * 64 + lane) * 8]);
#pragma unroll
    for (int nt = 0; nt < 4; ++nt)
      bf_[nt] = __builtin_bit_cast(bfrag8, *(const uint4*)&Bs[((no16 + nt) * 64 + lane) * 8]);
#pragma unroll
    for (int mt = 0; mt < 4; ++mt)
#pragma unroll
      for (int nt = 0; nt < 4; ++nt)
        acc[mt][nt] = __builtin_amdgcn_mfma_f32_16x16x32_bf16(af[mt], bf_[nt], acc[mt][nt], 0, 0, 0);
  }

  const int quad = lane >> 4, l15 = lane & 15;
#pragma unroll
  for (int nt = 0; nt < 4; ++nt) {
    int col = n0 + (no16 + nt) * 16 + l15;
    float bb = bias ? bias[col] : 0.f;
#pragma unroll
    for (int mt = 0; mt < 4; ++mt) {
#pragma unroll
      for (int r = 0; r < 4; ++r) {
        int row = m0 + (mo16 + mt) * 16 + quad * 4 + r;
        float val = acc[mt][nt][r] + bb;
        C[(size_t)row * N + col] = val;
        if (Cb) Cb[(size_t)row * N + col] = f2bf(val);
      }
    }
  }
}

// ---------------------------------------------------------------------------
// gate/alpha projections + sigmoid
// ---------------------------------------------------------------------------
__global__ __launch_bounds__(256) void gate_alpha(const float* __restrict__ x,
                                                  const float* __restrict__ Wg,
                                                  const float* __restrict__ bg,
                                                  const float* __restrict__ Wa,
                                                  const float* __restrict__ ba,
                                                  float* __restrict__ gate,
                                                  float* __restrict__ alpha) {
  const int row = blockIdx.x;
  const int wave = threadIdx.x >> 6, lane = threadIdx.x & 63;
  const float* xr = x + (size_t)row * Dn;
  for (int o = wave * 6; o < wave * 6 + 6; ++o) {
    const float* wrow;
    float bv;
    if (o < Hn * KT) { wrow = Wg + (size_t)o * Dn; bv = bg[o]; }
    else             { wrow = Wa + (size_t)(o - Hn * KT) * Dn; bv = ba[o - Hn * KT]; }
    float p = 0.f;
#pragma unroll
    for (int rr = 0; rr < 8; ++rr) p += xr[lane + 64 * rr] * wrow[lane + 64 * rr];
    p = wred_sum(p);
    if (lane == 0) {
      float s = sigmoidf_(p + bv);
      if (o < Hn * KT) gate[(size_t)row * (Hn * KT) + o] = s;
      else             alpha[(size_t)row * Hn + (o - Hn * KT)] = s;
    }
  }
}

// ---------------------------------------------------------------------------
// Per (b,h,k,chunk) wave: S = sum_t lam^{63-t} g_t k_t v_t^T  [64x64], z scalar
// ---------------------------------------------------------------------------
__global__ __launch_bounds__(256) void chunk_sums(const float* __restrict__ K_,
                                                  const float* __restrict__ V_,
                                                  const float* __restrict__ gate,
                                                  const float* __restrict__ decay,
                                                  float* __restrict__ S,
                                                  float* __restrict__ Zc) {
  const int gw = (blockIdx.x * blockDim.x + threadIdx.x) >> 6;
  const int lane = threadIdx.x & 63;
  int c = gw % NC, tmp = gw / NC;
  int k = tmp % KT; tmp /= KT;
  int h = tmp % Hn, b = tmp / Hn;
  const float lam = sigmoidf_(decay[h * KT + k]);
  float acc[64];
#pragma unroll
  for (int i = 0; i < 64; ++i) acc[i] = 0.f;
  float z = 0.f, lampow = 1.f;
  for (int t = 63; t >= 0; --t) {
    int tg = c * 64 + t;
    size_t base = (size_t)(b * Tn + tg) * QS + h * DH;
    float kv = K_[base + lane];
    float vv = V_[base + lane];
    float gv = gate[((size_t)(b * Tn + tg) * Hn + h) * KT + k];
    float coef = gv * lampow;
    float asum = wred_sum(fabsf(kv));
    z += coef * (asum * (1.f / 64.f) + EPS);
    float ck = coef * kv;
#pragma unroll
    for (int i = 0; i < 64; ++i) acc[i] += __shfl(ck, i, 64) * vv;
    lampow *= lam;
  }
  size_t sb = (size_t)gw * 4096;
#pragma unroll
  for (int i = 0; i < 64; ++i) S[sb + i * 64 + lane] = acc[i];
  if (lane == 0) Zc[gw] = z;
}

// ---------------------------------------------------------------------------
// Serial scan over chunks: grid (32 bhk, 8 slices of 512 floats).
// ---------------------------------------------------------------------------
__global__ __launch_bounds__(256) void scan_chunks(const float* __restrict__ S,
                                                   const float* __restrict__ Zc,
                                                   const float* __restrict__ decay,
                                                   float* __restrict__ Hinit,
                                                   float* __restrict__ Zinit) {
  const int bhk = blockIdx.x, slice = blockIdx.y;
  const int k = bhk % KT, h = (bhk / KT) % Hn;
  const float lam = sigmoidf_(decay[h * KT + k]);
  const float lam64 = powf(lam, 64.f);
  const int tid = threadIdx.x;
  const size_t base = (size_t)bhk * NC * 4096 + (size_t)slice * 512 + (size_t)tid * 2;
  float2 st = {0.f, 0.f};
#pragma unroll 2
  for (int c = 0; c < NC; ++c) {
    size_t off = base + (size_t)c * 4096;
    *(float2*)&Hinit[off] = st;
    float2 sv = *(const float2*)&S[off];
    st.x = lam64 * st.x + sv.x;
    st.y = lam64 * st.y + sv.y;
  }
  if (slice == 0 && tid < 64) {
    float v = (tid < NC) ? Zc[bhk * NC + tid] : 0.f;
    float lp = lam64;
#pragma unroll
    for (int o = 1; o < 32; o <<= 1) {
      float t2 = __shfl_up(v, o, 64);
      if (tid >= o) v += lp * t2;
      lp *= lp;
    }
    float prev = __shfl_up(v, 1, 64);
    if (tid < NC) Zinit[bhk * NC + tid] = (tid == 0) ? 0.f : prev;
  }
}

// ---------------------------------------------------------------------------
// Block per (b,h,c): chunked attention, MFMA everywhere.
// Q/K frags: direct 16B global loads from qkvb. V/H: LDS-transpose staging.
// sS rows are wave-private (C-layout rows == wave's m-tile).
// ---------------------------------------------------------------------------
__global__ __launch_bounds__(256) void attn_chunk(const float* __restrict__ qkv,
                                                  const unsigned short* __restrict__ qkvb,
                                                  const float* __restrict__ gate,
                                                  const float* __restrict__ alpha,
                                                  const float* __restrict__ decay,
                                                  const float* __restrict__ Hinit,
                                                  const float* __restrict__ Zinit,
                                                  unsigned short* __restrict__ ypre) {
  __shared__ float sS[64][132];              // raw scores -> probs (33.8KB)
  __shared__ unsigned short sT16[64 * 72];   // bf16 transpose-staging (9.2KB)
  __shared__ float sval_s[64];
  __shared__ float gk[KT][64];
  __shared__ float sz[KT][64];
  __shared__ float pw[KT][66];
  __shared__ float wt2[KT][64];              // g_s * lam^-s
  __shared__ float zin[KT];

  const int c = blockIdx.x, h = blockIdx.y, b = blockIdx.z;
  const int c0 = c * 64;
  const int tid = threadIdx.x;
  const int wave = tid >> 6, lane = tid & 63;
  const int quad = lane >> 4, l15 = lane & 15;
  const int mt = wave;  // 16-row m-tile per wave

  // ---------------- prologue ----------------
  {
    int s = tid >> 2, qq = tid & 3;
    const float* kr = qkv + (size_t)(b * Tn + c0 + s) * QS + 512 + h * DH + qq * 16;
    float acc = 0.f;
#pragma unroll
    for (int u = 0; u < 4; ++u) {
      float4 v = *(const float4*)(kr + u * 4);
      acc += fabsf(v.x) + fabsf(v.y) + fabsf(v.z) + fabsf(v.w);
    }
    ((float*)sT16)[tid] = acc;
  }
  if (tid < 128) {
    int s = tid >> 1, k2 = tid & 1;
    gk[k2][s] = gate[((size_t)(b * Tn + c0 + s) * Hn + h) * KT + k2];
  }
  if (tid >= 128) {
    int t2 = tid - 128;
    int k2 = t2 >> 6, d = t2 & 63;
    float lamv = sigmoidf_(decay[h * KT + k2]);
    pw[k2][d] = powf(lamv, (float)d);
  }
  if (tid < 2) {
    float lamv = sigmoidf_(decay[h * KT + tid]);
    pw[tid][64] = powf(lamv, 64.f);
    zin[tid] = Zinit[((size_t)((b * Hn + h) * KT + tid)) * NC + c];
  }
  __syncthreads();
  if (tid < 64) {
    const float* f = (const float*)sT16;
    sval_s[tid] = (f[tid * 4] + f[tid * 4 + 1] + f[tid * 4 + 2] + f[tid * 4 + 3]) * (1.f / 64.f) + EPS;
  }
  if (tid >= 128) {
    int t2 = tid - 128;
    int k2 = t2 >> 6, d = t2 & 63;
    float lamv = sigmoidf_(decay[h * KT + k2]);
    wt2[k2][d] = gk[k2][d] * powf(lamv, -(float)d);
  }
  __syncthreads();
  if (wave < 2) {
    const int kx = wave;
    float v = gk[kx][lane] * sval_s[lane];
#pragma unroll
    for (int o = 1; o < 64; o <<= 1) {
      float t2 = __shfl_up(v, o, 64);
      if (lane >= o) v += pw[kx][o] * t2;
    }
    sz[kx][lane] = v + pw[kx][lane + 1] * zin[kx];
  }

  // ---------------- Q fragments (A-operand, reused in A and C1) ------------
  us8v qf[2];
  {
    const size_t qrow = (size_t)(b * Tn + c0 + mt * 16 + l15) * QS + h * DH;
    qf[0] = *(const us8v*)&qkvb[qrow + quad * 8];
    qf[1] = *(const us8v*)&qkvb[qrow + 32 + quad * 8];
  }

  // ---------------- phase A: raw scores = Qc @ Kwin^T ----------------------
#pragma unroll
  for (int nt = 0; nt < 8; ++nt) {
    int rowg = c0 - 64 + nt * 16 + l15;
    us8v kf0 = (us8v){0, 0, 0, 0, 0, 0, 0, 0}, kf1 = kf0;
    if (rowg >= 0) {
      const size_t kb_ = (size_t)(b * Tn + rowg) * QS + 512 + h * DH;
      kf0 = *(const us8v*)&qkvb[kb_ + quad * 8];
      kf1 = *(const us8v*)&qkvb[kb_ + 32 + quad * 8];
    }
    ffrag4 a = (ffrag4){0.f, 0.f, 0.f, 0.f};
    a = __builtin_amdgcn_mfma_f32_16x16x32_bf16(__builtin_bit_cast(bfrag8, qf[0]),
                                                __builtin_bit_cast(bfrag8, kf0), a, 0, 0, 0);
    a = __builtin_amdgcn_mfma_f32_16x16x32_bf16(__builtin_bit_cast(bfrag8, qf[1]),
                                                __builtin_bit_cast(bfrag8, kf1), a, 0, 0, 0);
#pragma unroll
    for (int r = 0; r < 4; ++r) sS[mt * 16 + quad * 4 + r][nt * 16 + l15] = a[r];
  }

  // ---------------- phase C1: accH_k = Q @ Hinit_k -------------------------
  ffrag4 accH[KT][4];
#pragma unroll
  for (int k = 0; k < KT; ++k)
#pragma unroll
    for (int nt = 0; nt < 4; ++nt) accH[k][nt] = (ffrag4){0.f, 0.f, 0.f, 0.f};
  for (int k = 0; k < KT; ++k) {
    __syncthreads();
    {
      const size_t hb = ((size_t)((b * Hn + h) * KT + k) * NC + c) * 4096;
      int row = tid >> 2, cg = tid & 3;
#pragma unroll
      for (int u = 0; u < 4; ++u) {
        float4 v = *(const float4*)&Hinit[hb + (size_t)row * 64 + cg * 16 + u * 4];
        ushort4 o;
        o.x = f2bf(v.x); o.y = f2bf(v.y); o.z = f2bf(v.z); o.w = f2bf(v.w);
        *(ushort4*)&sT16[row * 72 + cg * 16 + u * 4] = o;
      }
    }
    __syncthreads();
#pragma unroll
    for (int nt = 0; nt < 4; ++nt) {
#pragma unroll
      for (int ks = 0; ks < 2; ++ks) {
        us8v g;
#pragma unroll
        for (int j = 0; j < 8; ++j) g[j] = sT16[(ks * 32 + quad * 8 + j) * 72 + nt * 16 + l15];
        accH[k][nt] = __builtin_amdgcn_mfma_f32_16x16x32_bf16(
            __builtin_bit_cast(bfrag8, qf[ks]), __builtin_bit_cast(bfrag8, g), accH[k][nt], 0, 0, 0);
      }
    }
  }

  // ---------------- stage Vc (cur chunk) + gather B-frags ------------------
  __syncthreads();
  {
    int row = tid >> 2, cg = tid & 3;
    const us8v* src = (const us8v*)&qkvb[(size_t)(b * Tn + c0 + row) * QS + 1024 + h * DH + cg * 16];
    *(us8v*)&sT16[row * 72 + cg * 16] = src[0];
    *(us8v*)&sT16[row * 72 + cg * 16 + 8] = src[1];
  }
  __syncthreads();
  us8v vf[4][2];
#pragma unroll
  for (int nt = 0; nt < 4; ++nt)
#pragma unroll
    for (int ks = 0; ks < 2; ++ks) {
#pragma unroll
      for (int j = 0; j < 8; ++j) vf[nt][ks][j] = sT16[(ks * 32 + quad * 8 + j) * 72 + nt * 16 + l15];
    }

  // ---------------- phase C2 + combine into accY ---------------------------
  const int i_loc = mt * 16 + l15;  // A-operand row for this lane
  ffrag4 accY[4];
#pragma unroll
  for (int nt = 0; nt < 4; ++nt) accY[nt] = (ffrag4){0.f, 0.f, 0.f, 0.f};
#pragma unroll
  for (int k = 0; k < KT; ++k) {
    const float lam_i = pw[k][i_loc];
    us8v af[2];
#pragma unroll
    for (int ks = 0; ks < 2; ++ks) {
      int sb_ = ks * 32 + quad * 8;
      float4 p0 = *(const float4*)&sS[i_loc][64 + sb_];
      float4 p1 = *(const float4*)&sS[i_loc][64 + sb_ + 4];
      float4 w0 = *(const float4*)&wt2[k][sb_];
      float4 w1 = *(const float4*)&wt2[k][sb_ + 4];
      float e[8] = {p0.x * w0.x, p0.y * w0.y, p0.z * w0.z, p0.w * w0.w,
                    p1.x * w1.x, p1.y * w1.y, p1.z * w1.z, p1.w * w1.w};
#pragma unroll
      for (int j = 0; j < 8; ++j) {
        float v = (sb_ + j <= i_loc) ? e[j] * lam_i : 0.f;
        af[ks][j] = f2bf(v);
      }
    }
    ffrag4 aD[4];
#pragma unroll
    for (int nt = 0; nt < 4; ++nt) aD[nt] = (ffrag4){0.f, 0.f, 0.f, 0.f};
#pragma unroll
    for (int nt = 0; nt < 4; ++nt)
#pragma unroll
      for (int ks = 0; ks < 2; ++ks)
        aD[nt] = __builtin_amdgcn_mfma_f32_16x16x32_bf16(
            __builtin_bit_cast(bfrag8, af[ks]), __builtin_bit_cast(bfrag8, vf[nt][ks]), aD[nt], 0, 0, 0);
#pragma unroll
    for (int nt = 0; nt < 4; ++nt) {
#pragma unroll
      for (int r = 0; r < 4; ++r) {
        int il = mt * 16 + quad * 4 + r;
        float invz = 1.f / (sz[k][il] + EPS);
        accY[nt][r] += (pw[k][il + 1] * accH[k][nt][r] + aD[nt][r]) * invz;
      }
    }
  }

  // ---------------- phase D: in-place masked ALiBi softmax -----------------
  {
    const float slope = exp2f(-8.f * (float)(h + 1) / (float)Hn);
    for (int rr = 0; rr < 16; ++rr) {
      const int i = mt * 16 + rr;
      float s0v = sS[i][lane], s1v = sS[i][lane + 64];
      bool va = (lane >= i + 1) && (c0 - 64 + lane >= 0);
      bool vb2 = (lane <= i);
      s0v = va  ? s0v - slope * (float)(i + 64 - lane) : -1e30f;
      s1v = vb2 ? s1v - slope * (float)(i - lane) : -1e30f;
      float m = wred_max(fmaxf(s0v, s1v));
      float p0 = __expf(s0v - m), p1 = __expf(s1v - m);
      float inv = 1.f / wred_sum(p0 + p1);
      sS[i][lane] = p0 * inv;
      sS[i][lane + 64] = p1 * inv;
    }
  }

  // ---------------- phase E: yloc = P @ Vwin (cur half reuses vf) ----------
  ffrag4 accL[4];
#pragma unroll
  for (int nt = 0; nt < 4; ++nt) accL[nt] = (ffrag4){0.f, 0.f, 0.f, 0.f};
  us8v pf[2];
#pragma unroll
  for (int ks = 0; ks < 2; ++ks) {
    int sb_ = ks * 32 + quad * 8;
    float4 p0 = *(const float4*)&sS[i_loc][64 + sb_];
    float4 p1 = *(const float4*)&sS[i_loc][64 + sb_ + 4];
    float e[8] = {p0.x, p0.y, p0.z, p0.w, p1.x, p1.y, p1.z, p1.w};
#pragma unroll
    for (int j = 0; j < 8; ++j) pf[ks][j] = f2bf(e[j]);
  }
#pragma unroll
  for (int nt = 0; nt < 4; ++nt)
#pragma unroll
    for (int ks = 0; ks < 2; ++ks)
      accL[nt] = __builtin_amdgcn_mfma_f32_16x16x32_bf16(
          __builtin_bit_cast(bfrag8, pf[ks]), __builtin_bit_cast(bfrag8, vf[nt][ks]), accL[nt], 0, 0, 0);

  // prev-half V
  __syncthreads();
  {
    int row = tid >> 2, cg = tid & 3;
    int rowg = c0 - 64 + row;
    us8v z8 = (us8v){0, 0, 0, 0, 0, 0, 0, 0};
    us8v v0 = z8, v1 = z8;
    if (rowg >= 0) {
      const us8v* src = (const us8v*)&qkvb[(size_t)(b * Tn + rowg) * QS + 1024 + h * DH + cg * 16];
      v0 = src[0]; v1 = src[1];
    }
    *(us8v*)&sT16[row * 72 + cg * 16] = v0;
    *(us8v*)&sT16[row * 72 + cg * 16 + 8] = v1;
  }
  __syncthreads();
#pragma unroll
  for (int ks = 0; ks < 2; ++ks) {
    int sb_ = ks * 32 + quad * 8;
    float4 p0 = *(const float4*)&sS[i_loc][sb_];
    float4 p1 = *(const float4*)&sS[i_loc][sb_ + 4];
    float e[8] = {p0.x, p0.y, p0.z, p0.w, p1.x, p1.y, p1.z, p1.w};
#pragma unroll
    for (int j = 0; j < 8; ++j) pf[ks][j] = f2bf(e[j]);
  }
#pragma unroll
  for (int nt = 0; nt < 4; ++nt) {
#pragma unroll
    for (int ks = 0; ks < 2; ++ks) {
      us8v g;
#pragma unroll
      for (int j = 0; j < 8; ++j) g[j] = sT16[(ks * 32 + quad * 8 + j) * 72 + nt * 16 + l15];
      accL[nt] = __builtin_amdgcn_mfma_f32_16x16x32_bf16(
          __builtin_bit_cast(bfrag8, pf[ks]), __builtin_bit_cast(bfrag8, g), accL[nt], 0, 0, 0);
    }
  }

  // ---------------- phase F: combine + bf16 write --------------------------
#pragma unroll
  for (int nt = 0; nt < 4; ++nt) {
#pragma unroll
    for (int r = 0; r < 4; ++r) {
      int il = mt * 16 + quad * 4 + r;
      int tt = c0 + il;
      float av = alpha[((size_t)(b * Tn + tt)) * Hn + h];
      float val = av * accL[nt][r] + (1.f - av) * accY[nt][r];
      ypre[(size_t)(b * Tn + tt) * Dn + h * DH + nt * 16 + l15] = f2bf(val);
    }
  }
}

// ---------------------------------------------------------------------------
// out = LayerNorm(x + proj) * gamma + beta
// ---------------------------------------------------------------------------
__global__ __launch_bounds__(256) void ln_kernel(const float* __restrict__ x,
                                                 const float* __restrict__ proj,
                                                 const float* __restrict__ gamma,
                                                 const float* __restrict__ beta,
                                                 float* __restrict__ out) {
  const int row = blockIdx.x;
  const int tid = threadIdx.x;
  const int wave = tid >> 6, lane = tid & 63;
  const size_t base = (size_t)row * Dn;
  __shared__ float red[8];
  float r0 = x[base + tid] + proj[base + tid];
  float r1 = x[base + tid + 256] + proj[base + tid + 256];
  float s = wred_sum(r0 + r1);
  if (lane == 0) red[wave] = s;
  __syncthreads();
  float mu = (red[0] + red[1] + red[2] + red[3]) * (1.f / (float)Dn);
  float d0 = r0 - mu, d1 = r1 - mu;
  float q = wred_sum(d0 * d0 + d1 * d1);
  if (lane == 0) red[4 + wave] = q;
  __syncthreads();
  float var = (red[4] + red[5] + red[6] + red[7]) * (1.f / (float)Dn);
  float inv = rsqrtf(var + LN_EPS);
  out[base + tid]       = d0 * inv * gamma[tid]       + beta[tid];
  out[base + tid + 256] = d1 * inv * gamma[tid + 256] + beta[tid + 256];
}

// ---------------------------------------------------------------------------
extern "C" void kernel_launch(void* const* d_in, const int* in_sizes, int n_in,
                              void* d_out, int out_size, void* d_ws, size_t ws_size,
                              hipStream_t stream) {
  const float* x     = (const float*)d_in[0];
  const float* Wq    = (const float*)d_in[1];
  const float* Wk    = (const float*)d_in[2];
  const float* Wv    = (const float*)d_in[3];
  const float* Wg    = (const float*)d_in[4];
  const float* bg    = (const float*)d_in[5];
  const float* Wa    = (const float*)d_in[6];
  const float* ba    = (const float*)d_in[7];
  const float* Wo    = (const float*)d_in[8];
  const float* bo    = (const float*)d_in[9];
  const float* decay = (const float*)d_in[10];
  const float* gamma = (const float*)d_in[11];
  const float* beta  = (const float*)d_in[12];
  float* out = (float*)d_out;

  const size_t NTOK = (size_t)Bn * Tn;  // 4096
  float* ws = (float*)d_ws;
  float* qkv  = ws; ws += NTOK * QS;                          // 6291456 f
  float* Sb   = ws; ws += (size_t)Bn * Hn * KT * NC * 4096;   // 4194304 f
  float* Hib  = ws; ws += (size_t)Bn * Hn * KT * NC * 4096;   // 4194304 f
  float* gateb = ws; ws += NTOK * Hn * KT;
  float* alphb = ws; ws += NTOK * Hn;
  float* Zcb  = ws; ws += (size_t)Bn * Hn * KT * NC;
  float* Zib  = ws; ws += (size_t)Bn * Hn * KT * NC;
  unsigned short* us = (unsigned short*)ws;
  unsigned short* xb   = us; us += NTOK * Dn;
  unsigned short* Wc   = us; us += (size_t)3 * Dn * Dn;
  unsigned short* Wob  = us; us += (size_t)Dn * Dn;
  unsigned short* ypre = us; us += NTOK * Dn;
  unsigned short* qkvb = us; us += NTOK * QS;
  float* proj = Sb;  // alias: Sb dead after scan_chunks

  const float* kb = qkv + 512;
  const float* vb = qkv + 1024;

  conv_bf16<<<3072, 256, 0, stream>>>(x, Wq, Wk, Wv, Wo, xb, Wc, Wob);

  gemm_mfma<<<dim3(QS / 128, (int)NTOK / 128), 256, 0, stream>>>(xb, Wc, nullptr, qkv, qkvb, QS, Dn);

  gate_alpha<<<(int)NTOK, 256, 0, stream>>>(x, Wg, bg, Wa, ba, gateb, alphb);

  chunk_sums<<<(Bn * Hn * KT * NC * 64) / 256, 256, 0, stream>>>(kb, vb, gateb, decay, Sb, Zcb);
  scan_chunks<<<dim3(Bn * Hn * KT, 8), 256, 0, stream>>>(Sb, Zcb, decay, Hib, Zib);

  attn_chunk<<<dim3(NC, Hn, Bn), 256, 0, stream>>>(qkv, qkvb, gateb, alphb,
                                                   decay, Hib, Zib, ypre);

  gemm_mfma<<<dim3(Dn / 128, (int)NTOK / 128), 256, 0, stream>>>(ypre, Wob, bo, proj, nullptr, Dn, Dn);
  ln_kernel<<<(int)NTOK, 256, 0, stream>>>(x, proj, gamma, beta, out);
}

// Round 6
// 193.777 us; speedup vs baseline: 4.4329x; 1.3535x over previous
//
#include <hip/hip_runtime.h>
#include <math.h>

#define EPS 1e-6f
#define LN_EPS 1e-5f

static constexpr int Bn = 2, Tn = 2048, Dn = 512, Hn = 8, KT = 2, DH = 64, NC = Tn / 64;
static constexpr int QS = 1536;  // fused qkv row stride (cols: q|k|v)

typedef __bf16 bfrag8 __attribute__((ext_vector_type(8)));
typedef float ffrag4 __attribute__((ext_vector_type(4)));
typedef unsigned short us8v __attribute__((ext_vector_type(8)));

__device__ __forceinline__ float wred_sum(float v) {
#pragma unroll
  for (int o = 32; o > 0; o >>= 1) v += __shfl_xor(v, o, 64);
  return v;
}
__device__ __forceinline__ float wred_max(float v) {
#pragma unroll
  for (int o = 32; o > 0; o >>= 1) v = fmaxf(v, __shfl_xor(v, o, 64));
  return v;
}
__device__ __forceinline__ float sigmoidf_(float v) { return 1.0f / (1.0f + expf(-v)); }
__device__ __forceinline__ unsigned short f2bf(float f) {
  unsigned u = __builtin_bit_cast(unsigned, f);
  return (unsigned short)((u + 0x7FFFu + ((u >> 16) & 1u)) >> 16);
}
__device__ __forceinline__ float bf2f(unsigned short u) {
  unsigned v = ((unsigned)u) << 16;
  return __builtin_bit_cast(float, v);
}

// ---------------------------------------------------------------------------
// fp32 -> bf16 conversion: x, Wq/Wk/Wv -> Wc (contig [1536][512]), Wo->Wob
// ---------------------------------------------------------------------------
__global__ __launch_bounds__(256) void conv_bf16(const float* __restrict__ x,
                                                 const float* __restrict__ Wq,
                                                 const float* __restrict__ Wk,
                                                 const float* __restrict__ Wv,
                                                 const float* __restrict__ Wo,
                                                 unsigned short* __restrict__ xb,
                                                 unsigned short* __restrict__ Wc,
                                                 unsigned short* __restrict__ Wob) {
  int idx = blockIdx.x * 256 + threadIdx.x;  // float4 index
  const float* src;
  unsigned short* dst;
  int off;
  if (idx < 524288)      { src = x;  dst = xb;           off = idx; }
  else if (idx < 589824) { src = Wq; dst = Wc;           off = idx - 524288; }
  else if (idx < 655360) { src = Wk; dst = Wc + 262144;  off = idx - 589824; }
  else if (idx < 720896) { src = Wv; dst = Wc + 524288;  off = idx - 655360; }
  else                   { src = Wo; dst = Wob;          off = idx - 720896; }
  float4 v = *(const float4*)&src[(size_t)off * 4];
  ushort4 o;
  o.x = f2bf(v.x); o.y = f2bf(v.y); o.z = f2bf(v.z); o.w = f2bf(v.w);
  *(ushort4*)&dst[(size_t)off * 4] = o;
}

// ---------------------------------------------------------------------------
// bf16 MFMA GEMM: C[M,N](fp32) = A[M,Kd](bf16) @ W[N,Kd](bf16)^T (+bias)
// optional bf16 copy of C into Cb.
// ---------------------------------------------------------------------------
__global__ __launch_bounds__(256) void gemm_mfma(const unsigned short* __restrict__ A,
                                                 const unsigned short* __restrict__ W,
                                                 const float* __restrict__ bias,
                                                 float* __restrict__ C,
                                                 unsigned short* __restrict__ Cb,
                                                 int N, int Kd) {
  __shared__ unsigned short As[4096];
  __shared__ unsigned short Bs[4096];
  const int tid = threadIdx.x;
  const int lane = tid & 63, wave = tid >> 6;
  const int m0 = blockIdx.y * 128, n0 = blockIdx.x * 128;
  const int mo16 = (wave >> 1) * 4;
  const int no16 = (wave & 1) * 4;

  ffrag4 acc[4][4];
#pragma unroll
  for (int i = 0; i < 4; ++i)
#pragma unroll
    for (int j = 0; j < 4; ++j) acc[i][j] = (ffrag4){0.f, 0.f, 0.f, 0.f};

  for (int k0 = 0; k0 < Kd; k0 += 32) {
    __syncthreads();
#pragma unroll
    for (int u = 0; u < 2; ++u) {
      int f = tid + u * 256;
      int mtile = f >> 6, li = f & 63;
      int row = mtile * 16 + (li & 15), colq = (li >> 4) * 8;
      uint4 va = *(const uint4*)&A[(size_t)(m0 + row) * Kd + k0 + colq];
      uint4 vb = *(const uint4*)&W[(size_t)(n0 + row) * Kd + k0 + colq];
      *(uint4*)&As[f * 8] = va;
      *(uint4*)&Bs[f * 8] = vb;
    }
    __syncthreads();
    bfrag8 af[4], bf_[4];
#pragma unroll
    for (int mt = 0; mt < 4; ++mt)
      af[mt] = __builtin_bit_cast(bfrag8, *(const uint4*)&As[((mo16 + mt) * 64 + lane) * 8]);
#pragma unroll
    for (int nt = 0; nt < 4; ++nt)
      bf_[nt] = __builtin_bit_cast(bfrag8, *(const uint4*)&Bs[((no16 + nt) * 64 + lane) * 8]);
#pragma unroll
    for (int mt = 0; mt < 4; ++mt)
#pragma unroll
      for (int nt = 0; nt < 4; ++nt)
        acc[mt][nt] = __builtin_amdgcn_mfma_f32_16x16x32_bf16(af[mt], bf_[nt], acc[mt][nt], 0, 0, 0);
  }

  const int quad = lane >> 4, l15 = lane & 15;
#pragma unroll
  for (int nt = 0; nt < 4; ++nt) {
    int col = n0 + (no16 + nt) * 16 + l15;
    float bb = bias ? bias[col] : 0.f;
#pragma unroll
    for (int mt = 0; mt < 4; ++mt) {
#pragma unroll
      for (int r = 0; r < 4; ++r) {
        int row = m0 + (mo16 + mt) * 16 + quad * 4 + r;
        float val = acc[mt][nt][r] + bb;
        C[(size_t)row * N + col] = val;
        if (Cb) Cb[(size_t)row * N + col] = f2bf(val);
      }
    }
  }
}

// ---------------------------------------------------------------------------
// gate/alpha projections + sigmoid
// ---------------------------------------------------------------------------
__global__ __launch_bounds__(256) void gate_alpha(const float* __restrict__ x,
                                                  const float* __restrict__ Wg,
                                                  const float* __restrict__ bg,
                                                  const float* __restrict__ Wa,
                                                  const float* __restrict__ ba,
                                                  float* __restrict__ gate,
                                                  float* __restrict__ alpha) {
  const int row = blockIdx.x;
  const int wave = threadIdx.x >> 6, lane = threadIdx.x & 63;
  const float* xr = x + (size_t)row * Dn;
  for (int o = wave * 6; o < wave * 6 + 6; ++o) {
    const float* wrow;
    float bv;
    if (o < Hn * KT) { wrow = Wg + (size_t)o * Dn; bv = bg[o]; }
    else             { wrow = Wa + (size_t)(o - Hn * KT) * Dn; bv = ba[o - Hn * KT]; }
    float p = 0.f;
#pragma unroll
    for (int rr = 0; rr < 8; ++rr) p += xr[lane + 64 * rr] * wrow[lane + 64 * rr];
    p = wred_sum(p);
    if (lane == 0) {
      float s = sigmoidf_(p + bv);
      if (o < Hn * KT) gate[(size_t)row * (Hn * KT) + o] = s;
      else             alpha[(size_t)row * Hn + (o - Hn * KT)] = s;
    }
  }
}

// ---------------------------------------------------------------------------
// Block per (b,h,c): S_k = K^T @ (w_k o V)  via MFMA (bf16 operands, single
// rounding each), fp32 S out. z_k via wred. w_k[t] = g_k[t] * lam_k^{63-t}.
// ---------------------------------------------------------------------------
__global__ __launch_bounds__(256) void chunk_sums(const float* __restrict__ qkv,
                                                  const unsigned short* __restrict__ qkvb,
                                                  const float* __restrict__ gate,
                                                  const float* __restrict__ decay,
                                                  float* __restrict__ S,
                                                  float* __restrict__ Zc) {
  __shared__ unsigned short sK[64 * 72];
  __shared__ unsigned short sV[64 * 72];
  __shared__ float red4[256];
  __shared__ float sval_s[64];
  __shared__ float gk[KT][64];
  __shared__ float pwr[KT][64];    // lam^d
  __shared__ float wcomb[KT][64];  // g[t] * lam^{63-t}
  const int c = blockIdx.x, h = blockIdx.y, b = blockIdx.z;
  const int c0 = c * 64;
  const int tid = threadIdx.x, wave = tid >> 6, lane = tid & 63;
  const int quad = lane >> 4, l15 = lane & 15;

  {
    int row = tid >> 2, cg = tid & 3;
    const us8v* ksrc = (const us8v*)&qkvb[(size_t)(b * Tn + c0 + row) * QS + 512 + h * DH + cg * 16];
    *(us8v*)&sK[row * 72 + cg * 16] = ksrc[0];
    *(us8v*)&sK[row * 72 + cg * 16 + 8] = ksrc[1];
    const us8v* vsrc = (const us8v*)&qkvb[(size_t)(b * Tn + c0 + row) * QS + 1024 + h * DH + cg * 16];
    *(us8v*)&sV[row * 72 + cg * 16] = vsrc[0];
    *(us8v*)&sV[row * 72 + cg * 16 + 8] = vsrc[1];
    // fp32 |k| partial sums for z
    const float* kr = qkv + (size_t)(b * Tn + c0 + row) * QS + 512 + h * DH + cg * 16;
    float acc = 0.f;
#pragma unroll
    for (int u = 0; u < 4; ++u) {
      float4 v = *(const float4*)(kr + u * 4);
      acc += fabsf(v.x) + fabsf(v.y) + fabsf(v.z) + fabsf(v.w);
    }
    red4[tid] = acc;
  }
  if (tid < 128) {
    int s = tid >> 1, k2 = tid & 1;
    gk[k2][s] = gate[((size_t)(b * Tn + c0 + s) * Hn + h) * KT + k2];
  } else {
    int t2 = tid - 128;
    int k2 = t2 >> 6, d = t2 & 63;
    pwr[k2][d] = powf(sigmoidf_(decay[h * KT + k2]), (float)d);
  }
  __syncthreads();
  if (tid < 64)
    sval_s[tid] = (red4[tid * 4] + red4[tid * 4 + 1] + red4[tid * 4 + 2] + red4[tid * 4 + 3]) *
                      (1.f / 64.f) + EPS;
  if (tid >= 128) {
    int t2 = tid - 128;
    int k2 = t2 >> 6, d = t2 & 63;
    wcomb[k2][d] = gk[k2][d] * pwr[k2][63 - d];
  }
  __syncthreads();
  if (wave < 2) {
    const int kx = wave;
    float v = wcomb[kx][lane] * sval_s[lane];
    v = wred_sum(v);
    if (lane == 0) Zc[((size_t)((b * Hn + h) * KT + kx)) * NC + c] = v;
  }

  // A-operand: K^T (rows = state dim m, contraction t) — no extra rounding
  const int m_glob = wave * 16 + l15;
  us8v kf[2];
#pragma unroll
  for (int ks = 0; ks < 2; ++ks)
#pragma unroll
    for (int j = 0; j < 8; ++j) kf[ks][j] = sK[(ks * 32 + quad * 8 + j) * 72 + m_glob];

#pragma unroll
  for (int k = 0; k < KT; ++k) {
    // B-operand: (w_k o V)[n][t], single product rounding
    us8v bv[4][2];
#pragma unroll
    for (int nt = 0; nt < 4; ++nt)
#pragma unroll
      for (int ks = 0; ks < 2; ++ks)
#pragma unroll
        for (int j = 0; j < 8; ++j) {
          int t = ks * 32 + quad * 8 + j;
          bv[nt][ks][j] = f2bf(wcomb[k][t] * bf2f(sV[t * 72 + nt * 16 + l15]));
        }
    ffrag4 acc[4];
#pragma unroll
    for (int nt = 0; nt < 4; ++nt) acc[nt] = (ffrag4){0.f, 0.f, 0.f, 0.f};
#pragma unroll
    for (int nt = 0; nt < 4; ++nt)
#pragma unroll
      for (int ks = 0; ks < 2; ++ks)
        acc[nt] = __builtin_amdgcn_mfma_f32_16x16x32_bf16(
            __builtin_bit_cast(bfrag8, kf[ks]), __builtin_bit_cast(bfrag8, bv[nt][ks]), acc[nt], 0, 0, 0);
    const size_t sb = ((size_t)((b * Hn + h) * KT + k) * NC + c) * 4096;
#pragma unroll
    for (int nt = 0; nt < 4; ++nt)
#pragma unroll
      for (int r = 0; r < 4; ++r)
        S[sb + (size_t)(wave * 16 + quad * 4 + r) * 64 + nt * 16 + l15] = acc[nt][r];
  }
}

// ---------------------------------------------------------------------------
// Serial scan over chunks (fp32): grid (32 bhk, 8 slices of 512 floats).
// ---------------------------------------------------------------------------
__global__ __launch_bounds__(256) void scan_chunks(const float* __restrict__ S,
                                                   const float* __restrict__ Zc,
                                                   const float* __restrict__ decay,
                                                   float* __restrict__ Hinit,
                                                   float* __restrict__ Zinit) {
  const int bhk = blockIdx.x, slice = blockIdx.y;
  const int k = bhk % KT, h = (bhk / KT) % Hn;
  const float lam = sigmoidf_(decay[h * KT + k]);
  const float lam64 = powf(lam, 64.f);
  const int tid = threadIdx.x;
  const size_t base = (size_t)bhk * NC * 4096 + (size_t)slice * 512 + (size_t)tid * 2;
  float2 st = {0.f, 0.f};
#pragma unroll 2
  for (int c = 0; c < NC; ++c) {
    size_t off = base + (size_t)c * 4096;
    *(float2*)&Hinit[off] = st;
    float2 sv = *(const float2*)&S[off];
    st.x = lam64 * st.x + sv.x;
    st.y = lam64 * st.y + sv.y;
  }
  if (slice == 0 && tid < 64) {
    float v = (tid < NC) ? Zc[bhk * NC + tid] : 0.f;
    float lp = lam64;
#pragma unroll
    for (int o = 1; o < 32; o <<= 1) {
      float t2 = __shfl_up(v, o, 64);
      if (tid >= o) v += lp * t2;
      lp *= lp;
    }
    float prev = __shfl_up(v, 1, 64);
    if (tid < NC) Zinit[bhk * NC + tid] = (tid == 0) ? 0.f : prev;
  }
}

// ---------------------------------------------------------------------------
// Block per (b,h,c): chunked attention, MFMA everywhere. Hinit fp32.
// ---------------------------------------------------------------------------
__global__ __launch_bounds__(256) void attn_chunk(const float* __restrict__ qkv,
                                                  const unsigned short* __restrict__ qkvb,
                                                  const float* __restrict__ gate,
                                                  const float* __restrict__ alpha,
                                                  const float* __restrict__ decay,
                                                  const float* __restrict__ Hinit,
                                                  const float* __restrict__ Zinit,
                                                  unsigned short* __restrict__ ypre) {
  __shared__ float sS[64][132];              // raw scores -> probs
  __shared__ unsigned short sT16[64 * 72];   // bf16 transpose-staging
  __shared__ float sval_s[64];
  __shared__ float gk[KT][64];
  __shared__ float sz[KT][64];
  __shared__ float pw[KT][66];
  __shared__ float wt2[KT][64];              // g_s * lam^-s
  __shared__ float zin[KT];

  const int c = blockIdx.x, h = blockIdx.y, b = blockIdx.z;
  const int c0 = c * 64;
  const int tid = threadIdx.x;
  const int wave = tid >> 6, lane = tid & 63;
  const int quad = lane >> 4, l15 = lane & 15;
  const int mt = wave;

  // ---------------- prologue ----------------
  {
    int s = tid >> 2, qq = tid & 3;
    const float* kr = qkv + (size_t)(b * Tn + c0 + s) * QS + 512 + h * DH + qq * 16;
    float acc = 0.f;
#pragma unroll
    for (int u = 0; u < 4; ++u) {
      float4 v = *(const float4*)(kr + u * 4);
      acc += fabsf(v.x) + fabsf(v.y) + fabsf(v.z) + fabsf(v.w);
    }
    ((float*)sT16)[tid] = acc;
  }
  if (tid < 128) {
    int s = tid >> 1, k2 = tid & 1;
    gk[k2][s] = gate[((size_t)(b * Tn + c0 + s) * Hn + h) * KT + k2];
  }
  if (tid >= 128) {
    int t2 = tid - 128;
    int k2 = t2 >> 6, d = t2 & 63;
    float lamv = sigmoidf_(decay[h * KT + k2]);
    pw[k2][d] = powf(lamv, (float)d);
  }
  if (tid < 2) {
    float lamv = sigmoidf_(decay[h * KT + tid]);
    pw[tid][64] = powf(lamv, 64.f);
    zin[tid] = Zinit[((size_t)((b * Hn + h) * KT + tid)) * NC + c];
  }
  __syncthreads();
  if (tid < 64) {
    const float* f = (const float*)sT16;
    sval_s[tid] = (f[tid * 4] + f[tid * 4 + 1] + f[tid * 4 + 2] + f[tid * 4 + 3]) * (1.f / 64.f) + EPS;
  }
  if (tid >= 128) {
    int t2 = tid - 128;
    int k2 = t2 >> 6, d = t2 & 63;
    float lamv = sigmoidf_(decay[h * KT + k2]);
    wt2[k2][d] = gk[k2][d] * powf(lamv, -(float)d);
  }
  __syncthreads();
  if (wave < 2) {
    const int kx = wave;
    float v = gk[kx][lane] * sval_s[lane];
#pragma unroll
    for (int o = 1; o < 64; o <<= 1) {
      float t2 = __shfl_up(v, o, 64);
      if (lane >= o) v += pw[kx][o] * t2;
    }
    sz[kx][lane] = v + pw[kx][lane + 1] * zin[kx];
  }

  // ---------------- Q fragments ----------------
  us8v qf[2];
  {
    const size_t qrow = (size_t)(b * Tn + c0 + mt * 16 + l15) * QS + h * DH;
    qf[0] = *(const us8v*)&qkvb[qrow + quad * 8];
    qf[1] = *(const us8v*)&qkvb[qrow + 32 + quad * 8];
  }

  // ---------------- phase A: raw scores = Qc @ Kwin^T ----------------------
#pragma unroll
  for (int nt = 0; nt < 8; ++nt) {
    int rowg = c0 - 64 + nt * 16 + l15;
    us8v kf0 = (us8v){0, 0, 0, 0, 0, 0, 0, 0}, kf1 = kf0;
    if (rowg >= 0) {
      const size_t kb_ = (size_t)(b * Tn + rowg) * QS + 512 + h * DH;
      kf0 = *(const us8v*)&qkvb[kb_ + quad * 8];
      kf1 = *(const us8v*)&qkvb[kb_ + 32 + quad * 8];
    }
    ffrag4 a = (ffrag4){0.f, 0.f, 0.f, 0.f};
    a = __builtin_amdgcn_mfma_f32_16x16x32_bf16(__builtin_bit_cast(bfrag8, qf[0]),
                                                __builtin_bit_cast(bfrag8, kf0), a, 0, 0, 0);
    a = __builtin_amdgcn_mfma_f32_16x16x32_bf16(__builtin_bit_cast(bfrag8, qf[1]),
                                                __builtin_bit_cast(bfrag8, kf1), a, 0, 0, 0);
#pragma unroll
    for (int r = 0; r < 4; ++r) sS[mt * 16 + quad * 4 + r][nt * 16 + l15] = a[r];
  }

  // ---------------- phase C1: accH_k = Q @ Hinit_k -------------------------
  ffrag4 accH[KT][4];
#pragma unroll
  for (int k = 0; k < KT; ++k)
#pragma unroll
    for (int nt = 0; nt < 4; ++nt) accH[k][nt] = (ffrag4){0.f, 0.f, 0.f, 0.f};
  for (int k = 0; k < KT; ++k) {
    __syncthreads();
    {
      const size_t hb = ((size_t)((b * Hn + h) * KT + k) * NC + c) * 4096;
      int row = tid >> 2, cg = tid & 3;
#pragma unroll
      for (int u = 0; u < 4; ++u) {
        float4 v = *(const float4*)&Hinit[hb + (size_t)row * 64 + cg * 16 + u * 4];
        ushort4 o;
        o.x = f2bf(v.x); o.y = f2bf(v.y); o.z = f2bf(v.z); o.w = f2bf(v.w);
        *(ushort4*)&sT16[row * 72 + cg * 16 + u * 4] = o;
      }
    }
    __syncthreads();
#pragma unroll
    for (int nt = 0; nt < 4; ++nt) {
#pragma unroll
      for (int ks = 0; ks < 2; ++ks) {
        us8v g;
#pragma unroll
        for (int j = 0; j < 8; ++j) g[j] = sT16[(ks * 32 + quad * 8 + j) * 72 + nt * 16 + l15];
        accH[k][nt] = __builtin_amdgcn_mfma_f32_16x16x32_bf16(
            __builtin_bit_cast(bfrag8, qf[ks]), __builtin_bit_cast(bfrag8, g), accH[k][nt], 0, 0, 0);
      }
    }
  }

  // ---------------- stage Vc (cur chunk) + gather B-frags ------------------
  __syncthreads();
  {
    int row = tid >> 2, cg = tid & 3;
    const us8v* src = (const us8v*)&qkvb[(size_t)(b * Tn + c0 + row) * QS + 1024 + h * DH + cg * 16];
    *(us8v*)&sT16[row * 72 + cg * 16] = src[0];
    *(us8v*)&sT16[row * 72 + cg * 16 + 8] = src[1];
  }
  __syncthreads();
  us8v vf[4][2];
#pragma unroll
  for (int nt = 0; nt < 4; ++nt)
#pragma unroll
    for (int ks = 0; ks < 2; ++ks) {
#pragma unroll
      for (int j = 0; j < 8; ++j) vf[nt][ks][j] = sT16[(ks * 32 + quad * 8 + j) * 72 + nt * 16 + l15];
    }

  // ---------------- phase C2 + combine into accY ---------------------------
  const int i_loc = mt * 16 + l15;
  ffrag4 accY[4];
#pragma unroll
  for (int nt = 0; nt < 4; ++nt) accY[nt] = (ffrag4){0.f, 0.f, 0.f, 0.f};
#pragma unroll
  for (int k = 0; k < KT; ++k) {
    const float lam_i = pw[k][i_loc];
    us8v af[2];
#pragma unroll
    for (int ks = 0; ks < 2; ++ks) {
      int sb_ = ks * 32 + quad * 8;
      float4 p0 = *(const float4*)&sS[i_loc][64 + sb_];
      float4 p1 = *(const float4*)&sS[i_loc][64 + sb_ + 4];
      float4 w0 = *(const float4*)&wt2[k][sb_];
      float4 w1 = *(const float4*)&wt2[k][sb_ + 4];
      float e[8] = {p0.x * w0.x, p0.y * w0.y, p0.z * w0.z, p0.w * w0.w,
                    p1.x * w1.x, p1.y * w1.y, p1.z * w1.z, p1.w * w1.w};
#pragma unroll
      for (int j = 0; j < 8; ++j) {
        float v = (sb_ + j <= i_loc) ? e[j] * lam_i : 0.f;
        af[ks][j] = f2bf(v);
      }
    }
    ffrag4 aD[4];
#pragma unroll
    for (int nt = 0; nt < 4; ++nt) aD[nt] = (ffrag4){0.f, 0.f, 0.f, 0.f};
#pragma unroll
    for (int nt = 0; nt < 4; ++nt)
#pragma unroll
      for (int ks = 0; ks < 2; ++ks)
        aD[nt] = __builtin_amdgcn_mfma_f32_16x16x32_bf16(
            __builtin_bit_cast(bfrag8, af[ks]), __builtin_bit_cast(bfrag8, vf[nt][ks]), aD[nt], 0, 0, 0);
#pragma unroll
    for (int nt = 0; nt < 4; ++nt) {
#pragma unroll
      for (int r = 0; r < 4; ++r) {
        int il = mt * 16 + quad * 4 + r;
        float invz = 1.f / (sz[k][il] + EPS);
        accY[nt][r] += (pw[k][il + 1] * accH[k][nt][r] + aD[nt][r]) * invz;
      }
    }
  }

  // ---------------- phase D: in-place masked ALiBi softmax -----------------
  {
    const float slope = exp2f(-8.f * (float)(h + 1) / (float)Hn);
    for (int rr = 0; rr < 16; ++rr) {
      const int i = mt * 16 + rr;
      float s0v = sS[i][lane], s1v = sS[i][lane + 64];
      bool va = (lane >= i + 1) && (c0 - 64 + lane >= 0);
      bool vb2 = (lane <= i);
      s0v = va  ? s0v - slope * (float)(i + 64 - lane) : -1e30f;
      s1v = vb2 ? s1v - slope * (float)(i - lane) : -1e30f;
      float m = wred_max(fmaxf(s0v, s1v));
      float p0 = __expf(s0v - m), p1 = __expf(s1v - m);
      float inv = 1.f / wred_sum(p0 + p1);
      sS[i][lane] = p0 * inv;
      sS[i][lane + 64] = p1 * inv;
    }
  }

  // ---------------- phase E: yloc = P @ Vwin (cur half reuses vf) ----------
  ffrag4 accL[4];
#pragma unroll
  for (int nt = 0; nt < 4; ++nt) accL[nt] = (ffrag4){0.f, 0.f, 0.f, 0.f};
  us8v pf[2];
#pragma unroll
  for (int ks = 0; ks < 2; ++ks) {
    int sb_ = ks * 32 + quad * 8;
    float4 p0 = *(const float4*)&sS[i_loc][64 + sb_];
    float4 p1 = *(const float4*)&sS[i_loc][64 + sb_ + 4];
    float e[8] = {p0.x, p0.y, p0.z, p0.w, p1.x, p1.y, p1.z, p1.w};
#pragma unroll
    for (int j = 0; j < 8; ++j) pf[ks][j] = f2bf(e[j]);
  }
#pragma unroll
  for (int nt = 0; nt < 4; ++nt)
#pragma unroll
    for (int ks = 0; ks < 2; ++ks)
      accL[nt] = __builtin_amdgcn_mfma_f32_16x16x32_bf16(
          __builtin_bit_cast(bfrag8, pf[ks]), __builtin_bit_cast(bfrag8, vf[nt][ks]), accL[nt], 0, 0, 0);

  // prev-half V
  __syncthreads();
  {
    int row = tid >> 2, cg = tid & 3;
    int rowg = c0 - 64 + row;
    us8v z8 = (us8v){0, 0, 0, 0, 0, 0, 0, 0};
    us8v v0 = z8, v1 = z8;
    if (rowg >= 0) {
      const us8v* src = (const us8v*)&qkvb[(size_t)(b * Tn + rowg) * QS + 1024 + h * DH + cg * 16];
      v0 = src[0]; v1 = src[1];
    }
    *(us8v*)&sT16[row * 72 + cg * 16] = v0;
    *(us8v*)&sT16[row * 72 + cg * 16 + 8] = v1;
  }
  __syncthreads();
#pragma unroll
  for (int ks = 0; ks < 2; ++ks) {
    int sb_ = ks * 32 + quad * 8;
    float4 p0 = *(const float4*)&sS[i_loc][sb_];
    float4 p1 = *(const float4*)&sS[i_loc][sb_ + 4];
    float e[8] = {p0.x, p0.y, p0.z, p0.w, p1.x, p1.y, p1.z, p1.w};
#pragma unroll
    for (int j = 0; j < 8; ++j) pf[ks][j] = f2bf(e[j]);
  }
#pragma unroll
  for (int nt = 0; nt < 4; ++nt) {
#pragma unroll
    for (int ks = 0; ks < 2; ++ks) {
      us8v g;
#pragma unroll
      for (int j = 0; j < 8; ++j) g[j] = sT16[(ks * 32 + quad * 8 + j) * 72 + nt * 16 + l15];
      accL[nt] = __builtin_amdgcn_mfma_f32_16x16x32_bf16(
          __builtin_bit_cast(bfrag8, pf[ks]), __builtin_bit_cast(bfrag8, g), accL[nt], 0, 0, 0);
    }
  }

  // ---------------- phase F: combine + bf16 write --------------------------
#pragma unroll
  for (int nt = 0; nt < 4; ++nt) {
#pragma unroll
    for (int r = 0; r < 4; ++r) {
      int il = mt * 16 + quad * 4 + r;
      int tt = c0 + il;
      float av = alpha[((size_t)(b * Tn + tt)) * Hn + h];
      float val = av * accL[nt][r] + (1.f - av) * accY[nt][r];
      ypre[(size_t)(b * Tn + tt) * Dn + h * DH + nt * 16 + l15] = f2bf(val);
    }
  }
}

// ---------------------------------------------------------------------------
// out = LayerNorm(x + proj) * gamma + beta
// ---------------------------------------------------------------------------
__global__ __launch_bounds__(256) void ln_kernel(const float* __restrict__ x,
                                                 const float* __restrict__ proj,
                                                 const float* __restrict__ gamma,
                                                 const float* __restrict__ beta,
                                                 float* __restrict__ out) {
  const int row = blockIdx.x;
  const int tid = threadIdx.x;
  const int wave = tid >> 6, lane = tid & 63;
  const size_t base = (size_t)row * Dn;
  __shared__ float red[8];
  float r0 = x[base + tid] + proj[base + tid];
  float r1 = x[base + tid + 256] + proj[base + tid + 256];
  float s = wred_sum(r0 + r1);
  if (lane == 0) red[wave] = s;
  __syncthreads();
  float mu = (red[0] + red[1] + red[2] + red[3]) * (1.f / (float)Dn);
  float d0 = r0 - mu, d1 = r1 - mu;
  float q = wred_sum(d0 * d0 + d1 * d1);
  if (lane == 0) red[4 + wave] = q;
  __syncthreads();
  float var = (red[4] + red[5] + red[6] + red[7]) * (1.f / (float)Dn);
  float inv = rsqrtf(var + LN_EPS);
  out[base + tid]       = d0 * inv * gamma[tid]       + beta[tid];
  out[base + tid + 256] = d1 * inv * gamma[tid + 256] + beta[tid + 256];
}

// ---------------------------------------------------------------------------
extern "C" void kernel_launch(void* const* d_in, const int* in_sizes, int n_in,
                              void* d_out, int out_size, void* d_ws, size_t ws_size,
                              hipStream_t stream) {
  const float* x     = (const float*)d_in[0];
  const float* Wq    = (const float*)d_in[1];
  const float* Wk    = (const float*)d_in[2];
  const float* Wv    = (const float*)d_in[3];
  const float* Wg    = (const float*)d_in[4];
  const float* bg    = (const float*)d_in[5];
  const float* Wa    = (const float*)d_in[6];
  const float* ba    = (const float*)d_in[7];
  const float* Wo    = (const float*)d_in[8];
  const float* bo    = (const float*)d_in[9];
  const float* decay = (const float*)d_in[10];
  const float* gamma = (const float*)d_in[11];
  const float* beta  = (const float*)d_in[12];
  float* out = (float*)d_out;

  const size_t NTOK = (size_t)Bn * Tn;  // 4096
  const size_t NST  = (size_t)Bn * Hn * KT * NC * 4096;  // 4194304 state elems
  float* ws = (float*)d_ws;
  float* qkv  = ws; ws += NTOK * QS;
  float* Sb   = ws; ws += NST;    // fp32 S (aliased by proj later)
  float* Hib  = ws; ws += NST;    // fp32 Hinit
  float* gateb = ws; ws += NTOK * Hn * KT;
  float* alphb = ws; ws += NTOK * Hn;
  float* Zcb  = ws; ws += (size_t)Bn * Hn * KT * NC;
  float* Zib  = ws; ws += (size_t)Bn * Hn * KT * NC;
  unsigned short* us = (unsigned short*)ws;
  unsigned short* xb   = us; us += NTOK * Dn;
  unsigned short* Wc   = us; us += (size_t)3 * Dn * Dn;
  unsigned short* Wob  = us; us += (size_t)Dn * Dn;
  unsigned short* ypre = us; us += NTOK * Dn;
  unsigned short* qkvb = us; us += NTOK * QS;
  float* proj = Sb;  // alias: Sb dead after scan_chunks

  conv_bf16<<<3072, 256, 0, stream>>>(x, Wq, Wk, Wv, Wo, xb, Wc, Wob);

  gemm_mfma<<<dim3(QS / 128, (int)NTOK / 128), 256, 0, stream>>>(xb, Wc, nullptr, qkv, qkvb, QS, Dn);

  gate_alpha<<<(int)NTOK, 256, 0, stream>>>(x, Wg, bg, Wa, ba, gateb, alphb);

  chunk_sums<<<dim3(NC, Hn, Bn), 256, 0, stream>>>(qkv, qkvb, gateb, decay, Sb, Zcb);
  scan_chunks<<<dim3(Bn * Hn * KT, 8), 256, 0, stream>>>(Sb, Zcb, decay, Hib, Zib);

  attn_chunk<<<dim3(NC, Hn, Bn), 256, 0, stream>>>(qkv, qkvb, gateb, alphb,
                                                   decay, Hib, Zib, ypre);

  gemm_mfma<<<dim3(Dn / 128, (int)NTOK / 128), 256, 0, stream>>>(ypre, Wob, bo, proj, nullptr, Dn, Dn);
  ln_kernel<<<(int)NTOK, 256, 0, stream>>>(x, proj, gamma, beta, out);
}

// Round 7
// 191.125 us; speedup vs baseline: 4.4944x; 1.0139x over previous
//
#include <hip/hip_runtime.h>
#include <math.h>

#define EPS 1e-6f
#define LN_EPS 1e-5f

static constexpr int Bn = 2, Tn = 2048, Dn = 512, Hn = 8, KT = 2, DH = 64, NC = Tn / 64;
static constexpr int QS = 1536;   // fused qkv bf16 row stride (cols: q|k|v)
static constexpr int NW = 1664;   // padded GEMM width: qkv 1536 | gate 16 | alpha 8 | pad 104

typedef __bf16 bfrag8 __attribute__((ext_vector_type(8)));
typedef float ffrag4 __attribute__((ext_vector_type(4)));
typedef unsigned short us8v __attribute__((ext_vector_type(8)));

__device__ __forceinline__ float wred_sum(float v) {
#pragma unroll
  for (int o = 32; o > 0; o >>= 1) v += __shfl_xor(v, o, 64);
  return v;
}
__device__ __forceinline__ float wred_max(float v) {
#pragma unroll
  for (int o = 32; o > 0; o >>= 1) v = fmaxf(v, __shfl_xor(v, o, 64));
  return v;
}
__device__ __forceinline__ float sigmoidf_(float v) { return 1.0f / (1.0f + expf(-v)); }
__device__ __forceinline__ unsigned short f2bf(float f) {
  unsigned u = __builtin_bit_cast(unsigned, f);
  return (unsigned short)((u + 0x7FFFu + ((u >> 16) & 1u)) >> 16);
}
__device__ __forceinline__ float bf2f(unsigned short u) {
  unsigned v = ((unsigned)u) << 16;
  return __builtin_bit_cast(float, v);
}

// ---------------------------------------------------------------------------
// fp32 -> bf16: x->xb; [Wq;Wk;Wv;Wg;Wa;pad] -> Wc (1664x512); Wo->Wob.
// grid covers 802816 float4 slots exactly (3136 blocks).
// ---------------------------------------------------------------------------
__global__ __launch_bounds__(256) void conv_bf16(const float* __restrict__ x,
                                                 const float* __restrict__ Wq,
                                                 const float* __restrict__ Wk,
                                                 const float* __restrict__ Wv,
                                                 const float* __restrict__ Wo,
                                                 const float* __restrict__ Wg,
                                                 const float* __restrict__ Wa,
                                                 unsigned short* __restrict__ xb,
                                                 unsigned short* __restrict__ Wc,
                                                 unsigned short* __restrict__ Wob) {
  int idx = blockIdx.x * 256 + threadIdx.x;  // float4 index
  if (idx < 789504) {
    const float* src;
    unsigned short* dst;
    int off;
    if (idx < 524288)      { src = x;  dst = xb;           off = idx; }
    else if (idx < 589824) { src = Wq; dst = Wc;           off = idx - 524288; }
    else if (idx < 655360) { src = Wk; dst = Wc + 262144;  off = idx - 589824; }
    else if (idx < 720896) { src = Wv; dst = Wc + 524288;  off = idx - 655360; }
    else if (idx < 786432) { src = Wo; dst = Wob;          off = idx - 720896; }
    else if (idx < 788480) { src = Wg; dst = Wc + 786432;  off = idx - 786432; }
    else                   { src = Wa; dst = Wc + 794624;  off = idx - 788480; }
    float4 v = *(const float4*)&src[(size_t)off * 4];
    ushort4 o;
    o.x = f2bf(v.x); o.y = f2bf(v.y); o.z = f2bf(v.z); o.w = f2bf(v.w);
    *(ushort4*)&dst[(size_t)off * 4] = o;
  } else {
    int off = idx - 789504;  // zero pad rows 1560..1663
    ushort4 z = {0, 0, 0, 0};
    *(ushort4*)&Wc[798720 + (size_t)off * 4] = z;
  }
}

// ---------------------------------------------------------------------------
// bf16 MFMA GEMM, 128x128 tile, BK=32.  Epilogue variants:
//   C  (fp32, stride N)          — out-proj path
//   Cb (bf16, stride 1536, col<1536) + sigmoid gate/alpha (cols>=1536) — QKV
// ---------------------------------------------------------------------------
__global__ __launch_bounds__(256) void gemm_mfma(const unsigned short* __restrict__ A,
                                                 const unsigned short* __restrict__ W,
                                                 const float* __restrict__ bias,
                                                 float* __restrict__ C,
                                                 unsigned short* __restrict__ Cb,
                                                 const float* __restrict__ bg,
                                                 const float* __restrict__ ba,
                                                 float* __restrict__ gate,
                                                 float* __restrict__ alpha,
                                                 int N, int Kd) {
  __shared__ unsigned short As[4096];
  __shared__ unsigned short Bs[4096];
  const int tid = threadIdx.x;
  const int lane = tid & 63, wave = tid >> 6;
  const int m0 = blockIdx.y * 128, n0 = blockIdx.x * 128;
  const int mo16 = (wave >> 1) * 4;
  const int no16 = (wave & 1) * 4;

  ffrag4 acc[4][4];
#pragma unroll
  for (int i = 0; i < 4; ++i)
#pragma unroll
    for (int j = 0; j < 4; ++j) acc[i][j] = (ffrag4){0.f, 0.f, 0.f, 0.f};

  for (int k0 = 0; k0 < Kd; k0 += 32) {
    __syncthreads();
#pragma unroll
    for (int u = 0; u < 2; ++u) {
      int f = tid + u * 256;
      int mtile = f >> 6, li = f & 63;
      int row = mtile * 16 + (li & 15), colq = (li >> 4) * 8;
      uint4 va = *(const uint4*)&A[(size_t)(m0 + row) * Kd + k0 + colq];
      uint4 vb = *(const uint4*)&W[(size_t)(n0 + row) * Kd + k0 + colq];
      *(uint4*)&As[f * 8] = va;
      *(uint4*)&Bs[f * 8] = vb;
    }
    __syncthreads();
    bfrag8 af[4], bf_[4];
#pragma unroll
    for (int mt = 0; mt < 4; ++mt)
      af[mt] = __builtin_bit_cast(bfrag8, *(const uint4*)&As[((mo16 + mt) * 64 + lane) * 8]);
#pragma unroll
    for (int nt = 0; nt < 4; ++nt)
      bf_[nt] = __builtin_bit_cast(bfrag8, *(const uint4*)&Bs[((no16 + nt) * 64 + lane) * 8]);
#pragma unroll
    for (int mt = 0; mt < 4; ++mt)
#pragma unroll
      for (int nt = 0; nt < 4; ++nt)
        acc[mt][nt] = __builtin_amdgcn_mfma_f32_16x16x32_bf16(af[mt], bf_[nt], acc[mt][nt], 0, 0, 0);
  }

  const int quad = lane >> 4, l15 = lane & 15;
#pragma unroll
  for (int nt = 0; nt < 4; ++nt) {
    int col = n0 + (no16 + nt) * 16 + l15;
    float bb = bias ? bias[col] : 0.f;
#pragma unroll
    for (int mt = 0; mt < 4; ++mt) {
#pragma unroll
      for (int r = 0; r < 4; ++r) {
        int row = m0 + (mo16 + mt) * 16 + quad * 4 + r;
        float val = acc[mt][nt][r] + bb;
        if (C) C[(size_t)row * N + col] = val;
        if (Cb) {
          if (col < 1536) {
            Cb[(size_t)row * QS + col] = f2bf(val);
          } else if (col < 1552) {
            gate[(size_t)row * (Hn * KT) + (col - 1536)] = sigmoidf_(val + bg[col - 1536]);
          } else if (col < 1560) {
            alpha[(size_t)row * Hn + (col - 1552)] = sigmoidf_(val + ba[col - 1552]);
          }
        }
      }
    }
  }
}

// ---------------------------------------------------------------------------
// Block per (b,h,c): S_k = K^T @ (w_k o V) via MFMA (fp32 S out), z_k via wred,
// sval (mean|k| per token) computed once here and exported for attn.
// ---------------------------------------------------------------------------
__global__ __launch_bounds__(256) void chunk_sums(const unsigned short* __restrict__ qkvb,
                                                  const float* __restrict__ gate,
                                                  const float* __restrict__ decay,
                                                  float* __restrict__ S,
                                                  float* __restrict__ Zc,
                                                  float* __restrict__ svalb) {
  __shared__ unsigned short sK[64 * 72];
  __shared__ unsigned short sV[64 * 72];
  __shared__ float red4[256];
  __shared__ float sval_s[64];
  __shared__ float gk[KT][64];
  __shared__ float pwr[KT][64];
  __shared__ float wcomb[KT][64];
  const int c = blockIdx.x, h = blockIdx.y, b = blockIdx.z;
  const int c0 = c * 64;
  const int tid = threadIdx.x, wave = tid >> 6, lane = tid & 63;
  const int quad = lane >> 4, l15 = lane & 15;

  {
    int row = tid >> 2, cg = tid & 3;
    const us8v* ksrc = (const us8v*)&qkvb[(size_t)(b * Tn + c0 + row) * QS + 512 + h * DH + cg * 16];
    *(us8v*)&sK[row * 72 + cg * 16] = ksrc[0];
    *(us8v*)&sK[row * 72 + cg * 16 + 8] = ksrc[1];
    const us8v* vsrc = (const us8v*)&qkvb[(size_t)(b * Tn + c0 + row) * QS + 1024 + h * DH + cg * 16];
    *(us8v*)&sV[row * 72 + cg * 16] = vsrc[0];
    *(us8v*)&sV[row * 72 + cg * 16 + 8] = vsrc[1];
  }
  if (tid < 128) {
    int s = tid >> 1, k2 = tid & 1;
    gk[k2][s] = gate[((size_t)(b * Tn + c0 + s) * Hn + h) * KT + k2];
  } else {
    int t2 = tid - 128;
    int k2 = t2 >> 6, d = t2 & 63;
    pwr[k2][d] = powf(sigmoidf_(decay[h * KT + k2]), (float)d);
  }
  __syncthreads();
  {
    int row = tid >> 2, cg = tid & 3;
    float acc = 0.f;
#pragma unroll
    for (int u = 0; u < 16; ++u) acc += fabsf(bf2f(sK[row * 72 + cg * 16 + u]));
    red4[tid] = acc;
  }
  if (tid >= 128) {
    int t2 = tid - 128;
    int k2 = t2 >> 6, d = t2 & 63;
    wcomb[k2][d] = gk[k2][d] * pwr[k2][63 - d];
  }
  __syncthreads();
  if (tid < 64) {
    float sv = (red4[tid * 4] + red4[tid * 4 + 1] + red4[tid * 4 + 2] + red4[tid * 4 + 3]) *
                   (1.f / 64.f) + EPS;
    sval_s[tid] = sv;
    svalb[((size_t)(b * Hn + h)) * Tn + c0 + tid] = sv;
  }
  __syncthreads();
  if (wave < 2) {
    const int kx = wave;
    float v = wcomb[kx][lane] * sval_s[lane];
    v = wred_sum(v);
    if (lane == 0) Zc[((size_t)((b * Hn + h) * KT + kx)) * NC + c] = v;
  }

  // A-operand: K^T (no extra rounding)
  const int m_glob = wave * 16 + l15;
  us8v kf[2];
#pragma unroll
  for (int ks = 0; ks < 2; ++ks)
#pragma unroll
    for (int j = 0; j < 8; ++j) kf[ks][j] = sK[(ks * 32 + quad * 8 + j) * 72 + m_glob];

#pragma unroll
  for (int k = 0; k < KT; ++k) {
    us8v bv[4][2];
#pragma unroll
    for (int nt = 0; nt < 4; ++nt)
#pragma unroll
      for (int ks = 0; ks < 2; ++ks)
#pragma unroll
        for (int j = 0; j < 8; ++j) {
          int t = ks * 32 + quad * 8 + j;
          bv[nt][ks][j] = f2bf(wcomb[k][t] * bf2f(sV[t * 72 + nt * 16 + l15]));
        }
    ffrag4 acc[4];
#pragma unroll
    for (int nt = 0; nt < 4; ++nt) acc[nt] = (ffrag4){0.f, 0.f, 0.f, 0.f};
#pragma unroll
    for (int nt = 0; nt < 4; ++nt)
#pragma unroll
      for (int ks = 0; ks < 2; ++ks)
        acc[nt] = __builtin_amdgcn_mfma_f32_16x16x32_bf16(
            __builtin_bit_cast(bfrag8, kf[ks]), __builtin_bit_cast(bfrag8, bv[nt][ks]), acc[nt], 0, 0, 0);
    const size_t sb = ((size_t)((b * Hn + h) * KT + k) * NC + c) * 4096;
#pragma unroll
    for (int nt = 0; nt < 4; ++nt)
#pragma unroll
      for (int r = 0; r < 4; ++r)
        S[sb + (size_t)(wave * 16 + quad * 4 + r) * 64 + nt * 16 + l15] = acc[nt][r];
  }
}

// ---------------------------------------------------------------------------
// Serial scan: fp32 S in, fp32 accumulator, bf16 Hinit out (bit-identical to
// the consumer-side rounding attn did before). grid (32 bhk, 8 slices).
// ---------------------------------------------------------------------------
__global__ __launch_bounds__(256) void scan_chunks(const float* __restrict__ S,
                                                   const float* __restrict__ Zc,
                                                   const float* __restrict__ decay,
                                                   unsigned short* __restrict__ Hinit,
                                                   float* __restrict__ Zinit) {
  const int bhk = blockIdx.x, slice = blockIdx.y;
  const int k = bhk % KT, h = (bhk / KT) % Hn;
  const float lam = sigmoidf_(decay[h * KT + k]);
  const float lam64 = powf(lam, 64.f);
  const int tid = threadIdx.x;
  const size_t base = (size_t)bhk * NC * 4096 + (size_t)slice * 512 + (size_t)tid * 2;
  float2 st = {0.f, 0.f};
#pragma unroll 2
  for (int c = 0; c < NC; ++c) {
    size_t off = base + (size_t)c * 4096;
    ushort2 o;
    o.x = f2bf(st.x); o.y = f2bf(st.y);
    *(ushort2*)&Hinit[off] = o;
    float2 sv = *(const float2*)&S[off];
    st.x = lam64 * st.x + sv.x;
    st.y = lam64 * st.y + sv.y;
  }
  if (slice == 0 && tid < 64) {
    float v = (tid < NC) ? Zc[bhk * NC + tid] : 0.f;
    float lp = lam64;
#pragma unroll
    for (int o = 1; o < 32; o <<= 1) {
      float t2 = __shfl_up(v, o, 64);
      if (tid >= o) v += lp * t2;
      lp *= lp;
    }
    float prev = __shfl_up(v, 1, 64);
    if (tid < NC) Zinit[bhk * NC + tid] = (tid == 0) ? 0.f : prev;
  }
}

// ---------------------------------------------------------------------------
// Block per (b,h,c): chunked attention, MFMA everywhere. Hinit bf16, sval
// precomputed.
// ---------------------------------------------------------------------------
__global__ __launch_bounds__(256) void attn_chunk(const unsigned short* __restrict__ qkvb,
                                                  const float* __restrict__ gate,
                                                  const float* __restrict__ alpha,
                                                  const float* __restrict__ decay,
                                                  const unsigned short* __restrict__ Hinit,
                                                  const float* __restrict__ Zinit,
                                                  const float* __restrict__ svalb,
                                                  unsigned short* __restrict__ ypre) {
  __shared__ float sS[64][132];              // raw scores -> probs
  __shared__ unsigned short sT16[64 * 72];   // bf16 transpose-staging
  __shared__ float sval_s[64];
  __shared__ float gk[KT][64];
  __shared__ float sz[KT][64];
  __shared__ float pw[KT][66];
  __shared__ float wt2[KT][64];              // g_s * lam^-s
  __shared__ float zin[KT];

  const int c = blockIdx.x, h = blockIdx.y, b = blockIdx.z;
  const int c0 = c * 64;
  const int tid = threadIdx.x;
  const int wave = tid >> 6, lane = tid & 63;
  const int quad = lane >> 4, l15 = lane & 15;
  const int mt = wave;

  // ---------------- prologue ----------------
  if (tid < 64) sval_s[tid] = svalb[((size_t)(b * Hn + h)) * Tn + c0 + tid];
  if (tid < 128) {
    int s = tid >> 1, k2 = tid & 1;
    gk[k2][s] = gate[((size_t)(b * Tn + c0 + s) * Hn + h) * KT + k2];
  }
  if (tid >= 128) {
    int t2 = tid - 128;
    int k2 = t2 >> 6, d = t2 & 63;
    float lamv = sigmoidf_(decay[h * KT + k2]);
    pw[k2][d] = powf(lamv, (float)d);
  }
  if (tid < 2) {
    float lamv = sigmoidf_(decay[h * KT + tid]);
    pw[tid][64] = powf(lamv, 64.f);
    zin[tid] = Zinit[((size_t)((b * Hn + h) * KT + tid)) * NC + c];
  }
  __syncthreads();
  if (tid >= 128) {
    int t2 = tid - 128;
    int k2 = t2 >> 6, d = t2 & 63;
    float lamv = sigmoidf_(decay[h * KT + k2]);
    wt2[k2][d] = gk[k2][d] * powf(lamv, -(float)d);
  }
  if (wave < 2) {
    const int kx = wave;
    float v = gk[kx][lane] * sval_s[lane];
#pragma unroll
    for (int o = 1; o < 64; o <<= 1) {
      float t2 = __shfl_up(v, o, 64);
      if (lane >= o) v += pw[kx][o] * t2;
    }
    sz[kx][lane] = v + pw[kx][lane + 1] * zin[kx];
  }
  // wt2/sz consumed in C2, after multiple syncs below — no extra barrier here.

  // ---------------- Q fragments ----------------
  us8v qf[2];
  {
    const size_t qrow = (size_t)(b * Tn + c0 + mt * 16 + l15) * QS + h * DH;
    qf[0] = *(const us8v*)&qkvb[qrow + quad * 8];
    qf[1] = *(const us8v*)&qkvb[qrow + 32 + quad * 8];
  }

  // ---------------- phase A: raw scores = Qc @ Kwin^T ----------------------
#pragma unroll
  for (int nt = 0; nt < 8; ++nt) {
    int rowg = c0 - 64 + nt * 16 + l15;
    us8v kf0 = (us8v){0, 0, 0, 0, 0, 0, 0, 0}, kf1 = kf0;
    if (rowg >= 0) {
      const size_t kb_ = (size_t)(b * Tn + rowg) * QS + 512 + h * DH;
      kf0 = *(const us8v*)&qkvb[kb_ + quad * 8];
      kf1 = *(const us8v*)&qkvb[kb_ + 32 + quad * 8];
    }
    ffrag4 a = (ffrag4){0.f, 0.f, 0.f, 0.f};
    a = __builtin_amdgcn_mfma_f32_16x16x32_bf16(__builtin_bit_cast(bfrag8, qf[0]),
                                                __builtin_bit_cast(bfrag8, kf0), a, 0, 0, 0);
    a = __builtin_amdgcn_mfma_f32_16x16x32_bf16(__builtin_bit_cast(bfrag8, qf[1]),
                                                __builtin_bit_cast(bfrag8, kf1), a, 0, 0, 0);
#pragma unroll
    for (int r = 0; r < 4; ++r) sS[mt * 16 + quad * 4 + r][nt * 16 + l15] = a[r];
  }

  // ---------------- phase C1: accH_k = Q @ Hinit_k (bf16 Hinit) ------------
  ffrag4 accH[KT][4];
#pragma unroll
  for (int k = 0; k < KT; ++k)
#pragma unroll
    for (int nt = 0; nt < 4; ++nt) accH[k][nt] = (ffrag4){0.f, 0.f, 0.f, 0.f};
  for (int k = 0; k < KT; ++k) {
    __syncthreads();
    {
      const size_t hb = ((size_t)((b * Hn + h) * KT + k) * NC + c) * 4096;
      int row = tid >> 2, cg = tid & 3;
      const us8v* src = (const us8v*)&Hinit[hb + (size_t)row * 64 + cg * 16];
      *(us8v*)&sT16[row * 72 + cg * 16] = src[0];
      *(us8v*)&sT16[row * 72 + cg * 16 + 8] = src[1];
    }
    __syncthreads();
#pragma unroll
    for (int nt = 0; nt < 4; ++nt) {
#pragma unroll
      for (int ks = 0; ks < 2; ++ks) {
        us8v g;
#pragma unroll
        for (int j = 0; j < 8; ++j) g[j] = sT16[(ks * 32 + quad * 8 + j) * 72 + nt * 16 + l15];
        accH[k][nt] = __builtin_amdgcn_mfma_f32_16x16x32_bf16(
            __builtin_bit_cast(bfrag8, qf[ks]), __builtin_bit_cast(bfrag8, g), accH[k][nt], 0, 0, 0);
      }
    }
  }

  // ---------------- stage Vc (cur chunk) + gather B-frags ------------------
  __syncthreads();
  {
    int row = tid >> 2, cg = tid & 3;
    const us8v* src = (const us8v*)&qkvb[(size_t)(b * Tn + c0 + row) * QS + 1024 + h * DH + cg * 16];
    *(us8v*)&sT16[row * 72 + cg * 16] = src[0];
    *(us8v*)&sT16[row * 72 + cg * 16 + 8] = src[1];
  }
  __syncthreads();
  us8v vf[4][2];
#pragma unroll
  for (int nt = 0; nt < 4; ++nt)
#pragma unroll
    for (int ks = 0; ks < 2; ++ks) {
#pragma unroll
      for (int j = 0; j < 8; ++j) vf[nt][ks][j] = sT16[(ks * 32 + quad * 8 + j) * 72 + nt * 16 + l15];
    }

  // ---------------- phase C2 + combine into accY ---------------------------
  const int i_loc = mt * 16 + l15;
  ffrag4 accY[4];
#pragma unroll
  for (int nt = 0; nt < 4; ++nt) accY[nt] = (ffrag4){0.f, 0.f, 0.f, 0.f};
#pragma unroll
  for (int k = 0; k < KT; ++k) {
    const float lam_i = pw[k][i_loc];
    us8v af[2];
#pragma unroll
    for (int ks = 0; ks < 2; ++ks) {
      int sb_ = ks * 32 + quad * 8;
      float4 p0 = *(const float4*)&sS[i_loc][64 + sb_];
      float4 p1 = *(const float4*)&sS[i_loc][64 + sb_ + 4];
      float4 w0 = *(const float4*)&wt2[k][sb_];
      float4 w1 = *(const float4*)&wt2[k][sb_ + 4];
      float e[8] = {p0.x * w0.x, p0.y * w0.y, p0.z * w0.z, p0.w * w0.w,
                    p1.x * w1.x, p1.y * w1.y, p1.z * w1.z, p1.w * w1.w};
#pragma unroll
      for (int j = 0; j < 8; ++j) {
        float v = (sb_ + j <= i_loc) ? e[j] * lam_i : 0.f;
        af[ks][j] = f2bf(v);
      }
    }
    ffrag4 aD[4];
#pragma unroll
    for (int nt = 0; nt < 4; ++nt) aD[nt] = (ffrag4){0.f, 0.f, 0.f, 0.f};
#pragma unroll
    for (int nt = 0; nt < 4; ++nt)
#pragma unroll
      for (int ks = 0; ks < 2; ++ks)
        aD[nt] = __builtin_amdgcn_mfma_f32_16x16x32_bf16(
            __builtin_bit_cast(bfrag8, af[ks]), __builtin_bit_cast(bfrag8, vf[nt][ks]), aD[nt], 0, 0, 0);
#pragma unroll
    for (int nt = 0; nt < 4; ++nt) {
#pragma unroll
      for (int r = 0; r < 4; ++r) {
        int il = mt * 16 + quad * 4 + r;
        float invz = 1.f / (sz[k][il] + EPS);
        accY[nt][r] += (pw[k][il + 1] * accH[k][nt][r] + aD[nt][r]) * invz;
      }
    }
  }

  // ---------------- phase D: in-place masked ALiBi softmax -----------------
  {
    const float slope = exp2f(-8.f * (float)(h + 1) / (float)Hn);
    for (int rr = 0; rr < 16; ++rr) {
      const int i = mt * 16 + rr;
      float s0v = sS[i][lane], s1v = sS[i][lane + 64];
      bool va = (lane >= i + 1) && (c0 - 64 + lane >= 0);
      bool vb2 = (lane <= i);
      s0v = va  ? s0v - slope * (float)(i + 64 - lane) : -1e30f;
      s1v = vb2 ? s1v - slope * (float)(i - lane) : -1e30f;
      float m = wred_max(fmaxf(s0v, s1v));
      float p0 = __expf(s0v - m), p1 = __expf(s1v - m);
      float inv = 1.f / wred_sum(p0 + p1);
      sS[i][lane] = p0 * inv;
      sS[i][lane + 64] = p1 * inv;
    }
  }

  // ---------------- phase E: yloc = P @ Vwin (cur half reuses vf) ----------
  ffrag4 accL[4];
#pragma unroll
  for (int nt = 0; nt < 4; ++nt) accL[nt] = (ffrag4){0.f, 0.f, 0.f, 0.f};
  us8v pf[2];
#pragma unroll
  for (int ks = 0; ks < 2; ++ks) {
    int sb_ = ks * 32 + quad * 8;
    float4 p0 = *(const float4*)&sS[i_loc][64 + sb_];
    float4 p1 = *(const float4*)&sS[i_loc][64 + sb_ + 4];
    float e[8] = {p0.x, p0.y, p0.z, p0.w, p1.x, p1.y, p1.z, p1.w};
#pragma unroll
    for (int j = 0; j < 8; ++j) pf[ks][j] = f2bf(e[j]);
  }
#pragma unroll
  for (int nt = 0; nt < 4; ++nt)
#pragma unroll
    for (int ks = 0; ks < 2; ++ks)
      accL[nt] = __builtin_amdgcn_mfma_f32_16x16x32_bf16(
          __builtin_bit_cast(bfrag8, pf[ks]), __builtin_bit_cast(bfrag8, vf[nt][ks]), accL[nt], 0, 0, 0);

  // prev-half V
  __syncthreads();
  {
    int row = tid >> 2, cg = tid & 3;
    int rowg = c0 - 64 + row;
    us8v z8 = (us8v){0, 0, 0, 0, 0, 0, 0, 0};
    us8v v0 = z8, v1 = z8;
    if (rowg >= 0) {
      const us8v* src = (const us8v*)&qkvb[(size_t)(b * Tn + rowg) * QS + 1024 + h * DH + cg * 16];
      v0 = src[0]; v1 = src[1];
    }
    *(us8v*)&sT16[row * 72 + cg * 16] = v0;
    *(us8v*)&sT16[row * 72 + cg * 16 + 8] = v1;
  }
  __syncthreads();
#pragma unroll
  for (int ks = 0; ks < 2; ++ks) {
    int sb_ = ks * 32 + quad * 8;
    float4 p0 = *(const float4*)&sS[i_loc][sb_];
    float4 p1 = *(const float4*)&sS[i_loc][sb_ + 4];
    float e[8] = {p0.x, p0.y, p0.z, p0.w, p1.x, p1.y, p1.z, p1.w};
#pragma unroll
    for (int j = 0; j < 8; ++j) pf[ks][j] = f2bf(e[j]);
  }
#pragma unroll
  for (int nt = 0; nt < 4; ++nt) {
#pragma unroll
    for (int ks = 0; ks < 2; ++ks) {
      us8v g;
#pragma unroll
      for (int j = 0; j < 8; ++j) g[j] = sT16[(ks * 32 + quad * 8 + j) * 72 + nt * 16 + l15];
      accL[nt] = __builtin_amdgcn_mfma_f32_16x16x32_bf16(
          __builtin_bit_cast(bfrag8, pf[ks]), __builtin_bit_cast(bfrag8, g), accL[nt], 0, 0, 0);
    }
  }

  // ---------------- phase F: combine + bf16 write --------------------------
#pragma unroll
  for (int nt = 0; nt < 4; ++nt) {
#pragma unroll
    for (int r = 0; r < 4; ++r) {
      int il = mt * 16 + quad * 4 + r;
      int tt = c0 + il;
      float av = alpha[((size_t)(b * Tn + tt)) * Hn + h];
      float val = av * accL[nt][r] + (1.f - av) * accY[nt][r];
      ypre[(size_t)(b * Tn + tt) * Dn + h * DH + nt * 16 + l15] = f2bf(val);
    }
  }
}

// ---------------------------------------------------------------------------
// out = LayerNorm(x + proj) * gamma + beta
// ---------------------------------------------------------------------------
__global__ __launch_bounds__(256) void ln_kernel(const float* __restrict__ x,
                                                 const float* __restrict__ proj,
                                                 const float* __restrict__ gamma,
                                                 const float* __restrict__ beta,
                                                 float* __restrict__ out) {
  const int row = blockIdx.x;
  const int tid = threadIdx.x;
  const int wave = tid >> 6, lane = tid & 63;
  const size_t base = (size_t)row * Dn;
  __shared__ float red[8];
  float r0 = x[base + tid] + proj[base + tid];
  float r1 = x[base + tid + 256] + proj[base + tid + 256];
  float s = wred_sum(r0 + r1);
  if (lane == 0) red[wave] = s;
  __syncthreads();
  float mu = (red[0] + red[1] + red[2] + red[3]) * (1.f / (float)Dn);
  float d0 = r0 - mu, d1 = r1 - mu;
  float q = wred_sum(d0 * d0 + d1 * d1);
  if (lane == 0) red[4 + wave] = q;
  __syncthreads();
  float var = (red[4] + red[5] + red[6] + red[7]) * (1.f / (float)Dn);
  float inv = rsqrtf(var + LN_EPS);
  out[base + tid]       = d0 * inv * gamma[tid]       + beta[tid];
  out[base + tid + 256] = d1 * inv * gamma[tid + 256] + beta[tid + 256];
}

// ---------------------------------------------------------------------------
extern "C" void kernel_launch(void* const* d_in, const int* in_sizes, int n_in,
                              void* d_out, int out_size, void* d_ws, size_t ws_size,
                              hipStream_t stream) {
  const float* x     = (const float*)d_in[0];
  const float* Wq    = (const float*)d_in[1];
  const float* Wk    = (const float*)d_in[2];
  const float* Wv    = (const float*)d_in[3];
  const float* Wg    = (const float*)d_in[4];
  const float* bg    = (const float*)d_in[5];
  const float* Wa    = (const float*)d_in[6];
  const float* ba    = (const float*)d_in[7];
  const float* Wo    = (const float*)d_in[8];
  const float* bo    = (const float*)d_in[9];
  const float* decay = (const float*)d_in[10];
  const float* gamma = (const float*)d_in[11];
  const float* beta  = (const float*)d_in[12];
  float* out = (float*)d_out;

  const size_t NTOK = (size_t)Bn * Tn;                  // 4096
  const size_t NST  = (size_t)Bn * Hn * KT * NC * 4096; // 4194304 state elems
  float* ws = (float*)d_ws;
  float* proj  = ws; ws += NTOK * Dn;
  float* Sb    = ws; ws += NST;    // fp32 S
  float* gateb = ws; ws += NTOK * Hn * KT;
  float* alphb = ws; ws += NTOK * Hn;
  float* Zcb   = ws; ws += (size_t)Bn * Hn * KT * NC;
  float* Zib   = ws; ws += (size_t)Bn * Hn * KT * NC;
  float* svalb = ws; ws += (size_t)Bn * Hn * Tn;
  unsigned short* us = (unsigned short*)ws;
  unsigned short* Hib  = us; us += NST;                  // bf16 Hinit
  unsigned short* xb   = us; us += NTOK * Dn;
  unsigned short* Wc   = us; us += (size_t)NW * Dn;      // 1664x512
  unsigned short* Wob  = us; us += (size_t)Dn * Dn;
  unsigned short* ypre = us; us += NTOK * Dn;
  unsigned short* qkvb = us; us += NTOK * QS;

  conv_bf16<<<3136, 256, 0, stream>>>(x, Wq, Wk, Wv, Wo, Wg, Wa, xb, Wc, Wob);

  gemm_mfma<<<dim3(NW / 128, (int)NTOK / 128), 256, 0, stream>>>(
      xb, Wc, nullptr, nullptr, qkvb, bg, ba, gateb, alphb, NW, Dn);

  chunk_sums<<<dim3(NC, Hn, Bn), 256, 0, stream>>>(qkvb, gateb, decay, Sb, Zcb, svalb);
  scan_chunks<<<dim3(Bn * Hn * KT, 8), 256, 0, stream>>>(Sb, Zcb, decay, Hib, Zib);

  attn_chunk<<<dim3(NC, Hn, Bn), 256, 0, stream>>>(qkvb, gateb, alphb, decay,
                                                   Hib, Zib, svalb, ypre);

  gemm_mfma<<<dim3(Dn / 128, (int)NTOK / 128), 256, 0, stream>>>(
      ypre, Wob, bo, proj, nullptr, nullptr, nullptr, nullptr, nullptr, Dn, Dn);
  ln_kernel<<<(int)NTOK, 256, 0, stream>>>(x, proj, gamma, beta, out);
}

// Round 8
// 166.510 us; speedup vs baseline: 5.1588x; 1.1478x over previous
//
#include <hip/hip_runtime.h>
#include <math.h>

#define EPS 1e-6f
#define LN_EPS 1e-5f

static constexpr int Bn = 2, Tn = 2048, Dn = 512, Hn = 8, KT = 2, DH = 64, NC = Tn / 64;
static constexpr int QS = 1536;   // fused qkv bf16 row stride (cols: q|k|v)
static constexpr int NW = 1664;   // padded GEMM width: qkv 1536 | gate 16 | alpha 8 | pad 104

typedef __bf16 bfrag8 __attribute__((ext_vector_type(8)));
typedef float ffrag4 __attribute__((ext_vector_type(4)));
typedef unsigned short us8v __attribute__((ext_vector_type(8)));

__device__ __forceinline__ float wred_sum(float v) {
#pragma unroll
  for (int o = 32; o > 0; o >>= 1) v += __shfl_xor(v, o, 64);
  return v;
}
__device__ __forceinline__ float wred_max(float v) {
#pragma unroll
  for (int o = 32; o > 0; o >>= 1) v = fmaxf(v, __shfl_xor(v, o, 64));
  return v;
}
__device__ __forceinline__ float sigmoidf_(float v) { return 1.0f / (1.0f + expf(-v)); }
__device__ __forceinline__ unsigned short f2bf(float f) {
  unsigned u = __builtin_bit_cast(unsigned, f);
  return (unsigned short)((u + 0x7FFFu + ((u >> 16) & 1u)) >> 16);
}
__device__ __forceinline__ float bf2f(unsigned short u) {
  unsigned v = ((unsigned)u) << 16;
  return __builtin_bit_cast(float, v);
}

// ---------------------------------------------------------------------------
// fp32 -> bf16: x->xb; [Wq;Wk;Wv;Wg;Wa;pad] -> Wc (1664x512); Wo->Wob.
// ---------------------------------------------------------------------------
__global__ __launch_bounds__(256) void conv_bf16(const float* __restrict__ x,
                                                 const float* __restrict__ Wq,
                                                 const float* __restrict__ Wk,
                                                 const float* __restrict__ Wv,
                                                 const float* __restrict__ Wo,
                                                 const float* __restrict__ Wg,
                                                 const float* __restrict__ Wa,
                                                 unsigned short* __restrict__ xb,
                                                 unsigned short* __restrict__ Wc,
                                                 unsigned short* __restrict__ Wob) {
  int idx = blockIdx.x * 256 + threadIdx.x;  // float4 index
  if (idx < 789504) {
    const float* src;
    unsigned short* dst;
    int off;
    if (idx < 524288)      { src = x;  dst = xb;           off = idx; }
    else if (idx < 589824) { src = Wq; dst = Wc;           off = idx - 524288; }
    else if (idx < 655360) { src = Wk; dst = Wc + 262144;  off = idx - 589824; }
    else if (idx < 720896) { src = Wv; dst = Wc + 524288;  off = idx - 655360; }
    else if (idx < 786432) { src = Wo; dst = Wob;          off = idx - 720896; }
    else if (idx < 788480) { src = Wg; dst = Wc + 786432;  off = idx - 786432; }
    else                   { src = Wa; dst = Wc + 794624;  off = idx - 788480; }
    float4 v = *(const float4*)&src[(size_t)off * 4];
    ushort4 o;
    o.x = f2bf(v.x); o.y = f2bf(v.y); o.z = f2bf(v.z); o.w = f2bf(v.w);
    *(ushort4*)&dst[(size_t)off * 4] = o;
  } else {
    int off = idx - 789504;  // zero pad rows 1560..1663
    ushort4 z = {0, 0, 0, 0};
    *(ushort4*)&Wc[798720 + (size_t)off * 4] = z;
  }
}

// ---------------------------------------------------------------------------
// QKV GEMM: 512 threads, 128x128 tile, BK=32, register double-buffered
// staging. 8 waves in 4x2 grid, each wave 2x4 16x16 MFMA tiles.
// Epilogue: bf16 qkv (col<1536), sigmoid gate (1536..1551), alpha (1552..1559).
// ---------------------------------------------------------------------------
__global__ __launch_bounds__(512) void gemm_qkv(const unsigned short* __restrict__ A,
                                                const unsigned short* __restrict__ W,
                                                const float* __restrict__ bg,
                                                const float* __restrict__ ba,
                                                unsigned short* __restrict__ qkvb,
                                                float* __restrict__ gate,
                                                float* __restrict__ alpha) {
  __shared__ unsigned short As[4096];  // 8 KB, fragment order
  __shared__ unsigned short Bs[4096];
  const int tid = threadIdx.x;
  const int lane = tid & 63, wave = tid >> 6;
  const int m0 = blockIdx.y * 128, n0 = blockIdx.x * 128;
  const int mw = (wave >> 1) * 2, nw = (wave & 1) * 4;

  ffrag4 acc[2][4];
#pragma unroll
  for (int i = 0; i < 2; ++i)
#pragma unroll
    for (int j = 0; j < 4; ++j) acc[i][j] = (ffrag4){0.f, 0.f, 0.f, 0.f};

  // staging address: thread tid stages fragment slot tid (mtile=tid>>6)
  const unsigned short* ag =
      A + (size_t)(m0 + (tid >> 6) * 16 + (tid & 15)) * Dn + ((tid >> 4) & 3) * 8;
  const unsigned short* wg =
      W + (size_t)(n0 + (tid >> 6) * 16 + (tid & 15)) * Dn + ((tid >> 4) & 3) * 8;
  uint4 va = *(const uint4*)ag;
  uint4 vb = *(const uint4*)wg;

  for (int k0 = 0; k0 < Dn; k0 += 32) {
    __syncthreads();
    *(uint4*)&As[tid * 8] = va;
    *(uint4*)&Bs[tid * 8] = vb;
    __syncthreads();
    if (k0 + 32 < Dn) {  // prefetch next tile while computing this one
      va = *(const uint4*)(ag + k0 + 32);
      vb = *(const uint4*)(wg + k0 + 32);
    }
    bfrag8 af[2], bf_[4];
#pragma unroll
    for (int mt = 0; mt < 2; ++mt)
      af[mt] = __builtin_bit_cast(bfrag8, *(const uint4*)&As[((mw + mt) * 64 + lane) * 8]);
#pragma unroll
    for (int nt = 0; nt < 4; ++nt)
      bf_[nt] = __builtin_bit_cast(bfrag8, *(const uint4*)&Bs[((nw + nt) * 64 + lane) * 8]);
#pragma unroll
    for (int mt = 0; mt < 2; ++mt)
#pragma unroll
      for (int nt = 0; nt < 4; ++nt)
        acc[mt][nt] = __builtin_amdgcn_mfma_f32_16x16x32_bf16(af[mt], bf_[nt], acc[mt][nt], 0, 0, 0);
  }

  const int quad = lane >> 4, l15 = lane & 15;
#pragma unroll
  for (int nt = 0; nt < 4; ++nt) {
    int col = n0 + (nw + nt) * 16 + l15;
#pragma unroll
    for (int mt = 0; mt < 2; ++mt) {
#pragma unroll
      for (int r = 0; r < 4; ++r) {
        int row = m0 + (mw + mt) * 16 + quad * 4 + r;
        float val = acc[mt][nt][r];
        if (col < 1536) {
          qkvb[(size_t)row * QS + col] = f2bf(val);
        } else if (col < 1552) {
          gate[(size_t)row * (Hn * KT) + (col - 1536)] = sigmoidf_(val + bg[col - 1536]);
        } else if (col < 1560) {
          alpha[(size_t)row * Hn + (col - 1552)] = sigmoidf_(val + ba[col - 1552]);
        }
      }
    }
  }
}

// ---------------------------------------------------------------------------
// Out-proj GEMM: 256 threads, 64x64 tile, BK=32, register double-buffered.
// 4 waves in 2x2 grid, each wave 2x2 16x16 tiles. fp32 C + bias.
// ---------------------------------------------------------------------------
__global__ __launch_bounds__(256) void gemm_out(const unsigned short* __restrict__ A,
                                                const unsigned short* __restrict__ W,
                                                const float* __restrict__ bias,
                                                float* __restrict__ C) {
  __shared__ unsigned short As[2048];  // 4 KB
  __shared__ unsigned short Bs[2048];
  const int tid = threadIdx.x;
  const int lane = tid & 63, wave = tid >> 6;
  const int m0 = blockIdx.y * 64, n0 = blockIdx.x * 64;
  const int mw = (wave >> 1) * 2, nw = (wave & 1) * 2;

  ffrag4 acc[2][2];
#pragma unroll
  for (int i = 0; i < 2; ++i)
#pragma unroll
    for (int j = 0; j < 2; ++j) acc[i][j] = (ffrag4){0.f, 0.f, 0.f, 0.f};

  const unsigned short* ag =
      A + (size_t)(m0 + (tid >> 6) * 16 + (tid & 15)) * Dn + ((tid >> 4) & 3) * 8;
  const unsigned short* wg =
      W + (size_t)(n0 + (tid >> 6) * 16 + (tid & 15)) * Dn + ((tid >> 4) & 3) * 8;
  uint4 va = *(const uint4*)ag;
  uint4 vb = *(const uint4*)wg;

  for (int k0 = 0; k0 < Dn; k0 += 32) {
    __syncthreads();
    *(uint4*)&As[tid * 8] = va;
    *(uint4*)&Bs[tid * 8] = vb;
    __syncthreads();
    if (k0 + 32 < Dn) {
      va = *(const uint4*)(ag + k0 + 32);
      vb = *(const uint4*)(wg + k0 + 32);
    }
    bfrag8 af[2], bf_[2];
#pragma unroll
    for (int mt = 0; mt < 2; ++mt)
      af[mt] = __builtin_bit_cast(bfrag8, *(const uint4*)&As[((mw + mt) * 64 + lane) * 8]);
#pragma unroll
    for (int nt = 0; nt < 2; ++nt)
      bf_[nt] = __builtin_bit_cast(bfrag8, *(const uint4*)&Bs[((nw + nt) * 64 + lane) * 8]);
#pragma unroll
    for (int mt = 0; mt < 2; ++mt)
#pragma unroll
      for (int nt = 0; nt < 2; ++nt)
        acc[mt][nt] = __builtin_amdgcn_mfma_f32_16x16x32_bf16(af[mt], bf_[nt], acc[mt][nt], 0, 0, 0);
  }

  const int quad = lane >> 4, l15 = lane & 15;
#pragma unroll
  for (int nt = 0; nt < 2; ++nt) {
    int col = n0 + (nw + nt) * 16 + l15;
    float bb = bias[col];
#pragma unroll
    for (int mt = 0; mt < 2; ++mt) {
#pragma unroll
      for (int r = 0; r < 4; ++r) {
        int row = m0 + (mw + mt) * 16 + quad * 4 + r;
        C[(size_t)row * Dn + col] = acc[mt][nt][r] + bb;
      }
    }
  }
}

// ---------------------------------------------------------------------------
// Block per (b,h,c): S_k = K^T @ (w_k o V) via MFMA (fp32 S out), z_k via wred,
// sval (mean|k| per token) computed once here and exported for attn.
// ---------------------------------------------------------------------------
__global__ __launch_bounds__(256) void chunk_sums(const unsigned short* __restrict__ qkvb,
                                                  const float* __restrict__ gate,
                                                  const float* __restrict__ decay,
                                                  float* __restrict__ S,
                                                  float* __restrict__ Zc,
                                                  float* __restrict__ svalb) {
  __shared__ unsigned short sK[64 * 72];
  __shared__ unsigned short sV[64 * 72];
  __shared__ float red4[256];
  __shared__ float sval_s[64];
  __shared__ float gk[KT][64];
  __shared__ float pwr[KT][64];
  __shared__ float wcomb[KT][64];
  const int c = blockIdx.x, h = blockIdx.y, b = blockIdx.z;
  const int c0 = c * 64;
  const int tid = threadIdx.x, wave = tid >> 6, lane = tid & 63;
  const int quad = lane >> 4, l15 = lane & 15;

  {
    int row = tid >> 2, cg = tid & 3;
    const us8v* ksrc = (const us8v*)&qkvb[(size_t)(b * Tn + c0 + row) * QS + 512 + h * DH + cg * 16];
    *(us8v*)&sK[row * 72 + cg * 16] = ksrc[0];
    *(us8v*)&sK[row * 72 + cg * 16 + 8] = ksrc[1];
    const us8v* vsrc = (const us8v*)&qkvb[(size_t)(b * Tn + c0 + row) * QS + 1024 + h * DH + cg * 16];
    *(us8v*)&sV[row * 72 + cg * 16] = vsrc[0];
    *(us8v*)&sV[row * 72 + cg * 16 + 8] = vsrc[1];
  }
  if (tid < 128) {
    int s = tid >> 1, k2 = tid & 1;
    gk[k2][s] = gate[((size_t)(b * Tn + c0 + s) * Hn + h) * KT + k2];
  } else {
    int t2 = tid - 128;
    int k2 = t2 >> 6, d = t2 & 63;
    pwr[k2][d] = powf(sigmoidf_(decay[h * KT + k2]), (float)d);
  }
  __syncthreads();
  {
    int row = tid >> 2, cg = tid & 3;
    float acc = 0.f;
#pragma unroll
    for (int u = 0; u < 16; ++u) acc += fabsf(bf2f(sK[row * 72 + cg * 16 + u]));
    red4[tid] = acc;
  }
  if (tid >= 128) {
    int t2 = tid - 128;
    int k2 = t2 >> 6, d = t2 & 63;
    wcomb[k2][d] = gk[k2][d] * pwr[k2][63 - d];
  }
  __syncthreads();
  if (tid < 64) {
    float sv = (red4[tid * 4] + red4[tid * 4 + 1] + red4[tid * 4 + 2] + red4[tid * 4 + 3]) *
                   (1.f / 64.f) + EPS;
    sval_s[tid] = sv;
    svalb[((size_t)(b * Hn + h)) * Tn + c0 + tid] = sv;
  }
  __syncthreads();
  if (wave < 2) {
    const int kx = wave;
    float v = wcomb[kx][lane] * sval_s[lane];
    v = wred_sum(v);
    if (lane == 0) Zc[((size_t)((b * Hn + h) * KT + kx)) * NC + c] = v;
  }

  // A-operand: K^T (no extra rounding)
  const int m_glob = wave * 16 + l15;
  us8v kf[2];
#pragma unroll
  for (int ks = 0; ks < 2; ++ks)
#pragma unroll
    for (int j = 0; j < 8; ++j) kf[ks][j] = sK[(ks * 32 + quad * 8 + j) * 72 + m_glob];

#pragma unroll
  for (int k = 0; k < KT; ++k) {
    us8v bv[4][2];
#pragma unroll
    for (int nt = 0; nt < 4; ++nt)
#pragma unroll
      for (int ks = 0; ks < 2; ++ks)
#pragma unroll
        for (int j = 0; j < 8; ++j) {
          int t = ks * 32 + quad * 8 + j;
          bv[nt][ks][j] = f2bf(wcomb[k][t] * bf2f(sV[t * 72 + nt * 16 + l15]));
        }
    ffrag4 acc[4];
#pragma unroll
    for (int nt = 0; nt < 4; ++nt) acc[nt] = (ffrag4){0.f, 0.f, 0.f, 0.f};
#pragma unroll
    for (int nt = 0; nt < 4; ++nt)
#pragma unroll
      for (int ks = 0; ks < 2; ++ks)
        acc[nt] = __builtin_amdgcn_mfma_f32_16x16x32_bf16(
            __builtin_bit_cast(bfrag8, kf[ks]), __builtin_bit_cast(bfrag8, bv[nt][ks]), acc[nt], 0, 0, 0);
    const size_t sb = ((size_t)((b * Hn + h) * KT + k) * NC + c) * 4096;
#pragma unroll
    for (int nt = 0; nt < 4; ++nt)
#pragma unroll
      for (int r = 0; r < 4; ++r)
        S[sb + (size_t)(wave * 16 + quad * 4 + r) * 64 + nt * 16 + l15] = acc[nt][r];
  }
}

// ---------------------------------------------------------------------------
// Serial scan: fp32 S in, fp32 accumulator, bf16 Hinit out.
// ---------------------------------------------------------------------------
__global__ __launch_bounds__(256) void scan_chunks(const float* __restrict__ S,
                                                   const float* __restrict__ Zc,
                                                   const float* __restrict__ decay,
                                                   unsigned short* __restrict__ Hinit,
                                                   float* __restrict__ Zinit) {
  const int bhk = blockIdx.x, slice = blockIdx.y;
  const int k = bhk % KT, h = (bhk / KT) % Hn;
  const float lam = sigmoidf_(decay[h * KT + k]);
  const float lam64 = powf(lam, 64.f);
  const int tid = threadIdx.x;
  const size_t base = (size_t)bhk * NC * 4096 + (size_t)slice * 512 + (size_t)tid * 2;
  float2 st = {0.f, 0.f};
#pragma unroll 2
  for (int c = 0; c < NC; ++c) {
    size_t off = base + (size_t)c * 4096;
    ushort2 o;
    o.x = f2bf(st.x); o.y = f2bf(st.y);
    *(ushort2*)&Hinit[off] = o;
    float2 sv = *(const float2*)&S[off];
    st.x = lam64 * st.x + sv.x;
    st.y = lam64 * st.y + sv.y;
  }
  if (slice == 0 && tid < 64) {
    float v = (tid < NC) ? Zc[bhk * NC + tid] : 0.f;
    float lp = lam64;
#pragma unroll
    for (int o = 1; o < 32; o <<= 1) {
      float t2 = __shfl_up(v, o, 64);
      if (tid >= o) v += lp * t2;
      lp *= lp;
    }
    float prev = __shfl_up(v, 1, 64);
    if (tid < NC) Zinit[bhk * NC + tid] = (tid == 0) ? 0.f : prev;
  }
}

// ---------------------------------------------------------------------------
// Block per (b,h,c): chunked attention, MFMA everywhere. Hinit bf16, sval
// precomputed.
// ---------------------------------------------------------------------------
__global__ __launch_bounds__(256) void attn_chunk(const unsigned short* __restrict__ qkvb,
                                                  const float* __restrict__ gate,
                                                  const float* __restrict__ alpha,
                                                  const float* __restrict__ decay,
                                                  const unsigned short* __restrict__ Hinit,
                                                  const float* __restrict__ Zinit,
                                                  const float* __restrict__ svalb,
                                                  unsigned short* __restrict__ ypre) {
  __shared__ float sS[64][132];              // raw scores -> probs
  __shared__ unsigned short sT16[64 * 72];   // bf16 transpose-staging
  __shared__ float sval_s[64];
  __shared__ float gk[KT][64];
  __shared__ float sz[KT][64];
  __shared__ float pw[KT][66];
  __shared__ float wt2[KT][64];              // g_s * lam^-s
  __shared__ float zin[KT];

  const int c = blockIdx.x, h = blockIdx.y, b = blockIdx.z;
  const int c0 = c * 64;
  const int tid = threadIdx.x;
  const int wave = tid >> 6, lane = tid & 63;
  const int quad = lane >> 4, l15 = lane & 15;
  const int mt = wave;

  // ---------------- prologue ----------------
  if (tid < 64) sval_s[tid] = svalb[((size_t)(b * Hn + h)) * Tn + c0 + tid];
  if (tid < 128) {
    int s = tid >> 1, k2 = tid & 1;
    gk[k2][s] = gate[((size_t)(b * Tn + c0 + s) * Hn + h) * KT + k2];
  }
  if (tid >= 128) {
    int t2 = tid - 128;
    int k2 = t2 >> 6, d = t2 & 63;
    float lamv = sigmoidf_(decay[h * KT + k2]);
    pw[k2][d] = powf(lamv, (float)d);
  }
  if (tid < 2) {
    float lamv = sigmoidf_(decay[h * KT + tid]);
    pw[tid][64] = powf(lamv, 64.f);
    zin[tid] = Zinit[((size_t)((b * Hn + h) * KT + tid)) * NC + c];
  }
  __syncthreads();
  if (tid >= 128) {
    int t2 = tid - 128;
    int k2 = t2 >> 6, d = t2 & 63;
    float lamv = sigmoidf_(decay[h * KT + k2]);
    wt2[k2][d] = gk[k2][d] * powf(lamv, -(float)d);
  }
  if (wave < 2) {
    const int kx = wave;
    float v = gk[kx][lane] * sval_s[lane];
#pragma unroll
    for (int o = 1; o < 64; o <<= 1) {
      float t2 = __shfl_up(v, o, 64);
      if (lane >= o) v += pw[kx][o] * t2;
    }
    sz[kx][lane] = v + pw[kx][lane + 1] * zin[kx];
  }
  // wt2/sz consumed in C2, after multiple syncs below.

  // ---------------- Q fragments ----------------
  us8v qf[2];
  {
    const size_t qrow = (size_t)(b * Tn + c0 + mt * 16 + l15) * QS + h * DH;
    qf[0] = *(const us8v*)&qkvb[qrow + quad * 8];
    qf[1] = *(const us8v*)&qkvb[qrow + 32 + quad * 8];
  }

  // ---------------- phase A: raw scores = Qc @ Kwin^T ----------------------
#pragma unroll
  for (int nt = 0; nt < 8; ++nt) {
    int rowg = c0 - 64 + nt * 16 + l15;
    us8v kf0 = (us8v){0, 0, 0, 0, 0, 0, 0, 0}, kf1 = kf0;
    if (rowg >= 0) {
      const size_t kb_ = (size_t)(b * Tn + rowg) * QS + 512 + h * DH;
      kf0 = *(const us8v*)&qkvb[kb_ + quad * 8];
      kf1 = *(const us8v*)&qkvb[kb_ + 32 + quad * 8];
    }
    ffrag4 a = (ffrag4){0.f, 0.f, 0.f, 0.f};
    a = __builtin_amdgcn_mfma_f32_16x16x32_bf16(__builtin_bit_cast(bfrag8, qf[0]),
                                                __builtin_bit_cast(bfrag8, kf0), a, 0, 0, 0);
    a = __builtin_amdgcn_mfma_f32_16x16x32_bf16(__builtin_bit_cast(bfrag8, qf[1]),
                                                __builtin_bit_cast(bfrag8, kf1), a, 0, 0, 0);
#pragma unroll
    for (int r = 0; r < 4; ++r) sS[mt * 16 + quad * 4 + r][nt * 16 + l15] = a[r];
  }

  // ---------------- phase C1: accH_k = Q @ Hinit_k (bf16 Hinit) ------------
  ffrag4 accH[KT][4];
#pragma unroll
  for (int k = 0; k < KT; ++k)
#pragma unroll
    for (int nt = 0; nt < 4; ++nt) accH[k][nt] = (ffrag4){0.f, 0.f, 0.f, 0.f};
  for (int k = 0; k < KT; ++k) {
    __syncthreads();
    {
      const size_t hb = ((size_t)((b * Hn + h) * KT + k) * NC + c) * 4096;
      int row = tid >> 2, cg = tid & 3;
      const us8v* src = (const us8v*)&Hinit[hb + (size_t)row * 64 + cg * 16];
      *(us8v*)&sT16[row * 72 + cg * 16] = src[0];
      *(us8v*)&sT16[row * 72 + cg * 16 + 8] = src[1];
    }
    __syncthreads();
#pragma unroll
    for (int nt = 0; nt < 4; ++nt) {
#pragma unroll
      for (int ks = 0; ks < 2; ++ks) {
        us8v g;
#pragma unroll
        for (int j = 0; j < 8; ++j) g[j] = sT16[(ks * 32 + quad * 8 + j) * 72 + nt * 16 + l15];
        accH[k][nt] = __builtin_amdgcn_mfma_f32_16x16x32_bf16(
            __builtin_bit_cast(bfrag8, qf[ks]), __builtin_bit_cast(bfrag8, g), accH[k][nt], 0, 0, 0);
      }
    }
  }

  // ---------------- stage Vc (cur chunk) + gather B-frags ------------------
  __syncthreads();
  {
    int row = tid >> 2, cg = tid & 3;
    const us8v* src = (const us8v*)&qkvb[(size_t)(b * Tn + c0 + row) * QS + 1024 + h * DH + cg * 16];
    *(us8v*)&sT16[row * 72 + cg * 16] = src[0];
    *(us8v*)&sT16[row * 72 + cg * 16 + 8] = src[1];
  }
  __syncthreads();
  us8v vf[4][2];
#pragma unroll
  for (int nt = 0; nt < 4; ++nt)
#pragma unroll
    for (int ks = 0; ks < 2; ++ks) {
#pragma unroll
      for (int j = 0; j < 8; ++j) vf[nt][ks][j] = sT16[(ks * 32 + quad * 8 + j) * 72 + nt * 16 + l15];
    }

  // ---------------- phase C2 + combine into accY ---------------------------
  const int i_loc = mt * 16 + l15;
  ffrag4 accY[4];
#pragma unroll
  for (int nt = 0; nt < 4; ++nt) accY[nt] = (ffrag4){0.f, 0.f, 0.f, 0.f};
#pragma unroll
  for (int k = 0; k < KT; ++k) {
    const float lam_i = pw[k][i_loc];
    us8v af[2];
#pragma unroll
    for (int ks = 0; ks < 2; ++ks) {
      int sb_ = ks * 32 + quad * 8;
      float4 p0 = *(const float4*)&sS[i_loc][64 + sb_];
      float4 p1 = *(const float4*)&sS[i_loc][64 + sb_ + 4];
      float4 w0 = *(const float4*)&wt2[k][sb_];
      float4 w1 = *(const float4*)&wt2[k][sb_ + 4];
      float e[8] = {p0.x * w0.x, p0.y * w0.y, p0.z * w0.z, p0.w * w0.w,
                    p1.x * w1.x, p1.y * w1.y, p1.z * w1.z, p1.w * w1.w};
#pragma unroll
      for (int j = 0; j < 8; ++j) {
        float v = (sb_ + j <= i_loc) ? e[j] * lam_i : 0.f;
        af[ks][j] = f2bf(v);
      }
    }
    ffrag4 aD[4];
#pragma unroll
    for (int nt = 0; nt < 4; ++nt) aD[nt] = (ffrag4){0.f, 0.f, 0.f, 0.f};
#pragma unroll
    for (int nt = 0; nt < 4; ++nt)
#pragma unroll
      for (int ks = 0; ks < 2; ++ks)
        aD[nt] = __builtin_amdgcn_mfma_f32_16x16x32_bf16(
            __builtin_bit_cast(bfrag8, af[ks]), __builtin_bit_cast(bfrag8, vf[nt][ks]), aD[nt], 0, 0, 0);
#pragma unroll
    for (int nt = 0; nt < 4; ++nt) {
#pragma unroll
      for (int r = 0; r < 4; ++r) {
        int il = mt * 16 + quad * 4 + r;
        float invz = 1.f / (sz[k][il] + EPS);
        accY[nt][r] += (pw[k][il + 1] * accH[k][nt][r] + aD[nt][r]) * invz;
      }
    }
  }

  // ---------------- phase D: in-place masked ALiBi softmax -----------------
  {
    const float slope = exp2f(-8.f * (float)(h + 1) / (float)Hn);
    for (int rr = 0; rr < 16; ++rr) {
      const int i = mt * 16 + rr;
      float s0v = sS[i][lane], s1v = sS[i][lane + 64];
      bool va = (lane >= i + 1) && (c0 - 64 + lane >= 0);
      bool vb2 = (lane <= i);
      s0v = va  ? s0v - slope * (float)(i + 64 - lane) : -1e30f;
      s1v = vb2 ? s1v - slope * (float)(i - lane) : -1e30f;
      float m = wred_max(fmaxf(s0v, s1v));
      float p0 = __expf(s0v - m), p1 = __expf(s1v - m);
      float inv = 1.f / wred_sum(p0 + p1);
      sS[i][lane] = p0 * inv;
      sS[i][lane + 64] = p1 * inv;
    }
  }

  // ---------------- phase E: yloc = P @ Vwin (cur half reuses vf) ----------
  ffrag4 accL[4];
#pragma unroll
  for (int nt = 0; nt < 4; ++nt) accL[nt] = (ffrag4){0.f, 0.f, 0.f, 0.f};
  us8v pf[2];
#pragma unroll
  for (int ks = 0; ks < 2; ++ks) {
    int sb_ = ks * 32 + quad * 8;
    float4 p0 = *(const float4*)&sS[i_loc][64 + sb_];
    float4 p1 = *(const float4*)&sS[i_loc][64 + sb_ + 4];
    float e[8] = {p0.x, p0.y, p0.z, p0.w, p1.x, p1.y, p1.z, p1.w};
#pragma unroll
    for (int j = 0; j < 8; ++j) pf[ks][j] = f2bf(e[j]);
  }
#pragma unroll
  for (int nt = 0; nt < 4; ++nt)
#pragma unroll
    for (int ks = 0; ks < 2; ++ks)
      accL[nt] = __builtin_amdgcn_mfma_f32_16x16x32_bf16(
          __builtin_bit_cast(bfrag8, pf[ks]), __builtin_bit_cast(bfrag8, vf[nt][ks]), accL[nt], 0, 0, 0);

  // prev-half V
  __syncthreads();
  {
    int row = tid >> 2, cg = tid & 3;
    int rowg = c0 - 64 + row;
    us8v z8 = (us8v){0, 0, 0, 0, 0, 0, 0, 0};
    us8v v0 = z8, v1 = z8;
    if (rowg >= 0) {
      const us8v* src = (const us8v*)&qkvb[(size_t)(b * Tn + rowg) * QS + 1024 + h * DH + cg * 16];
      v0 = src[0]; v1 = src[1];
    }
    *(us8v*)&sT16[row * 72 + cg * 16] = v0;
    *(us8v*)&sT16[row * 72 + cg * 16 + 8] = v1;
  }
  __syncthreads();
#pragma unroll
  for (int ks = 0; ks < 2; ++ks) {
    int sb_ = ks * 32 + quad * 8;
    float4 p0 = *(const float4*)&sS[i_loc][sb_];
    float4 p1 = *(const float4*)&sS[i_loc][sb_ + 4];
    float e[8] = {p0.x, p0.y, p0.z, p0.w, p1.x, p1.y, p1.z, p1.w};
#pragma unroll
    for (int j = 0; j < 8; ++j) pf[ks][j] = f2bf(e[j]);
  }
#pragma unroll
  for (int nt = 0; nt < 4; ++nt) {
#pragma unroll
    for (int ks = 0; ks < 2; ++ks) {
      us8v g;
#pragma unroll
      for (int j = 0; j < 8; ++j) g[j] = sT16[(ks * 32 + quad * 8 + j) * 72 + nt * 16 + l15];
      accL[nt] = __builtin_amdgcn_mfma_f32_16x16x32_bf16(
          __builtin_bit_cast(bfrag8, pf[ks]), __builtin_bit_cast(bfrag8, g), accL[nt], 0, 0, 0);
    }
  }

  // ---------------- phase F: combine + bf16 write --------------------------
#pragma unroll
  for (int nt = 0; nt < 4; ++nt) {
#pragma unroll
    for (int r = 0; r < 4; ++r) {
      int il = mt * 16 + quad * 4 + r;
      int tt = c0 + il;
      float av = alpha[((size_t)(b * Tn + tt)) * Hn + h];
      float val = av * accL[nt][r] + (1.f - av) * accY[nt][r];
      ypre[(size_t)(b * Tn + tt) * Dn + h * DH + nt * 16 + l15] = f2bf(val);
    }
  }
}

// ---------------------------------------------------------------------------
// out = LayerNorm(x + proj) * gamma + beta
// ---------------------------------------------------------------------------
__global__ __launch_bounds__(256) void ln_kernel(const float* __restrict__ x,
                                                 const float* __restrict__ proj,
                                                 const float* __restrict__ gamma,
                                                 const float* __restrict__ beta,
                                                 float* __restrict__ out) {
  const int row = blockIdx.x;
  const int tid = threadIdx.x;
  const int wave = tid >> 6, lane = tid & 63;
  const size_t base = (size_t)row * Dn;
  __shared__ float red[8];
  float r0 = x[base + tid] + proj[base + tid];
  float r1 = x[base + tid + 256] + proj[base + tid + 256];
  float s = wred_sum(r0 + r1);
  if (lane == 0) red[wave] = s;
  __syncthreads();
  float mu = (red[0] + red[1] + red[2] + red[3]) * (1.f / (float)Dn);
  float d0 = r0 - mu, d1 = r1 - mu;
  float q = wred_sum(d0 * d0 + d1 * d1);
  if (lane == 0) red[4 + wave] = q;
  __syncthreads();
  float var = (red[4] + red[5] + red[6] + red[7]) * (1.f / (float)Dn);
  float inv = rsqrtf(var + LN_EPS);
  out[base + tid]       = d0 * inv * gamma[tid]       + beta[tid];
  out[base + tid + 256] = d1 * inv * gamma[tid + 256] + beta[tid + 256];
}

// ---------------------------------------------------------------------------
extern "C" void kernel_launch(void* const* d_in, const int* in_sizes, int n_in,
                              void* d_out, int out_size, void* d_ws, size_t ws_size,
                              hipStream_t stream) {
  const float* x     = (const float*)d_in[0];
  const float* Wq    = (const float*)d_in[1];
  const float* Wk    = (const float*)d_in[2];
  const float* Wv    = (const float*)d_in[3];
  const float* Wg    = (const float*)d_in[4];
  const float* bg    = (const float*)d_in[5];
  const float* Wa    = (const float*)d_in[6];
  const float* ba    = (const float*)d_in[7];
  const float* Wo    = (const float*)d_in[8];
  const float* bo    = (const float*)d_in[9];
  const float* decay = (const float*)d_in[10];
  const float* gamma = (const float*)d_in[11];
  const float* beta  = (const float*)d_in[12];
  float* out = (float*)d_out;

  const size_t NTOK = (size_t)Bn * Tn;                  // 4096
  const size_t NST  = (size_t)Bn * Hn * KT * NC * 4096; // 4194304 state elems
  float* ws = (float*)d_ws;
  float* proj  = ws; ws += NTOK * Dn;
  float* Sb    = ws; ws += NST;    // fp32 S
  float* gateb = ws; ws += NTOK * Hn * KT;
  float* alphb = ws; ws += NTOK * Hn;
  float* Zcb   = ws; ws += (size_t)Bn * Hn * KT * NC;
  float* Zib   = ws; ws += (size_t)Bn * Hn * KT * NC;
  float* svalb = ws; ws += (size_t)Bn * Hn * Tn;
  unsigned short* us = (unsigned short*)ws;
  unsigned short* Hib  = us; us += NST;                  // bf16 Hinit
  unsigned short* xb   = us; us += NTOK * Dn;
  unsigned short* Wc   = us; us += (size_t)NW * Dn;      // 1664x512
  unsigned short* Wob  = us; us += (size_t)Dn * Dn;
  unsigned short* ypre = us; us += NTOK * Dn;
  unsigned short* qkvb = us; us += NTOK * QS;

  conv_bf16<<<3136, 256, 0, stream>>>(x, Wq, Wk, Wv, Wo, Wg, Wa, xb, Wc, Wob);

  gemm_qkv<<<dim3(NW / 128, (int)NTOK / 128), 512, 0, stream>>>(
      xb, Wc, bg, ba, qkvb, gateb, alphb);

  chunk_sums<<<dim3(NC, Hn, Bn), 256, 0, stream>>>(qkvb, gateb, decay, Sb, Zcb, svalb);
  scan_chunks<<<dim3(Bn * Hn * KT, 8), 256, 0, stream>>>(Sb, Zcb, decay, Hib, Zib);

  attn_chunk<<<dim3(NC, Hn, Bn), 256, 0, stream>>>(qkvb, gateb, alphb, decay,
                                                   Hib, Zib, svalb, ypre);

  gemm_out<<<dim3(Dn / 64, (int)NTOK / 64), 256, 0, stream>>>(ypre, Wob, bo, proj);
  ln_kernel<<<(int)NTOK, 256, 0, stream>>>(x, proj, gamma, beta, out);
}

// Round 9
// 163.327 us; speedup vs baseline: 5.2593x; 1.0195x over previous
//
#include <hip/hip_runtime.h>
#include <math.h>

#define EPS 1e-6f
#define LN_EPS 1e-5f

static constexpr int Bn = 2, Tn = 2048, Dn = 512, Hn = 8, KT = 2, DH = 64, NC = Tn / 64;
static constexpr int QS = 1536;   // fused qkv bf16 row stride (cols: q|k|v)
static constexpr int NW = 1664;   // padded GEMM width: qkv 1536 | gate 16 | alpha 8 | pad 104

typedef __bf16 bfrag8 __attribute__((ext_vector_type(8)));
typedef float ffrag4 __attribute__((ext_vector_type(4)));
typedef unsigned short us8v __attribute__((ext_vector_type(8)));

__device__ __forceinline__ float wred_sum(float v) {
#pragma unroll
  for (int o = 32; o > 0; o >>= 1) v += __shfl_xor(v, o, 64);
  return v;
}
__device__ __forceinline__ float wred_max(float v) {
#pragma unroll
  for (int o = 32; o > 0; o >>= 1) v = fmaxf(v, __shfl_xor(v, o, 64));
  return v;
}
__device__ __forceinline__ float sigmoidf_(float v) { return 1.0f / (1.0f + expf(-v)); }
__device__ __forceinline__ unsigned short f2bf(float f) {
  unsigned u = __builtin_bit_cast(unsigned, f);
  return (unsigned short)((u + 0x7FFFu + ((u >> 16) & 1u)) >> 16);
}
__device__ __forceinline__ float bf2f(unsigned short u) {
  unsigned v = ((unsigned)u) << 16;
  return __builtin_bit_cast(float, v);
}

// ---------------------------------------------------------------------------
// fp32 -> bf16: x->xb; [Wq;Wk;Wv;Wg;Wa;pad] -> Wc (1664x512); Wo->Wob.
// ---------------------------------------------------------------------------
__global__ __launch_bounds__(256) void conv_bf16(const float* __restrict__ x,
                                                 const float* __restrict__ Wq,
                                                 const float* __restrict__ Wk,
                                                 const float* __restrict__ Wv,
                                                 const float* __restrict__ Wo,
                                                 const float* __restrict__ Wg,
                                                 const float* __restrict__ Wa,
                                                 unsigned short* __restrict__ xb,
                                                 unsigned short* __restrict__ Wc,
                                                 unsigned short* __restrict__ Wob) {
  int idx = blockIdx.x * 256 + threadIdx.x;  // float4 index
  if (idx < 789504) {
    const float* src;
    unsigned short* dst;
    int off;
    if (idx < 524288)      { src = x;  dst = xb;           off = idx; }
    else if (idx < 589824) { src = Wq; dst = Wc;           off = idx - 524288; }
    else if (idx < 655360) { src = Wk; dst = Wc + 262144;  off = idx - 589824; }
    else if (idx < 720896) { src = Wv; dst = Wc + 524288;  off = idx - 655360; }
    else if (idx < 786432) { src = Wo; dst = Wob;          off = idx - 720896; }
    else if (idx < 788480) { src = Wg; dst = Wc + 786432;  off = idx - 786432; }
    else                   { src = Wa; dst = Wc + 794624;  off = idx - 788480; }
    float4 v = *(const float4*)&src[(size_t)off * 4];
    ushort4 o;
    o.x = f2bf(v.x); o.y = f2bf(v.y); o.z = f2bf(v.z); o.w = f2bf(v.w);
    *(ushort4*)&dst[(size_t)off * 4] = o;
  } else {
    int off = idx - 789504;  // zero pad rows 1560..1663
    ushort4 z = {0, 0, 0, 0};
    *(ushort4*)&Wc[798720 + (size_t)off * 4] = z;
  }
}

// ---------------------------------------------------------------------------
// QKV GEMM: 512 threads, 128x128 tile, BK=32, depth-2 register prefetch.
// Epilogue: bf16 qkv (col<1536), sigmoid gate (1536..1551), alpha (1552..1559).
// ---------------------------------------------------------------------------
__global__ __launch_bounds__(512) void gemm_qkv(const unsigned short* __restrict__ A,
                                                const unsigned short* __restrict__ W,
                                                const float* __restrict__ bg,
                                                const float* __restrict__ ba,
                                                unsigned short* __restrict__ qkvb,
                                                float* __restrict__ gate,
                                                float* __restrict__ alpha) {
  __shared__ unsigned short As[4096];
  __shared__ unsigned short Bs[4096];
  const int tid = threadIdx.x;
  const int lane = tid & 63, wave = tid >> 6;
  const int m0 = blockIdx.y * 128, n0 = blockIdx.x * 128;
  const int mw = (wave >> 1) * 2, nw = (wave & 1) * 4;

  ffrag4 acc[2][4];
#pragma unroll
  for (int i = 0; i < 2; ++i)
#pragma unroll
    for (int j = 0; j < 4; ++j) acc[i][j] = (ffrag4){0.f, 0.f, 0.f, 0.f};

  const unsigned short* ag =
      A + (size_t)(m0 + (tid >> 6) * 16 + (tid & 15)) * Dn + ((tid >> 4) & 3) * 8;
  const unsigned short* wg =
      W + (size_t)(n0 + (tid >> 6) * 16 + (tid & 15)) * Dn + ((tid >> 4) & 3) * 8;
  uint4 pa0 = *(const uint4*)ag;
  uint4 pb0 = *(const uint4*)wg;
  uint4 pa1 = *(const uint4*)(ag + 32);
  uint4 pb1 = *(const uint4*)(wg + 32);

  for (int k0 = 0; k0 < Dn; k0 += 32) {
    __syncthreads();
    *(uint4*)&As[tid * 8] = pa0;
    *(uint4*)&Bs[tid * 8] = pb0;
    __syncthreads();
    pa0 = pa1; pb0 = pb1;
    if (k0 + 64 < Dn) {  // depth-2 prefetch
      pa1 = *(const uint4*)(ag + k0 + 64);
      pb1 = *(const uint4*)(wg + k0 + 64);
    }
    bfrag8 af[2], bf_[4];
#pragma unroll
    for (int mt = 0; mt < 2; ++mt)
      af[mt] = __builtin_bit_cast(bfrag8, *(const uint4*)&As[((mw + mt) * 64 + lane) * 8]);
#pragma unroll
    for (int nt = 0; nt < 4; ++nt)
      bf_[nt] = __builtin_bit_cast(bfrag8, *(const uint4*)&Bs[((nw + nt) * 64 + lane) * 8]);
#pragma unroll
    for (int mt = 0; mt < 2; ++mt)
#pragma unroll
      for (int nt = 0; nt < 4; ++nt)
        acc[mt][nt] = __builtin_amdgcn_mfma_f32_16x16x32_bf16(af[mt], bf_[nt], acc[mt][nt], 0, 0, 0);
  }

  const int quad = lane >> 4, l15 = lane & 15;
#pragma unroll
  for (int nt = 0; nt < 4; ++nt) {
    int col = n0 + (nw + nt) * 16 + l15;
#pragma unroll
    for (int mt = 0; mt < 2; ++mt) {
#pragma unroll
      for (int r = 0; r < 4; ++r) {
        int row = m0 + (mw + mt) * 16 + quad * 4 + r;
        float val = acc[mt][nt][r];
        if (col < 1536) {
          qkvb[(size_t)row * QS + col] = f2bf(val);
        } else if (col < 1552) {
          gate[(size_t)row * (Hn * KT) + (col - 1536)] = sigmoidf_(val + bg[col - 1536]);
        } else if (col < 1560) {
          alpha[(size_t)row * Hn + (col - 1552)] = sigmoidf_(val + ba[col - 1552]);
        }
      }
    }
  }
}

// ---------------------------------------------------------------------------
// Out-proj GEMM: 256 threads, 64x64 tile, BK=32, depth-2 register prefetch.
// ---------------------------------------------------------------------------
__global__ __launch_bounds__(256) void gemm_out(const unsigned short* __restrict__ A,
                                                const unsigned short* __restrict__ W,
                                                const float* __restrict__ bias,
                                                float* __restrict__ C) {
  __shared__ unsigned short As[2048];
  __shared__ unsigned short Bs[2048];
  const int tid = threadIdx.x;
  const int lane = tid & 63, wave = tid >> 6;
  const int m0 = blockIdx.y * 64, n0 = blockIdx.x * 64;
  const int mw = (wave >> 1) * 2, nw = (wave & 1) * 2;

  ffrag4 acc[2][2];
#pragma unroll
  for (int i = 0; i < 2; ++i)
#pragma unroll
    for (int j = 0; j < 2; ++j) acc[i][j] = (ffrag4){0.f, 0.f, 0.f, 0.f};

  const unsigned short* ag =
      A + (size_t)(m0 + (tid >> 6) * 16 + (tid & 15)) * Dn + ((tid >> 4) & 3) * 8;
  const unsigned short* wg =
      W + (size_t)(n0 + (tid >> 6) * 16 + (tid & 15)) * Dn + ((tid >> 4) & 3) * 8;
  uint4 pa0 = *(const uint4*)ag;
  uint4 pb0 = *(const uint4*)wg;
  uint4 pa1 = *(const uint4*)(ag + 32);
  uint4 pb1 = *(const uint4*)(wg + 32);

  for (int k0 = 0; k0 < Dn; k0 += 32) {
    __syncthreads();
    *(uint4*)&As[tid * 8] = pa0;
    *(uint4*)&Bs[tid * 8] = pb0;
    __syncthreads();
    pa0 = pa1; pb0 = pb1;
    if (k0 + 64 < Dn) {
      pa1 = *(const uint4*)(ag + k0 + 64);
      pb1 = *(const uint4*)(wg + k0 + 64);
    }
    bfrag8 af[2], bf_[2];
#pragma unroll
    for (int mt = 0; mt < 2; ++mt)
      af[mt] = __builtin_bit_cast(bfrag8, *(const uint4*)&As[((mw + mt) * 64 + lane) * 8]);
#pragma unroll
    for (int nt = 0; nt < 2; ++nt)
      bf_[nt] = __builtin_bit_cast(bfrag8, *(const uint4*)&Bs[((nw + nt) * 64 + lane) * 8]);
#pragma unroll
    for (int mt = 0; mt < 2; ++mt)
#pragma unroll
      for (int nt = 0; nt < 2; ++nt)
        acc[mt][nt] = __builtin_amdgcn_mfma_f32_16x16x32_bf16(af[mt], bf_[nt], acc[mt][nt], 0, 0, 0);
  }

  const int quad = lane >> 4, l15 = lane & 15;
#pragma unroll
  for (int nt = 0; nt < 2; ++nt) {
    int col = n0 + (nw + nt) * 16 + l15;
    float bb = bias[col];
#pragma unroll
    for (int mt = 0; mt < 2; ++mt) {
#pragma unroll
      for (int r = 0; r < 4; ++r) {
        int row = m0 + (mw + mt) * 16 + quad * 4 + r;
        C[(size_t)row * Dn + col] = acc[mt][nt][r] + bb;
      }
    }
  }
}

// ---------------------------------------------------------------------------
// Block per (b,h,c): S_k = K^T @ (w_k o V) via MFMA (fp32 S out), z_k via wred,
// sval exported for attn.
// ---------------------------------------------------------------------------
__global__ __launch_bounds__(256) void chunk_sums(const unsigned short* __restrict__ qkvb,
                                                  const float* __restrict__ gate,
                                                  const float* __restrict__ decay,
                                                  float* __restrict__ S,
                                                  float* __restrict__ Zc,
                                                  float* __restrict__ svalb) {
  __shared__ unsigned short sK[64 * 72];
  __shared__ unsigned short sV[64 * 72];
  __shared__ float red4[256];
  __shared__ float sval_s[64];
  __shared__ float gk[KT][64];
  __shared__ float pwr[KT][64];
  __shared__ float wcomb[KT][64];
  const int c = blockIdx.x, h = blockIdx.y, b = blockIdx.z;
  const int c0 = c * 64;
  const int tid = threadIdx.x, wave = tid >> 6, lane = tid & 63;
  const int quad = lane >> 4, l15 = lane & 15;

  {
    int row = tid >> 2, cg = tid & 3;
    const us8v* ksrc = (const us8v*)&qkvb[(size_t)(b * Tn + c0 + row) * QS + 512 + h * DH + cg * 16];
    *(us8v*)&sK[row * 72 + cg * 16] = ksrc[0];
    *(us8v*)&sK[row * 72 + cg * 16 + 8] = ksrc[1];
    const us8v* vsrc = (const us8v*)&qkvb[(size_t)(b * Tn + c0 + row) * QS + 1024 + h * DH + cg * 16];
    *(us8v*)&sV[row * 72 + cg * 16] = vsrc[0];
    *(us8v*)&sV[row * 72 + cg * 16 + 8] = vsrc[1];
  }
  if (tid < 128) {
    int s = tid >> 1, k2 = tid & 1;
    gk[k2][s] = gate[((size_t)(b * Tn + c0 + s) * Hn + h) * KT + k2];
  } else {
    int t2 = tid - 128;
    int k2 = t2 >> 6, d = t2 & 63;
    pwr[k2][d] = powf(sigmoidf_(decay[h * KT + k2]), (float)d);
  }
  __syncthreads();
  {
    int row = tid >> 2, cg = tid & 3;
    float acc = 0.f;
#pragma unroll
    for (int u = 0; u < 16; ++u) acc += fabsf(bf2f(sK[row * 72 + cg * 16 + u]));
    red4[tid] = acc;
  }
  if (tid >= 128) {
    int t2 = tid - 128;
    int k2 = t2 >> 6, d = t2 & 63;
    wcomb[k2][d] = gk[k2][d] * pwr[k2][63 - d];
  }
  __syncthreads();
  if (tid < 64) {
    float sv = (red4[tid * 4] + red4[tid * 4 + 1] + red4[tid * 4 + 2] + red4[tid * 4 + 3]) *
                   (1.f / 64.f) + EPS;
    sval_s[tid] = sv;
    svalb[((size_t)(b * Hn + h)) * Tn + c0 + tid] = sv;
  }
  __syncthreads();
  if (wave < 2) {
    const int kx = wave;
    float v = wcomb[kx][lane] * sval_s[lane];
    v = wred_sum(v);
    if (lane == 0) Zc[((size_t)((b * Hn + h) * KT + kx)) * NC + c] = v;
  }

  const int m_glob = wave * 16 + l15;
  us8v kf[2];
#pragma unroll
  for (int ks = 0; ks < 2; ++ks)
#pragma unroll
    for (int j = 0; j < 8; ++j) kf[ks][j] = sK[(ks * 32 + quad * 8 + j) * 72 + m_glob];

#pragma unroll
  for (int k = 0; k < KT; ++k) {
    us8v bv[4][2];
#pragma unroll
    for (int nt = 0; nt < 4; ++nt)
#pragma unroll
      for (int ks = 0; ks < 2; ++ks)
#pragma unroll
        for (int j = 0; j < 8; ++j) {
          int t = ks * 32 + quad * 8 + j;
          bv[nt][ks][j] = f2bf(wcomb[k][t] * bf2f(sV[t * 72 + nt * 16 + l15]));
        }
    ffrag4 acc[4];
#pragma unroll
    for (int nt = 0; nt < 4; ++nt) acc[nt] = (ffrag4){0.f, 0.f, 0.f, 0.f};
#pragma unroll
    for (int nt = 0; nt < 4; ++nt)
#pragma unroll
      for (int ks = 0; ks < 2; ++ks)
        acc[nt] = __builtin_amdgcn_mfma_f32_16x16x32_bf16(
            __builtin_bit_cast(bfrag8, kf[ks]), __builtin_bit_cast(bfrag8, bv[nt][ks]), acc[nt], 0, 0, 0);
    const size_t sb = ((size_t)((b * Hn + h) * KT + k) * NC + c) * 4096;
#pragma unroll
    for (int nt = 0; nt < 4; ++nt)
#pragma unroll
      for (int r = 0; r < 4; ++r)
        S[sb + (size_t)(wave * 16 + quad * 4 + r) * 64 + nt * 16 + l15] = acc[nt][r];
  }
}

// ---------------------------------------------------------------------------
// Serial scan: fp32 S in, fp32 accumulator, bf16 Hinit out.
// Batch-4 loads: 4 independent loads in flight per wave per step.
// ---------------------------------------------------------------------------
__global__ __launch_bounds__(256) void scan_chunks(const float* __restrict__ S,
                                                   const float* __restrict__ Zc,
                                                   const float* __restrict__ decay,
                                                   unsigned short* __restrict__ Hinit,
                                                   float* __restrict__ Zinit) {
  const int bhk = blockIdx.x, slice = blockIdx.y;
  const int k = bhk % KT, h = (bhk / KT) % Hn;
  const float lam = sigmoidf_(decay[h * KT + k]);
  const float lam64 = powf(lam, 64.f);
  const int tid = threadIdx.x;
  const size_t base = (size_t)bhk * NC * 4096 + (size_t)slice * 512 + (size_t)tid * 2;
  float2 st = {0.f, 0.f};
  float2 sv[4];
#pragma unroll
  for (int j = 0; j < 4; ++j) sv[j] = *(const float2*)&S[base + (size_t)j * 4096];
  for (int cb = 0; cb < NC; cb += 4) {
    float2 nx[4] = {sv[0], sv[1], sv[2], sv[3]};
    if (cb + 4 < NC) {
#pragma unroll
      for (int j = 0; j < 4; ++j) nx[j] = *(const float2*)&S[base + (size_t)(cb + 4 + j) * 4096];
    }
#pragma unroll
    for (int j = 0; j < 4; ++j) {
      size_t off = base + (size_t)(cb + j) * 4096;
      ushort2 o;
      o.x = f2bf(st.x); o.y = f2bf(st.y);
      *(ushort2*)&Hinit[off] = o;
      st.x = lam64 * st.x + sv[j].x;
      st.y = lam64 * st.y + sv[j].y;
    }
#pragma unroll
    for (int j = 0; j < 4; ++j) sv[j] = nx[j];
  }
  if (slice == 0 && tid < 64) {
    float v = (tid < NC) ? Zc[bhk * NC + tid] : 0.f;
    float lp = lam64;
#pragma unroll
    for (int o = 1; o < 32; o <<= 1) {
      float t2 = __shfl_up(v, o, 64);
      if (tid >= o) v += lp * t2;
      lp *= lp;
    }
    float prev = __shfl_up(v, 1, 64);
    if (tid < NC) Zinit[bhk * NC + tid] = (tid == 0) ? 0.f : prev;
  }
}

// ---------------------------------------------------------------------------
// Block per (b,h,c): chunked attention, MFMA everywhere. Hinit bf16, sval
// precomputed. Single combined staging barrier (Hinit k0,k1 + Vc), staged
// through registers so phase A's MFMAs cover the global-load latency.
// ---------------------------------------------------------------------------
__global__ __launch_bounds__(256) void attn_chunk(const unsigned short* __restrict__ qkvb,
                                                  const float* __restrict__ gate,
                                                  const float* __restrict__ alpha,
                                                  const float* __restrict__ decay,
                                                  const unsigned short* __restrict__ Hinit,
                                                  const float* __restrict__ Zinit,
                                                  const float* __restrict__ svalb,
                                                  unsigned short* __restrict__ ypre) {
  __shared__ float sS[64][132];               // raw scores -> probs (33.8 KB)
  __shared__ unsigned short sT16[3 * 4608];   // 3 bf16 staging regions (27.6 KB)
  __shared__ float sval_s[64];
  __shared__ float gk[KT][64];
  __shared__ float sz[KT][64];
  __shared__ float pw[KT][66];
  __shared__ float wt2[KT][64];               // g_s * lam^-s
  __shared__ float zin[KT];

  const int c = blockIdx.x, h = blockIdx.y, b = blockIdx.z;
  const int c0 = c * 64;
  const int tid = threadIdx.x;
  const int wave = tid >> 6, lane = tid & 63;
  const int quad = lane >> 4, l15 = lane & 15;
  const int mt = wave;

  // ---------------- prologue ----------------
  if (tid < 64) sval_s[tid] = svalb[((size_t)(b * Hn + h)) * Tn + c0 + tid];
  if (tid < 128) {
    int s = tid >> 1, k2 = tid & 1;
    gk[k2][s] = gate[((size_t)(b * Tn + c0 + s) * Hn + h) * KT + k2];
  }
  if (tid >= 128) {
    int t2 = tid - 128;
    int k2 = t2 >> 6, d = t2 & 63;
    float lamv = sigmoidf_(decay[h * KT + k2]);
    pw[k2][d] = powf(lamv, (float)d);
  }
  if (tid < 2) {
    float lamv = sigmoidf_(decay[h * KT + tid]);
    pw[tid][64] = powf(lamv, 64.f);
    zin[tid] = Zinit[((size_t)((b * Hn + h) * KT + tid)) * NC + c];
  }
  __syncthreads();
  if (tid >= 128) {
    int t2 = tid - 128;
    int k2 = t2 >> 6, d = t2 & 63;
    float lamv = sigmoidf_(decay[h * KT + k2]);
    wt2[k2][d] = gk[k2][d] * powf(lamv, -(float)d);
  }
  if (wave < 2) {
    const int kx = wave;
    float v = gk[kx][lane] * sval_s[lane];
#pragma unroll
    for (int o = 1; o < 64; o <<= 1) {
      float t2 = __shfl_up(v, o, 64);
      if (lane >= o) v += pw[kx][o] * t2;
    }
    sz[kx][lane] = v + pw[kx][lane + 1] * zin[kx];
  }
  // wt2/sz consumed in C2, after the staging barrier below.

  // -------- issue staging loads early (regs): Hinit k0,k1 + Vc ------------
  us8v stg[3][2];
  {
    int row = tid >> 2, cg = tid & 3;
#pragma unroll
    for (int k = 0; k < KT; ++k) {
      const size_t hb = ((size_t)((b * Hn + h) * KT + k) * NC + c) * 4096;
      const us8v* src = (const us8v*)&Hinit[hb + (size_t)row * 64 + cg * 16];
      stg[k][0] = src[0];
      stg[k][1] = src[1];
    }
    const us8v* vsrc = (const us8v*)&qkvb[(size_t)(b * Tn + c0 + row) * QS + 1024 + h * DH + cg * 16];
    stg[2][0] = vsrc[0];
    stg[2][1] = vsrc[1];
  }

  // ---------------- Q fragments ----------------
  us8v qf[2];
  {
    const size_t qrow = (size_t)(b * Tn + c0 + mt * 16 + l15) * QS + h * DH;
    qf[0] = *(const us8v*)&qkvb[qrow + quad * 8];
    qf[1] = *(const us8v*)&qkvb[qrow + 32 + quad * 8];
  }

  // ---------------- phase A: raw scores = Qc @ Kwin^T ----------------------
#pragma unroll
  for (int nt = 0; nt < 8; ++nt) {
    int rowg = c0 - 64 + nt * 16 + l15;
    us8v kf0 = (us8v){0, 0, 0, 0, 0, 0, 0, 0}, kf1 = kf0;
    if (rowg >= 0) {
      const size_t kb_ = (size_t)(b * Tn + rowg) * QS + 512 + h * DH;
      kf0 = *(const us8v*)&qkvb[kb_ + quad * 8];
      kf1 = *(const us8v*)&qkvb[kb_ + 32 + quad * 8];
    }
    ffrag4 a = (ffrag4){0.f, 0.f, 0.f, 0.f};
    a = __builtin_amdgcn_mfma_f32_16x16x32_bf16(__builtin_bit_cast(bfrag8, qf[0]),
                                                __builtin_bit_cast(bfrag8, kf0), a, 0, 0, 0);
    a = __builtin_amdgcn_mfma_f32_16x16x32_bf16(__builtin_bit_cast(bfrag8, qf[1]),
                                                __builtin_bit_cast(bfrag8, kf1), a, 0, 0, 0);
#pragma unroll
    for (int r = 0; r < 4; ++r) sS[mt * 16 + quad * 4 + r][nt * 16 + l15] = a[r];
  }

  // -------- commit staging regs to LDS, single barrier ---------------------
  {
    int row = tid >> 2, cg = tid & 3;
#pragma unroll
    for (int r3 = 0; r3 < 3; ++r3) {
      *(us8v*)&sT16[r3 * 4608 + row * 72 + cg * 16] = stg[r3][0];
      *(us8v*)&sT16[r3 * 4608 + row * 72 + cg * 16 + 8] = stg[r3][1];
    }
  }
  __syncthreads();

  // ---------------- phase C1: accH_k = Q @ Hinit_k -------------------------
  ffrag4 accH[KT][4];
#pragma unroll
  for (int k = 0; k < KT; ++k)
#pragma unroll
    for (int nt = 0; nt < 4; ++nt) accH[k][nt] = (ffrag4){0.f, 0.f, 0.f, 0.f};
#pragma unroll
  for (int k = 0; k < KT; ++k) {
#pragma unroll
    for (int nt = 0; nt < 4; ++nt) {
#pragma unroll
      for (int ks = 0; ks < 2; ++ks) {
        us8v g;
#pragma unroll
        for (int j = 0; j < 8; ++j)
          g[j] = sT16[k * 4608 + (ks * 32 + quad * 8 + j) * 72 + nt * 16 + l15];
        accH[k][nt] = __builtin_amdgcn_mfma_f32_16x16x32_bf16(
            __builtin_bit_cast(bfrag8, qf[ks]), __builtin_bit_cast(bfrag8, g), accH[k][nt], 0, 0, 0);
      }
    }
  }

  // ---------------- gather Vc B-frags from region 2 ------------------------
  us8v vf[4][2];
#pragma unroll
  for (int nt = 0; nt < 4; ++nt)
#pragma unroll
    for (int ks = 0; ks < 2; ++ks) {
#pragma unroll
      for (int j = 0; j < 8; ++j)
        vf[nt][ks][j] = sT16[2 * 4608 + (ks * 32 + quad * 8 + j) * 72 + nt * 16 + l15];
    }

  // ---------------- phase C2 + combine into accY ---------------------------
  const int i_loc = mt * 16 + l15;
  ffrag4 accY[4];
#pragma unroll
  for (int nt = 0; nt < 4; ++nt) accY[nt] = (ffrag4){0.f, 0.f, 0.f, 0.f};
#pragma unroll
  for (int k = 0; k < KT; ++k) {
    const float lam_i = pw[k][i_loc];
    us8v af[2];
#pragma unroll
    for (int ks = 0; ks < 2; ++ks) {
      int sb_ = ks * 32 + quad * 8;
      float4 p0 = *(const float4*)&sS[i_loc][64 + sb_];
      float4 p1 = *(const float4*)&sS[i_loc][64 + sb_ + 4];
      float4 w0 = *(const float4*)&wt2[k][sb_];
      float4 w1 = *(const float4*)&wt2[k][sb_ + 4];
      float e[8] = {p0.x * w0.x, p0.y * w0.y, p0.z * w0.z, p0.w * w0.w,
                    p1.x * w1.x, p1.y * w1.y, p1.z * w1.z, p1.w * w1.w};
#pragma unroll
      for (int j = 0; j < 8; ++j) {
        float v = (sb_ + j <= i_loc) ? e[j] * lam_i : 0.f;
        af[ks][j] = f2bf(v);
      }
    }
    ffrag4 aD[4];
#pragma unroll
    for (int nt = 0; nt < 4; ++nt) aD[nt] = (ffrag4){0.f, 0.f, 0.f, 0.f};
#pragma unroll
    for (int nt = 0; nt < 4; ++nt)
#pragma unroll
      for (int ks = 0; ks < 2; ++ks)
        aD[nt] = __builtin_amdgcn_mfma_f32_16x16x32_bf16(
            __builtin_bit_cast(bfrag8, af[ks]), __builtin_bit_cast(bfrag8, vf[nt][ks]), aD[nt], 0, 0, 0);
#pragma unroll
    for (int nt = 0; nt < 4; ++nt) {
#pragma unroll
      for (int r = 0; r < 4; ++r) {
        int il = mt * 16 + quad * 4 + r;
        float invz = 1.f / (sz[k][il] + EPS);
        accY[nt][r] += (pw[k][il + 1] * accH[k][nt][r] + aD[nt][r]) * invz;
      }
    }
  }

  // ---------------- phase D: in-place masked ALiBi softmax -----------------
  {
    const float slope = exp2f(-8.f * (float)(h + 1) / (float)Hn);
    for (int rr = 0; rr < 16; ++rr) {
      const int i = mt * 16 + rr;
      float s0v = sS[i][lane], s1v = sS[i][lane + 64];
      bool va = (lane >= i + 1) && (c0 - 64 + lane >= 0);
      bool vb2 = (lane <= i);
      s0v = va  ? s0v - slope * (float)(i + 64 - lane) : -1e30f;
      s1v = vb2 ? s1v - slope * (float)(i - lane) : -1e30f;
      float m = wred_max(fmaxf(s0v, s1v));
      float p0 = __expf(s0v - m), p1 = __expf(s1v - m);
      float inv = 1.f / wred_sum(p0 + p1);
      sS[i][lane] = p0 * inv;
      sS[i][lane + 64] = p1 * inv;
    }
  }

  // ---------------- phase E: yloc = P @ Vwin (cur half reuses vf) ----------
  ffrag4 accL[4];
#pragma unroll
  for (int nt = 0; nt < 4; ++nt) accL[nt] = (ffrag4){0.f, 0.f, 0.f, 0.f};
  us8v pf[2];
#pragma unroll
  for (int ks = 0; ks < 2; ++ks) {
    int sb_ = ks * 32 + quad * 8;
    float4 p0 = *(const float4*)&sS[i_loc][64 + sb_];
    float4 p1 = *(const float4*)&sS[i_loc][64 + sb_ + 4];
    float e[8] = {p0.x, p0.y, p0.z, p0.w, p1.x, p1.y, p1.z, p1.w};
#pragma unroll
    for (int j = 0; j < 8; ++j) pf[ks][j] = f2bf(e[j]);
  }
#pragma unroll
  for (int nt = 0; nt < 4; ++nt)
#pragma unroll
    for (int ks = 0; ks < 2; ++ks)
      accL[nt] = __builtin_amdgcn_mfma_f32_16x16x32_bf16(
          __builtin_bit_cast(bfrag8, pf[ks]), __builtin_bit_cast(bfrag8, vf[nt][ks]), accL[nt], 0, 0, 0);

  // prev-half V -> region 0
  __syncthreads();
  {
    int row = tid >> 2, cg = tid & 3;
    int rowg = c0 - 64 + row;
    us8v z8 = (us8v){0, 0, 0, 0, 0, 0, 0, 0};
    us8v v0 = z8, v1 = z8;
    if (rowg >= 0) {
      const us8v* src = (const us8v*)&qkvb[(size_t)(b * Tn + rowg) * QS + 1024 + h * DH + cg * 16];
      v0 = src[0]; v1 = src[1];
    }
    *(us8v*)&sT16[row * 72 + cg * 16] = v0;
    *(us8v*)&sT16[row * 72 + cg * 16 + 8] = v1;
  }
  __syncthreads();
#pragma unroll
  for (int ks = 0; ks < 2; ++ks) {
    int sb_ = ks * 32 + quad * 8;
    float4 p0 = *(const float4*)&sS[i_loc][sb_];
    float4 p1 = *(const float4*)&sS[i_loc][sb_ + 4];
    float e[8] = {p0.x, p0.y, p0.z, p0.w, p1.x, p1.y, p1.z, p1.w};
#pragma unroll
    for (int j = 0; j < 8; ++j) pf[ks][j] = f2bf(e[j]);
  }
#pragma unroll
  for (int nt = 0; nt < 4; ++nt) {
#pragma unroll
    for (int ks = 0; ks < 2; ++ks) {
      us8v g;
#pragma unroll
      for (int j = 0; j < 8; ++j) g[j] = sT16[(ks * 32 + quad * 8 + j) * 72 + nt * 16 + l15];
      accL[nt] = __builtin_amdgcn_mfma_f32_16x16x32_bf16(
          __builtin_bit_cast(bfrag8, pf[ks]), __builtin_bit_cast(bfrag8, g), accL[nt], 0, 0, 0);
    }
  }

  // ---------------- phase F: combine + bf16 write --------------------------
#pragma unroll
  for (int nt = 0; nt < 4; ++nt) {
#pragma unroll
    for (int r = 0; r < 4; ++r) {
      int il = mt * 16 + quad * 4 + r;
      int tt = c0 + il;
      float av = alpha[((size_t)(b * Tn + tt)) * Hn + h];
      float val = av * accL[nt][r] + (1.f - av) * accY[nt][r];
      ypre[(size_t)(b * Tn + tt) * Dn + h * DH + nt * 16 + l15] = f2bf(val);
    }
  }
}

// ---------------------------------------------------------------------------
// out = LayerNorm(x + proj) * gamma + beta
// ---------------------------------------------------------------------------
__global__ __launch_bounds__(256) void ln_kernel(const float* __restrict__ x,
                                                 const float* __restrict__ proj,
                                                 const float* __restrict__ gamma,
                                                 const float* __restrict__ beta,
                                                 float* __restrict__ out) {
  const int row = blockIdx.x;
  const int tid = threadIdx.x;
  const int wave = tid >> 6, lane = tid & 63;
  const size_t base = (size_t)row * Dn;
  __shared__ float red[8];
  float r0 = x[base + tid] + proj[base + tid];
  float r1 = x[base + tid + 256] + proj[base + tid + 256];
  float s = wred_sum(r0 + r1);
  if (lane == 0) red[wave] = s;
  __syncthreads();
  float mu = (red[0] + red[1] + red[2] + red[3]) * (1.f / (float)Dn);
  float d0 = r0 - mu, d1 = r1 - mu;
  float q = wred_sum(d0 * d0 + d1 * d1);
  if (lane == 0) red[4 + wave] = q;
  __syncthreads();
  float var = (red[4] + red[5] + red[6] + red[7]) * (1.f / (float)Dn);
  float inv = rsqrtf(var + LN_EPS);
  out[base + tid]       = d0 * inv * gamma[tid]       + beta[tid];
  out[base + tid + 256] = d1 * inv * gamma[tid + 256] + beta[tid + 256];
}

// ---------------------------------------------------------------------------
extern "C" void kernel_launch(void* const* d_in, const int* in_sizes, int n_in,
                              void* d_out, int out_size, void* d_ws, size_t ws_size,
                              hipStream_t stream) {
  const float* x     = (const float*)d_in[0];
  const float* Wq    = (const float*)d_in[1];
  const float* Wk    = (const float*)d_in[2];
  const float* Wv    = (const float*)d_in[3];
  const float* Wg    = (const float*)d_in[4];
  const float* bg    = (const float*)d_in[5];
  const float* Wa    = (const float*)d_in[6];
  const float* ba    = (const float*)d_in[7];
  const float* Wo    = (const float*)d_in[8];
  const float* bo    = (const float*)d_in[9];
  const float* decay = (const float*)d_in[10];
  const float* gamma = (const float*)d_in[11];
  const float* beta  = (const float*)d_in[12];
  float* out = (float*)d_out;

  const size_t NTOK = (size_t)Bn * Tn;                  // 4096
  const size_t NST  = (size_t)Bn * Hn * KT * NC * 4096; // 4194304 state elems
  float* ws = (float*)d_ws;
  float* proj  = ws; ws += NTOK * Dn;
  float* Sb    = ws; ws += NST;    // fp32 S
  float* gateb = ws; ws += NTOK * Hn * KT;
  float* alphb = ws; ws += NTOK * Hn;
  float* Zcb   = ws; ws += (size_t)Bn * Hn * KT * NC;
  float* Zib   = ws; ws += (size_t)Bn * Hn * KT * NC;
  float* svalb = ws; ws += (size_t)Bn * Hn * Tn;
  unsigned short* us = (unsigned short*)ws;
  unsigned short* Hib  = us; us += NST;                  // bf16 Hinit
  unsigned short* xb   = us; us += NTOK * Dn;
  unsigned short* Wc   = us; us += (size_t)NW * Dn;      // 1664x512
  unsigned short* Wob  = us; us += (size_t)Dn * Dn;
  unsigned short* ypre = us; us += NTOK * Dn;
  unsigned short* qkvb = us; us += NTOK * QS;

  conv_bf16<<<3136, 256, 0, stream>>>(x, Wq, Wk, Wv, Wo, Wg, Wa, xb, Wc, Wob);

  gemm_qkv<<<dim3(NW / 128, (int)NTOK / 128), 512, 0, stream>>>(
      xb, Wc, bg, ba, qkvb, gateb, alphb);

  chunk_sums<<<dim3(NC, Hn, Bn), 256, 0, stream>>>(qkvb, gateb, decay, Sb, Zcb, svalb);
  scan_chunks<<<dim3(Bn * Hn * KT, 8), 256, 0, stream>>>(Sb, Zcb, decay, Hib, Zib);

  attn_chunk<<<dim3(NC, Hn, Bn), 256, 0, stream>>>(qkvb, gateb, alphb, decay,
                                                   Hib, Zib, svalb, ypre);

  gemm_out<<<dim3(Dn / 64, (int)NTOK / 64), 256, 0, stream>>>(ypre, Wob, bo, proj);
  ln_kernel<<<(int)NTOK, 256, 0, stream>>>(x, proj, gamma, beta, out);
}